// Round 11
// baseline (242.956 us; speedup 1.0000x reference)
//
#include <hip/hip_runtime.h>

typedef __bf16 bf16x8 __attribute__((ext_vector_type(8)));
typedef __bf16 bf16x4 __attribute__((ext_vector_type(4)));
typedef _Float16 f16x8 __attribute__((ext_vector_type(8)));
typedef float f32x4 __attribute__((ext_vector_type(4)));
typedef float f32x16 __attribute__((ext_vector_type(16)));
typedef unsigned short u16x8 __attribute__((ext_vector_type(8)));
typedef unsigned short u16x4 __attribute__((ext_vector_type(4)));
typedef unsigned int u32x4 __attribute__((ext_vector_type(4)));
typedef unsigned short us;

#define MM 2048
#define TT 4096

__device__ __forceinline__ us f2bf(float f){
  unsigned int u = __builtin_bit_cast(unsigned int, f);
  u = (u + 0x7fffu + ((u >> 16) & 1u)) >> 16;
  return (us)u;
}
__device__ __forceinline__ float bf2f(us u){
  unsigned int x = ((unsigned int)u) << 16;
  return __builtin_bit_cast(float, x);
}
__device__ __forceinline__ us f2h(float f){
  _Float16 h = (_Float16)f;
  return __builtin_bit_cast(us, h);
}
__device__ __forceinline__ unsigned int cvt_pk_bf16(float lo, float hi){
  unsigned int r;
  asm("v_cvt_pk_bf16_f32 %0, %1, %2" : "=v"(r) : "v"(lo), "v"(hi));
  return r;
}
__device__ __forceinline__ void plane_swap(unsigned int &x, unsigned int &y){
  asm("v_permlane32_swap_b32 %0, %1" : "+v"(x), "+v"(y));
}

#define GLDS(gp, lp) __builtin_amdgcn_global_load_lds( \
    (const __attribute__((address_space(1))) unsigned int*)(gp), \
    (__attribute__((address_space(3))) unsigned int*)(lp), 16, 0, 0)

// ---------------- fused fp32 -> fp16 cast (x and data in one launch) ----------------
__global__ __launch_bounds__(256) void cast_f16_all(const float* __restrict__ x,
                                                    const float* __restrict__ data,
                                                    us* __restrict__ xf, us* __restrict__ df){
  int bid = blockIdx.x;
  const float* in; us* o;
  if (bid < 2048){ in = x; o = xf; }
  else           { in = data; o = df; bid -= 2048; }
  size_t i = ((size_t)bid * 256 + threadIdx.x) * 8;
  float4 a = *(const float4*)(in + i);
  float4 b = *(const float4*)(in + i + 4);
  float v[8] = {a.x,a.y,a.z,a.w,b.x,b.y,b.z,b.w};
  u16x8 r;
  for (int j = 0; j < 8; j++) r[j] = f2h(v[j]);
  *(u16x8*)(o + i) = r;
}

// ---------------- fused transpose for all three weights (attn/data fp16, proj bf16) ----------------
__global__ __launch_bounds__(256) void transpose_all(const float* __restrict__ W_attn,
                                                     const float* __restrict__ W_data,
                                                     const float* __restrict__ W_proj,
                                                     us* __restrict__ Af, us* __restrict__ Df,
                                                     us* __restrict__ Pb){
  __shared__ float tile[32][33];
  int bx = blockIdx.x;
  const float* W; us* o; int N; bool tobf;
  if (bx < 96){ W = W_attn; o = Af; N = 3072; tobf = false; }
  else if (bx < 160){ W = W_data; o = Df; N = 2048; bx -= 96; tobf = false; }
  else { W = W_proj; o = Pb; N = 1024; bx -= 160; tobf = true; }
  int tx = threadIdx.x & 31, ty = threadIdx.x >> 5;   // 32 x 8
  int n0 = bx * 32, k0 = blockIdx.y * 32;
  for (int r = 0; r < 32; r += 8)
    tile[ty + r][tx] = W[(size_t)(k0 + ty + r) * N + n0 + tx];
  __syncthreads();
  for (int r = 0; r < 32; r += 8){
    float v = tile[tx][ty + r];
    size_t idx = (size_t)(n0 + ty + r) * 1024 + k0 + tx;
    o[idx] = tobf ? f2bf(v) : f2h(v);
  }
}

// ---------------- merged projection GEMM, single-pass fp16 ----------------
__global__ __launch_bounds__(256) void gemm_all(const us* __restrict__ xf, const us* __restrict__ df,
                                                const us* __restrict__ Watf, const us* __restrict__ Wdtf,
                                                const float* __restrict__ b_attn, const float* __restrict__ b_data,
                                                us* __restrict__ Qf, us* __restrict__ Kf,
                                                us* __restrict__ VT){
  __shared__ us sm[8192];  // A@0, B@4096
  const int bx = blockIdx.x;
  const us *Ah, *Bth; const float* bias; int region, kroff, col0;
  if (bx < 24){
    Ah = xf; Bth = Watf; bias = b_attn;
    region = bx >> 3; kroff = 0; col0 = bx * 128;
  } else {
    int b2 = bx - 24;
    Ah = df; Bth = Wdtf; bias = b_data;
    region = 1 + (b2 >> 3); kroff = 2048; col0 = b2 * 128;
  }
  const int tid = threadIdx.x, wid = tid >> 6, lane = tid & 63;
  const int l15 = lane & 15, l16 = lane >> 4;
  const int row0 = blockIdx.y * 128;
  const int wr = (wid >> 1) * 64, wc = (wid & 1) * 64;
  f32x4 acc[4][4] = {};

  for (int k0 = 0; k0 < 1024; k0 += 32){
    for (int c = 0; c < 2; ++c){
      int i = c * 256 + tid;                           // 0..511: row=i>>2, k8=(i&3)*8
      size_t aoff = (size_t)(row0 + (i >> 2)) * 1024 + k0 + (i & 3) * 8;
      size_t boff = (size_t)(col0 + (i >> 2)) * 1024 + k0 + (i & 3) * 8;
      GLDS(Ah + aoff, &sm[c * 2048 + wid * 512]);
      GLDS(Bth + boff, &sm[4096 + c * 2048 + wid * 512]);
    }
    __syncthreads();
    f16x8 af[4], bf[4];
    for (int m = 0; m < 4; m++) af[m] = *(const f16x8*)&sm[(wr + m * 16 + l15) * 32 + l16 * 8];
    for (int n = 0; n < 4; n++) bf[n] = *(const f16x8*)&sm[4096 + (wc + n * 16 + l15) * 32 + l16 * 8];
    for (int m = 0; m < 4; m++)
      for (int n = 0; n < 4; n++)
        acc[m][n] = __builtin_amdgcn_mfma_f32_16x16x32_f16(af[m], bf[n], acc[m][n], 0, 0, 0);
    __syncthreads();
  }

  for (int m = 0; m < 4; m++)
    for (int n = 0; n < 4; n++){
      int gcol = col0 + wc + n * 16 + l15;
      int ocol = gcol & 1023;
      float bv = bias[gcol];
      if (region == 2){                    // V -> VT[b][d][t] bf16, vectorized over 4 rows
        int r = row0 + wr + m * 16 + l16 * 4;
        u16x4 o;
        for (int j = 0; j < 4; j++) o[j] = f2bf(acc[m][n][j] + bv);
        *(u16x4*)&VT[((size_t)((r >> 11) * 1024 + ocol)) * 4096 + kroff + (r & 2047)] = o;
      } else {                             // Q or K -> fp16
        us* P = (region == 0) ? Qf : Kf;
        for (int j = 0; j < 4; j++){
          int r = row0 + wr + m * 16 + l16 * 4 + j;
          size_t orow = (region == 0) ? (size_t)r
                                      : (size_t)((r >> 11) * 4096 + kroff + (r & 2047));
          P[orow * 1024 + ocol] = f2h(acc[m][n][j] + bv);
        }
      }
    }
}

// ---------------- output projection GEMM (bf16, fp32 out) ----------------
__global__ __launch_bounds__(256) void gemm_proj(const us* __restrict__ Ah,
                                                 const us* __restrict__ Bth,
                                                 const float* __restrict__ bias,
                                                 float* __restrict__ Co){
  __shared__ us sm[8192];
  const int tid = threadIdx.x, wid = tid >> 6, lane = tid & 63;
  const int l15 = lane & 15, l16 = lane >> 4;
  const int row0 = blockIdx.y * 128, col0 = blockIdx.x * 128;
  const int wr = (wid >> 1) * 64, wc = (wid & 1) * 64;
  f32x4 acc[4][4] = {};

  for (int k0 = 0; k0 < 1024; k0 += 32){
    for (int c = 0; c < 2; ++c){
      int i = c * 256 + tid;
      size_t aoff = (size_t)(row0 + (i >> 2)) * 1024 + k0 + (i & 3) * 8;
      size_t boff = (size_t)(col0 + (i >> 2)) * 1024 + k0 + (i & 3) * 8;
      GLDS(Ah + aoff, &sm[c * 2048 + wid * 512]);
      GLDS(Bth + boff, &sm[4096 + c * 2048 + wid * 512]);
    }
    __syncthreads();
    bf16x8 afh[4], bfh[4];
    for (int m = 0; m < 4; m++) afh[m] = *(const bf16x8*)&sm[(wr + m * 16 + l15) * 32 + l16 * 8];
    for (int n = 0; n < 4; n++) bfh[n] = *(const bf16x8*)&sm[4096 + (wc + n * 16 + l15) * 32 + l16 * 8];
    for (int m = 0; m < 4; m++)
      for (int n = 0; n < 4; n++)
        acc[m][n] = __builtin_amdgcn_mfma_f32_16x16x32_bf16(afh[m], bfh[n], acc[m][n], 0, 0, 0);
    __syncthreads();
  }

  for (int m = 0; m < 4; m++)
    for (int n = 0; n < 4; n++){
      int col = col0 + wc + n * 16 + l15;
      float bv = bias[col];
      for (int j = 0; j < 4; j++){
        int r = row0 + wr + m * 16 + l16 * 4 + j;
        Co[(size_t)r * 1024 + col] = acc[m][n][j] + bv;
      }
    }
}

// ---------------- fused attention: fp16 Q/K, bf16 V, MFMA row-sum, max3 tree ----------------
// grid: B*H*(M/128); 4 waves x 32 q-rows. q = lane&31, hb = lane>>5.
// S^T C-layout (m74/m101): reg 4g+j -> t = ts*32 + 8g + 4*hb + j.
// K,V: LDS double-buffered, write-late + 1 barrier/tile.
// P: T12 cvt_pk + v_permlane32_swap. T13 defer-max. l via ones-MFMA (VALU->MFMA shift).
__global__ __launch_bounds__(256) void attn_kernel(const us* __restrict__ Qf,
                                                   const us* __restrict__ Kf,
                                                   const us* __restrict__ VT,
                                                   us* __restrict__ attno){
  __shared__ us Kb[2][64 * 72];        // [dbuf][64 t][72] fp16
  __shared__ us Vb[2][64 * 72];        // [dbuf][64 d][72] bf16 (V^T tile)
  const int tid = threadIdx.x, wid = tid >> 6, lane = tid & 63;
  const int l31 = lane & 31, hb = lane >> 5, h8 = hb * 8;
  const int qt = blockIdx.x & 15;             // M/128 = 16
  const int bh = blockIdx.x >> 4;
  const int hd = (bh & 15) * 64, b = bh >> 4;
  const int qrow = qt * 128 + wid * 32 + l31;

  // Q fragments (B operand): lane holds Q[qrow][d = kk*16 + h8 + i], fp16
  f16x8 qf[4];
  {
    const us* qp = Qf + (size_t)(b * MM + qrow) * 1024 + hd;
#pragma unroll
    for (int kk = 0; kk < 4; kk++)
      qf[kk] = *(const f16x8*)(qp + kk * 16 + h8);
  }

  // all-ones bf16 A-fragment for the l row-sum MFMA (layout-immune constant)
  u16x8 ones_u;
#pragma unroll
  for (int j = 0; j < 8; j++) ones_u[j] = 0x3F80;
  const bf16x8 ones8 = __builtin_bit_cast(bf16x8, ones_u);

  const int i0 = tid, i1 = 256 + tid;
  const int kt0 = i0 >> 3, kd0 = (i0 & 7) * 8;
  const int kt1 = i1 >> 3, kd1 = (i1 & 7) * 8;

#define GK(t0_, t_, d_) (((size_t)(b * TT + (t0_) + (t_))) * 1024 + hd + (d_))
#define GV(t0_, d_, t_) (((size_t)b * 1024 + hd + (d_)) * 4096 + (t0_) + (t_))

  // prologue: stage K,V tile 0 into buf 0
  uint4 rK0 = *(const uint4*)(Kf + GK(0, kt0, kd0));
  uint4 rK1 = *(const uint4*)(Kf + GK(0, kt1, kd1));
  uint4 rV0 = *(const uint4*)(VT + GV(0, kt0, kd0));
  uint4 rV1 = *(const uint4*)(VT + GV(0, kt1, kd1));
  *(uint4*)&Kb[0][kt0 * 72 + kd0] = rK0;
  *(uint4*)&Kb[0][kt1 * 72 + kd1] = rK1;
  *(uint4*)&Vb[0][kt0 * 72 + kd0] = rV0;
  *(uint4*)&Vb[0][kt1 * 72 + kd1] = rV1;
  __syncthreads();

  f32x16 acc0 = {}, acc1 = {}, accS = {};
  float mrow = -1e30f;
  const float cs = 0.125f * 1.44269504088896f;   // to log2 domain

  for (int t0 = 0; t0 < TT; t0 += 64){
    const int cur = (t0 >> 6) & 1;
    const bool pre = (t0 + 64 < TT);
    if (pre){
      rK0 = *(const uint4*)(Kf + GK(t0 + 64, kt0, kd0));
      rK1 = *(const uint4*)(Kf + GK(t0 + 64, kt1, kd1));
      rV0 = *(const uint4*)(VT + GV(t0 + 64, kt0, kd0));
      rV1 = *(const uint4*)(VT + GV(t0 + 64, kt1, kd1));
    }

    // S^T = K . Q^T (fp16): frag ts holds t = ts*32 + tloc, q = l31
    const us* KbC = &Kb[cur][0];
    f32x16 sfr0 = {}, sfr1 = {};
    __builtin_amdgcn_s_setprio(1);
#pragma unroll
    for (int kk = 0; kk < 4; kk++){
      f16x8 a0 = *(const f16x8*)&KbC[l31 * 72 + kk * 16 + h8];
      f16x8 a1 = *(const f16x8*)&KbC[(32 + l31) * 72 + kk * 16 + h8];
      sfr0 = __builtin_amdgcn_mfma_f32_32x32x16_f16(a0, qf[kk], sfr0, 0, 0, 0);
      sfr1 = __builtin_amdgcn_mfma_f32_32x32x16_f16(a1, qf[kk], sfr1, 0, 0, 0);
    }
    __builtin_amdgcn_s_setprio(0);

    // tile max via two max3 chains (T17)
    float va = -1e30f, vb2 = -1e30f;
#pragma unroll
    for (int r = 0; r < 16; r += 2){
      va  = fmaxf(fmaxf(sfr0[r],     sfr1[r]),     va);
      vb2 = fmaxf(fmaxf(sfr0[r + 1], sfr1[r + 1]), vb2);
    }
    float v = fmaxf(va, vb2);
    float vs = v * cs;
    vs = fmaxf(vs, __shfl_xor(vs, 32, 64));
    if (!__all(vs <= mrow + 8.f)){      // T13 defer-max
      float mn = fmaxf(mrow, vs);
      float rs = __builtin_amdgcn_exp2f(mrow - mn);
      mrow = mn;
#pragma unroll
      for (int r = 0; r < 16; r++){ acc0[r] *= rs; acc1[r] *= rs; accS[r] *= rs; }
    }
    const float nm = -mrow;
    unsigned int A0[4][2], A1[4][2];
#pragma unroll
    for (int g = 0; g < 4; g++){
      float e00 = __builtin_amdgcn_exp2f(__builtin_fmaf(sfr0[4*g+0], cs, nm));
      float e01 = __builtin_amdgcn_exp2f(__builtin_fmaf(sfr0[4*g+1], cs, nm));
      float e02 = __builtin_amdgcn_exp2f(__builtin_fmaf(sfr0[4*g+2], cs, nm));
      float e03 = __builtin_amdgcn_exp2f(__builtin_fmaf(sfr0[4*g+3], cs, nm));
      float e10 = __builtin_amdgcn_exp2f(__builtin_fmaf(sfr1[4*g+0], cs, nm));
      float e11 = __builtin_amdgcn_exp2f(__builtin_fmaf(sfr1[4*g+1], cs, nm));
      float e12 = __builtin_amdgcn_exp2f(__builtin_fmaf(sfr1[4*g+2], cs, nm));
      float e13 = __builtin_amdgcn_exp2f(__builtin_fmaf(sfr1[4*g+3], cs, nm));
      A0[g][0] = cvt_pk_bf16(e00, e01);
      A0[g][1] = cvt_pk_bf16(e02, e03);
      A1[g][0] = cvt_pk_bf16(e10, e11);
      A1[g][1] = cvt_pk_bf16(e12, e13);
    }

    // build P fragments in-register (T12): frag kk = {x'0, x'1, y'0, y'1}
    bf16x8 pf[4];
#pragma unroll
    for (int kkl = 0; kkl < 2; kkl++){
      unsigned int x0 = A0[2*kkl][0], y0 = A0[2*kkl+1][0];
      unsigned int x1 = A0[2*kkl][1], y1 = A0[2*kkl+1][1];
      plane_swap(x0, y0);
      plane_swap(x1, y1);
      u32x4 w = {x0, x1, y0, y1};
      pf[kkl] = __builtin_bit_cast(bf16x8, w);
      unsigned int z0 = A1[2*kkl][0], t0w = A1[2*kkl+1][0];
      unsigned int z1 = A1[2*kkl][1], t1w = A1[2*kkl+1][1];
      plane_swap(z0, t0w);
      plane_swap(z1, t1w);
      u32x4 w2 = {z0, z1, t0w, t1w};
      pf[2 + kkl] = __builtin_bit_cast(bf16x8, w2);
    }

    // O^T += V^T . P^T ; l-row-sum via ones-MFMA (every C row = sum_t P[q][t])
    const us* VbC = &Vb[cur][0];
    __builtin_amdgcn_s_setprio(1);
#pragma unroll
    for (int kk = 0; kk < 4; kk++){
      bf16x8 av0 = *(const bf16x8*)&VbC[l31 * 72 + kk * 16 + h8];
      bf16x8 av1 = *(const bf16x8*)&VbC[(32 + l31) * 72 + kk * 16 + h8];
      acc0 = __builtin_amdgcn_mfma_f32_32x32x16_bf16(av0, pf[kk], acc0, 0, 0, 0);
      acc1 = __builtin_amdgcn_mfma_f32_32x32x16_bf16(av1, pf[kk], acc1, 0, 0, 0);
      accS = __builtin_amdgcn_mfma_f32_32x32x16_bf16(ones8, pf[kk], accS, 0, 0, 0);
    }
    __builtin_amdgcn_s_setprio(0);

    // stage next tile into the other buffer, then single barrier
    if (pre){
      const int nxt = cur ^ 1;
      *(uint4*)&Kb[nxt][kt0 * 72 + kd0] = rK0;
      *(uint4*)&Kb[nxt][kt1 * 72 + kd1] = rK1;
      *(uint4*)&Vb[nxt][kt0 * 72 + kd0] = rV0;
      *(uint4*)&Vb[nxt][kt1 * 72 + kd1] = rV1;
    }
    __syncthreads();
  }
#undef GK
#undef GV

  float inv = 1.f / accS[0];
  us* op = attno + (size_t)(b * MM + qrow) * 1024 + hd;
#pragma unroll
  for (int g = 0; g < 4; g++){
    bf16x4 w0, w1;
#pragma unroll
    for (int j = 0; j < 4; j++){
      w0[j] = (__bf16)(acc0[4 * g + j] * inv);
      w1[j] = (__bf16)(acc1[4 * g + j] * inv);
    }
    *(u16x4*)&op[8 * g + 4 * hb]      = __builtin_bit_cast(u16x4, w0);
    *(u16x4*)&op[32 + 8 * g + 4 * hb] = __builtin_bit_cast(u16x4, w1);
  }
}

extern "C" void kernel_launch(void* const* d_in, const int* in_sizes, int n_in,
                              void* d_out, int out_size, void* d_ws, size_t ws_size,
                              hipStream_t stream){
  const float* x      = (const float*)d_in[0];
  const float* data   = (const float*)d_in[1];
  const float* W_attn = (const float*)d_in[2];
  const float* b_attn = (const float*)d_in[3];
  const float* W_data = (const float*)d_in[4];
  const float* b_data = (const float*)d_in[5];
  const float* W_proj = (const float*)d_in[6];
  const float* b_proj = (const float*)d_in[7];
  float* out = (float*)d_out;

  char* ws = (char*)d_ws;
  us* xf    = (us*)(ws + 0);             // [2][2048][1024] fp16 (8 MB)
  us* df    = (us*)(ws + 8388608);       // [2][2048][1024] fp16 (8 MB)
  us* Watf  = (us*)(ws + 16777216);      // [3072][1024] fp16 (6 MB)
  us* Wdtf  = (us*)(ws + 23068672);      // [2048][1024] fp16 (4 MB)
  us* Wptb  = (us*)(ws + 27262976);      // [1024][1024] bf16 (2 MB)
  us* Qf    = (us*)(ws + 29360128);      // [2][2048][1024] fp16 (8 MB)
  us* Kf    = (us*)(ws + 37748736);      // [2][4096][1024] fp16 (16 MB)
  us* VT    = (us*)(ws + 54525952);      // [2][1024][4096] bf16 (16 MB)
  us* attno = (us*)(ws + 0);             // alias xf (dead after gemm_all)

  cast_f16_all<<<4096, 256, 0, stream>>>(x, data, xf, df);
  transpose_all<<<dim3(192, 32), 256, 0, stream>>>(W_attn, W_data, W_proj, Watf, Wdtf, Wptb);

  gemm_all<<<dim3(40, 32), 256, 0, stream>>>(xf, df, Watf, Wdtf,
                                             b_attn, b_data, Qf, Kf, VT);

  attn_kernel<<<512, 256, 0, stream>>>(Qf, Kf, VT, attno);

  gemm_proj<<<dim3(8, 32), 256, 0, stream>>>(attno, Wptb, b_proj, out);
}

// Round 12
// 237.259 us; speedup vs baseline: 1.0240x; 1.0240x over previous
//
#include <hip/hip_runtime.h>

typedef __bf16 bf16x8 __attribute__((ext_vector_type(8)));
typedef __bf16 bf16x4 __attribute__((ext_vector_type(4)));
typedef _Float16 f16x8 __attribute__((ext_vector_type(8)));
typedef float f32x4 __attribute__((ext_vector_type(4)));
typedef float f32x16 __attribute__((ext_vector_type(16)));
typedef unsigned short u16x8 __attribute__((ext_vector_type(8)));
typedef unsigned short u16x4 __attribute__((ext_vector_type(4)));
typedef unsigned int u32x4 __attribute__((ext_vector_type(4)));
typedef unsigned short us;

#define MM 2048
#define TT 4096

__device__ __forceinline__ us f2bf(float f){
  unsigned int u = __builtin_bit_cast(unsigned int, f);
  u = (u + 0x7fffu + ((u >> 16) & 1u)) >> 16;
  return (us)u;
}
__device__ __forceinline__ float bf2f(us u){
  unsigned int x = ((unsigned int)u) << 16;
  return __builtin_bit_cast(float, x);
}
__device__ __forceinline__ us f2h(float f){
  _Float16 h = (_Float16)f;
  return __builtin_bit_cast(us, h);
}
__device__ __forceinline__ unsigned int cvt_pk_bf16(float lo, float hi){
  unsigned int r;
  asm("v_cvt_pk_bf16_f32 %0, %1, %2" : "=v"(r) : "v"(lo), "v"(hi));
  return r;
}
__device__ __forceinline__ void plane_swap(unsigned int &x, unsigned int &y){
  asm("v_permlane32_swap_b32 %0, %1" : "+v"(x), "+v"(y));
}
// Schraudolph-style full-rate 2^x (x <= ~+8): 3 full-rate VALU ops.
__device__ __forceinline__ float fast_exp2(float s, float A23, float B23){
  float t = __builtin_fmaf(s, A23, B23);
  t = fmaxf(t, 0.f);                      // underflow -> +0.0 (correct limit)
  return __builtin_bit_cast(float, (int)t);
}

#define GLDS(gp, lp) __builtin_amdgcn_global_load_lds( \
    (const __attribute__((address_space(1))) unsigned int*)(gp), \
    (__attribute__((address_space(3))) unsigned int*)(lp), 16, 0, 0)

// ---------------- fused fp32 -> fp16 cast (x and data in one launch) ----------------
__global__ __launch_bounds__(256) void cast_f16_all(const float* __restrict__ x,
                                                    const float* __restrict__ data,
                                                    us* __restrict__ xf, us* __restrict__ df){
  int bid = blockIdx.x;
  const float* in; us* o;
  if (bid < 2048){ in = x; o = xf; }
  else           { in = data; o = df; bid -= 2048; }
  size_t i = ((size_t)bid * 256 + threadIdx.x) * 8;
  float4 a = *(const float4*)(in + i);
  float4 b = *(const float4*)(in + i + 4);
  float v[8] = {a.x,a.y,a.z,a.w,b.x,b.y,b.z,b.w};
  u16x8 r;
  for (int j = 0; j < 8; j++) r[j] = f2h(v[j]);
  *(u16x8*)(o + i) = r;
}

// ---------------- fused transpose for all three weights (attn/data fp16, proj bf16) ----------------
__global__ __launch_bounds__(256) void transpose_all(const float* __restrict__ W_attn,
                                                     const float* __restrict__ W_data,
                                                     const float* __restrict__ W_proj,
                                                     us* __restrict__ Af, us* __restrict__ Df,
                                                     us* __restrict__ Pb){
  __shared__ float tile[32][33];
  int bx = blockIdx.x;
  const float* W; us* o; int N; bool tobf;
  if (bx < 96){ W = W_attn; o = Af; N = 3072; tobf = false; }
  else if (bx < 160){ W = W_data; o = Df; N = 2048; bx -= 96; tobf = false; }
  else { W = W_proj; o = Pb; N = 1024; bx -= 160; tobf = true; }
  int tx = threadIdx.x & 31, ty = threadIdx.x >> 5;   // 32 x 8
  int n0 = bx * 32, k0 = blockIdx.y * 32;
  for (int r = 0; r < 32; r += 8)
    tile[ty + r][tx] = W[(size_t)(k0 + ty + r) * N + n0 + tx];
  __syncthreads();
  for (int r = 0; r < 32; r += 8){
    float v = tile[tx][ty + r];
    size_t idx = (size_t)(n0 + ty + r) * 1024 + k0 + tx;
    o[idx] = tobf ? f2bf(v) : f2h(v);
  }
}

// ---------------- merged projection GEMM, single-pass fp16 ----------------
__global__ __launch_bounds__(256) void gemm_all(const us* __restrict__ xf, const us* __restrict__ df,
                                                const us* __restrict__ Watf, const us* __restrict__ Wdtf,
                                                const float* __restrict__ b_attn, const float* __restrict__ b_data,
                                                us* __restrict__ Qf, us* __restrict__ Kf,
                                                us* __restrict__ VT){
  __shared__ us sm[8192];  // A@0, B@4096
  const int bx = blockIdx.x;
  const us *Ah, *Bth; const float* bias; int region, kroff, col0;
  if (bx < 24){
    Ah = xf; Bth = Watf; bias = b_attn;
    region = bx >> 3; kroff = 0; col0 = bx * 128;
  } else {
    int b2 = bx - 24;
    Ah = df; Bth = Wdtf; bias = b_data;
    region = 1 + (b2 >> 3); kroff = 2048; col0 = b2 * 128;
  }
  const int tid = threadIdx.x, wid = tid >> 6, lane = tid & 63;
  const int l15 = lane & 15, l16 = lane >> 4;
  const int row0 = blockIdx.y * 128;
  const int wr = (wid >> 1) * 64, wc = (wid & 1) * 64;
  f32x4 acc[4][4] = {};

  for (int k0 = 0; k0 < 1024; k0 += 32){
    for (int c = 0; c < 2; ++c){
      int i = c * 256 + tid;                           // 0..511: row=i>>2, k8=(i&3)*8
      size_t aoff = (size_t)(row0 + (i >> 2)) * 1024 + k0 + (i & 3) * 8;
      size_t boff = (size_t)(col0 + (i >> 2)) * 1024 + k0 + (i & 3) * 8;
      GLDS(Ah + aoff, &sm[c * 2048 + wid * 512]);
      GLDS(Bth + boff, &sm[4096 + c * 2048 + wid * 512]);
    }
    __syncthreads();
    f16x8 af[4], bf[4];
    for (int m = 0; m < 4; m++) af[m] = *(const f16x8*)&sm[(wr + m * 16 + l15) * 32 + l16 * 8];
    for (int n = 0; n < 4; n++) bf[n] = *(const f16x8*)&sm[4096 + (wc + n * 16 + l15) * 32 + l16 * 8];
    for (int m = 0; m < 4; m++)
      for (int n = 0; n < 4; n++)
        acc[m][n] = __builtin_amdgcn_mfma_f32_16x16x32_f16(af[m], bf[n], acc[m][n], 0, 0, 0);
    __syncthreads();
  }

  for (int m = 0; m < 4; m++)
    for (int n = 0; n < 4; n++){
      int gcol = col0 + wc + n * 16 + l15;
      int ocol = gcol & 1023;
      float bv = bias[gcol];
      if (region == 2){                    // V -> VT[b][d][t] bf16, vectorized over 4 rows
        int r = row0 + wr + m * 16 + l16 * 4;
        u16x4 o;
        for (int j = 0; j < 4; j++) o[j] = f2bf(acc[m][n][j] + bv);
        *(u16x4*)&VT[((size_t)((r >> 11) * 1024 + ocol)) * 4096 + kroff + (r & 2047)] = o;
      } else {                             // Q or K -> fp16
        us* P = (region == 0) ? Qf : Kf;
        for (int j = 0; j < 4; j++){
          int r = row0 + wr + m * 16 + l16 * 4 + j;
          size_t orow = (region == 0) ? (size_t)r
                                      : (size_t)((r >> 11) * 4096 + kroff + (r & 2047));
          P[orow * 1024 + ocol] = f2h(acc[m][n][j] + bv);
        }
      }
    }
}

// ---------------- output projection GEMM (bf16, fp32 out) ----------------
__global__ __launch_bounds__(256) void gemm_proj(const us* __restrict__ Ah,
                                                 const us* __restrict__ Bth,
                                                 const float* __restrict__ bias,
                                                 float* __restrict__ Co){
  __shared__ us sm[8192];
  const int tid = threadIdx.x, wid = tid >> 6, lane = tid & 63;
  const int l15 = lane & 15, l16 = lane >> 4;
  const int row0 = blockIdx.y * 128, col0 = blockIdx.x * 128;
  const int wr = (wid >> 1) * 64, wc = (wid & 1) * 64;
  f32x4 acc[4][4] = {};

  for (int k0 = 0; k0 < 1024; k0 += 32){
    for (int c = 0; c < 2; ++c){
      int i = c * 256 + tid;
      size_t aoff = (size_t)(row0 + (i >> 2)) * 1024 + k0 + (i & 3) * 8;
      size_t boff = (size_t)(col0 + (i >> 2)) * 1024 + k0 + (i & 3) * 8;
      GLDS(Ah + aoff, &sm[c * 2048 + wid * 512]);
      GLDS(Bth + boff, &sm[4096 + c * 2048 + wid * 512]);
    }
    __syncthreads();
    bf16x8 afh[4], bfh[4];
    for (int m = 0; m < 4; m++) afh[m] = *(const bf16x8*)&sm[(wr + m * 16 + l15) * 32 + l16 * 8];
    for (int n = 0; n < 4; n++) bfh[n] = *(const bf16x8*)&sm[4096 + (wc + n * 16 + l15) * 32 + l16 * 8];
    for (int m = 0; m < 4; m++)
      for (int n = 0; n < 4; n++)
        acc[m][n] = __builtin_amdgcn_mfma_f32_16x16x32_bf16(afh[m], bfh[n], acc[m][n], 0, 0, 0);
    __syncthreads();
  }

  for (int m = 0; m < 4; m++)
    for (int n = 0; n < 4; n++){
      int col = col0 + wc + n * 16 + l15;
      float bv = bias[col];
      for (int j = 0; j < 4; j++){
        int r = row0 + wr + m * 16 + l16 * 4 + j;
        Co[(size_t)r * 1024 + col] = acc[m][n][j] + bv;
      }
    }
}

// ---------------- fused attention: fp16 Q/K, bf16 V, MFMA row-sum, fast exp2 ----------------
// grid: B*H*(M/128); 4 waves x 32 q-rows. q = lane&31, hb = lane>>5.
// S^T C-layout (m74/m101): reg 4g+j -> t = ts*32 + 8g + 4*hb + j.
// K,V: LDS double-buffered, write-late + 1 barrier/tile.
// P: T12 cvt_pk + v_permlane32_swap. T13 defer-max. l via ones-MFMA.
// exp2 via full-rate Schraudolph bit-trick (quarter-rate v_exp_f32 was ~70% of VALU).
__global__ __launch_bounds__(256) void attn_kernel(const us* __restrict__ Qf,
                                                   const us* __restrict__ Kf,
                                                   const us* __restrict__ VT,
                                                   us* __restrict__ attno){
  __shared__ us Kb[2][64 * 72];        // [dbuf][64 t][72] fp16
  __shared__ us Vb[2][64 * 72];        // [dbuf][64 d][72] bf16 (V^T tile)
  const int tid = threadIdx.x, wid = tid >> 6, lane = tid & 63;
  const int l31 = lane & 31, hb = lane >> 5, h8 = hb * 8;
  const int qt = blockIdx.x & 15;             // M/128 = 16
  const int bh = blockIdx.x >> 4;
  const int hd = (bh & 15) * 64, b = bh >> 4;
  const int qrow = qt * 128 + wid * 32 + l31;

  // Q fragments (B operand): lane holds Q[qrow][d = kk*16 + h8 + i], fp16
  f16x8 qf[4];
  {
    const us* qp = Qf + (size_t)(b * MM + qrow) * 1024 + hd;
#pragma unroll
    for (int kk = 0; kk < 4; kk++)
      qf[kk] = *(const f16x8*)(qp + kk * 16 + h8);
  }

  // all-ones bf16 A-fragment for the l row-sum MFMA
  u16x8 ones_u;
#pragma unroll
  for (int j = 0; j < 8; j++) ones_u[j] = 0x3F80;
  const bf16x8 ones8 = __builtin_bit_cast(bf16x8, ones_u);

  const int i0 = tid, i1 = 256 + tid;
  const int kt0 = i0 >> 3, kd0 = (i0 & 7) * 8;
  const int kt1 = i1 >> 3, kd1 = (i1 & 7) * 8;

#define GK(t0_, t_, d_) (((size_t)(b * TT + (t0_) + (t_))) * 1024 + hd + (d_))
#define GV(t0_, d_, t_) (((size_t)b * 1024 + hd + (d_)) * 4096 + (t0_) + (t_))

  // prologue: stage K,V tile 0 into buf 0
  uint4 rK0 = *(const uint4*)(Kf + GK(0, kt0, kd0));
  uint4 rK1 = *(const uint4*)(Kf + GK(0, kt1, kd1));
  uint4 rV0 = *(const uint4*)(VT + GV(0, kt0, kd0));
  uint4 rV1 = *(const uint4*)(VT + GV(0, kt1, kd1));
  *(uint4*)&Kb[0][kt0 * 72 + kd0] = rK0;
  *(uint4*)&Kb[0][kt1 * 72 + kd1] = rK1;
  *(uint4*)&Vb[0][kt0 * 72 + kd0] = rV0;
  *(uint4*)&Vb[0][kt1 * 72 + kd1] = rV1;
  __syncthreads();

  f32x16 acc0 = {}, acc1 = {}, accS = {};
  float mrow = -1e30f;
  const float cs  = 0.125f * 1.44269504088896f;    // to log2 domain
  const float A23 = cs * 8388608.0f;               // cs * 2^23
  // B23 = (127 - mrow)*2^23 - 250000 (balanced-error correction), updated when mrow changes
  float B23 = 0.f;

  for (int t0 = 0; t0 < TT; t0 += 64){
    const int cur = (t0 >> 6) & 1;
    const bool pre = (t0 + 64 < TT);
    if (pre){
      rK0 = *(const uint4*)(Kf + GK(t0 + 64, kt0, kd0));
      rK1 = *(const uint4*)(Kf + GK(t0 + 64, kt1, kd1));
      rV0 = *(const uint4*)(VT + GV(t0 + 64, kt0, kd0));
      rV1 = *(const uint4*)(VT + GV(t0 + 64, kt1, kd1));
    }

    // S^T = K . Q^T (fp16): frag ts holds t = ts*32 + tloc, q = l31
    const us* KbC = &Kb[cur][0];
    f32x16 sfr0 = {}, sfr1 = {};
    __builtin_amdgcn_s_setprio(1);
#pragma unroll
    for (int kk = 0; kk < 4; kk++){
      f16x8 a0 = *(const f16x8*)&KbC[l31 * 72 + kk * 16 + h8];
      f16x8 a1 = *(const f16x8*)&KbC[(32 + l31) * 72 + kk * 16 + h8];
      sfr0 = __builtin_amdgcn_mfma_f32_32x32x16_f16(a0, qf[kk], sfr0, 0, 0, 0);
      sfr1 = __builtin_amdgcn_mfma_f32_32x32x16_f16(a1, qf[kk], sfr1, 0, 0, 0);
    }
    __builtin_amdgcn_s_setprio(0);

    // tile max via two max3 chains (T17)
    float va = -1e30f, vb2 = -1e30f;
#pragma unroll
    for (int r = 0; r < 16; r += 2){
      va  = fmaxf(fmaxf(sfr0[r],     sfr1[r]),     va);
      vb2 = fmaxf(fmaxf(sfr0[r + 1], sfr1[r + 1]), vb2);
    }
    float v = fmaxf(va, vb2);
    float vs = v * cs;
    vs = fmaxf(vs, __shfl_xor(vs, 32, 64));
    if (!__all(vs <= mrow + 8.f)){      // T13 defer-max
      float mn = fmaxf(mrow, vs);
      float rs = __builtin_amdgcn_exp2f(mrow - mn);
      mrow = mn;
#pragma unroll
      for (int r = 0; r < 16; r++){ acc0[r] *= rs; acc1[r] *= rs; accS[r] *= rs; }
    }
    B23 = __builtin_fmaf(mrow, -8388608.0f, 1065103216.0f);
    unsigned int A0[4][2], A1[4][2];
#pragma unroll
    for (int g = 0; g < 4; g++){
      float e00 = fast_exp2(sfr0[4*g+0], A23, B23);
      float e01 = fast_exp2(sfr0[4*g+1], A23, B23);
      float e02 = fast_exp2(sfr0[4*g+2], A23, B23);
      float e03 = fast_exp2(sfr0[4*g+3], A23, B23);
      float e10 = fast_exp2(sfr1[4*g+0], A23, B23);
      float e11 = fast_exp2(sfr1[4*g+1], A23, B23);
      float e12 = fast_exp2(sfr1[4*g+2], A23, B23);
      float e13 = fast_exp2(sfr1[4*g+3], A23, B23);
      A0[g][0] = cvt_pk_bf16(e00, e01);
      A0[g][1] = cvt_pk_bf16(e02, e03);
      A1[g][0] = cvt_pk_bf16(e10, e11);
      A1[g][1] = cvt_pk_bf16(e12, e13);
    }

    // build P fragments in-register (T12): frag kk = {x'0, x'1, y'0, y'1}
    bf16x8 pf[4];
#pragma unroll
    for (int kkl = 0; kkl < 2; kkl++){
      unsigned int x0 = A0[2*kkl][0], y0 = A0[2*kkl+1][0];
      unsigned int x1 = A0[2*kkl][1], y1 = A0[2*kkl+1][1];
      plane_swap(x0, y0);
      plane_swap(x1, y1);
      u32x4 w = {x0, x1, y0, y1};
      pf[kkl] = __builtin_bit_cast(bf16x8, w);
      unsigned int z0 = A1[2*kkl][0], t0w = A1[2*kkl+1][0];
      unsigned int z1 = A1[2*kkl][1], t1w = A1[2*kkl+1][1];
      plane_swap(z0, t0w);
      plane_swap(z1, t1w);
      u32x4 w2 = {z0, z1, t0w, t1w};
      pf[2 + kkl] = __builtin_bit_cast(bf16x8, w2);
    }

    // O^T += V^T . P^T ; l-row-sum via ones-MFMA
    const us* VbC = &Vb[cur][0];
    __builtin_amdgcn_s_setprio(1);
#pragma unroll
    for (int kk = 0; kk < 4; kk++){
      bf16x8 av0 = *(const bf16x8*)&VbC[l31 * 72 + kk * 16 + h8];
      bf16x8 av1 = *(const bf16x8*)&VbC[(32 + l31) * 72 + kk * 16 + h8];
      acc0 = __builtin_amdgcn_mfma_f32_32x32x16_bf16(av0, pf[kk], acc0, 0, 0, 0);
      acc1 = __builtin_amdgcn_mfma_f32_32x32x16_bf16(av1, pf[kk], acc1, 0, 0, 0);
      accS = __builtin_amdgcn_mfma_f32_32x32x16_bf16(ones8, pf[kk], accS, 0, 0, 0);
    }
    __builtin_amdgcn_s_setprio(0);

    // stage next tile into the other buffer, then single barrier
    if (pre){
      const int nxt = cur ^ 1;
      *(uint4*)&Kb[nxt][kt0 * 72 + kd0] = rK0;
      *(uint4*)&Kb[nxt][kt1 * 72 + kd1] = rK1;
      *(uint4*)&Vb[nxt][kt0 * 72 + kd0] = rV0;
      *(uint4*)&Vb[nxt][kt1 * 72 + kd1] = rV1;
    }
    __syncthreads();
  }
#undef GK
#undef GV

  float inv = 1.f / accS[0];
  us* op = attno + (size_t)(b * MM + qrow) * 1024 + hd;
#pragma unroll
  for (int g = 0; g < 4; g++){
    bf16x4 w0, w1;
#pragma unroll
    for (int j = 0; j < 4; j++){
      w0[j] = (__bf16)(acc0[4 * g + j] * inv);
      w1[j] = (__bf16)(acc1[4 * g + j] * inv);
    }
    *(u16x4*)&op[8 * g + 4 * hb]      = __builtin_bit_cast(u16x4, w0);
    *(u16x4*)&op[32 + 8 * g + 4 * hb] = __builtin_bit_cast(u16x4, w1);
  }
}

extern "C" void kernel_launch(void* const* d_in, const int* in_sizes, int n_in,
                              void* d_out, int out_size, void* d_ws, size_t ws_size,
                              hipStream_t stream){
  const float* x      = (const float*)d_in[0];
  const float* data   = (const float*)d_in[1];
  const float* W_attn = (const float*)d_in[2];
  const float* b_attn = (const float*)d_in[3];
  const float* W_data = (const float*)d_in[4];
  const float* b_data = (const float*)d_in[5];
  const float* W_proj = (const float*)d_in[6];
  const float* b_proj = (const float*)d_in[7];
  float* out = (float*)d_out;

  char* ws = (char*)d_ws;
  us* xf    = (us*)(ws + 0);             // [2][2048][1024] fp16 (8 MB)
  us* df    = (us*)(ws + 8388608);       // [2][2048][1024] fp16 (8 MB)
  us* Watf  = (us*)(ws + 16777216);      // [3072][1024] fp16 (6 MB)
  us* Wdtf  = (us*)(ws + 23068672);      // [2048][1024] fp16 (4 MB)
  us* Wptb  = (us*)(ws + 27262976);      // [1024][1024] bf16 (2 MB)
  us* Qf    = (us*)(ws + 29360128);      // [2][2048][1024] fp16 (8 MB)
  us* Kf    = (us*)(ws + 37748736);      // [2][4096][1024] fp16 (16 MB)
  us* VT    = (us*)(ws + 54525952);      // [2][1024][4096] bf16 (16 MB)
  us* attno = (us*)(ws + 0);             // alias xf (dead after gemm_all)

  cast_f16_all<<<4096, 256, 0, stream>>>(x, data, xf, df);
  transpose_all<<<dim3(192, 32), 256, 0, stream>>>(W_attn, W_data, W_proj, Watf, Wdtf, Wptb);

  gemm_all<<<dim3(40, 32), 256, 0, stream>>>(xf, df, Watf, Wdtf,
                                             b_attn, b_data, Qf, Kf, VT);

  attn_kernel<<<512, 256, 0, stream>>>(Qf, Kf, VT, attno);

  gemm_proj<<<dim3(8, 32), 256, 0, stream>>>(attno, Wptb, b_proj, out);
}

// Round 13
// 228.707 us; speedup vs baseline: 1.0623x; 1.0374x over previous
//
#include <hip/hip_runtime.h>

typedef __bf16 bf16x8 __attribute__((ext_vector_type(8)));
typedef __bf16 bf16x4 __attribute__((ext_vector_type(4)));
typedef _Float16 f16x8 __attribute__((ext_vector_type(8)));
typedef float f32x4 __attribute__((ext_vector_type(4)));
typedef float f32x16 __attribute__((ext_vector_type(16)));
typedef unsigned short u16x8 __attribute__((ext_vector_type(8)));
typedef unsigned short u16x4 __attribute__((ext_vector_type(4)));
typedef unsigned int u32x4 __attribute__((ext_vector_type(4)));
typedef unsigned short us;

#define MM 2048
#define TT 4096

__device__ __forceinline__ us f2bf(float f){
  unsigned int u = __builtin_bit_cast(unsigned int, f);
  u = (u + 0x7fffu + ((u >> 16) & 1u)) >> 16;
  return (us)u;
}
__device__ __forceinline__ float bf2f(us u){
  unsigned int x = ((unsigned int)u) << 16;
  return __builtin_bit_cast(float, x);
}
__device__ __forceinline__ us f2h(float f){
  _Float16 h = (_Float16)f;
  return __builtin_bit_cast(us, h);
}
__device__ __forceinline__ unsigned int cvt_pk_bf16(float lo, float hi){
  unsigned int r;
  asm("v_cvt_pk_bf16_f32 %0, %1, %2" : "=v"(r) : "v"(lo), "v"(hi));
  return r;
}
__device__ __forceinline__ void plane_swap(unsigned int &x, unsigned int &y){
  asm("v_permlane32_swap_b32 %0, %1" : "+v"(x), "+v"(y));
}
// Schraudolph-style full-rate 2^x (x <= ~+8): 3 full-rate VALU ops.
__device__ __forceinline__ float fast_exp2(float s, float A23, float B23){
  float t = __builtin_fmaf(s, A23, B23);
  t = fmaxf(t, 0.f);                      // underflow -> +0.0 (correct limit)
  return __builtin_bit_cast(float, (int)t);
}

#define GLDS(gp, lp) __builtin_amdgcn_global_load_lds( \
    (const __attribute__((address_space(1))) unsigned int*)(gp), \
    (__attribute__((address_space(3))) unsigned int*)(lp), 16, 0, 0)

// ---------------- fused fp32 -> fp16 cast (x and data in one launch) ----------------
__global__ __launch_bounds__(256) void cast_f16_all(const float* __restrict__ x,
                                                    const float* __restrict__ data,
                                                    us* __restrict__ xf, us* __restrict__ df){
  int bid = blockIdx.x;
  const float* in; us* o;
  if (bid < 2048){ in = x; o = xf; }
  else           { in = data; o = df; bid -= 2048; }
  size_t i = ((size_t)bid * 256 + threadIdx.x) * 8;
  float4 a = *(const float4*)(in + i);
  float4 b = *(const float4*)(in + i + 4);
  float v[8] = {a.x,a.y,a.z,a.w,b.x,b.y,b.z,b.w};
  u16x8 r;
  for (int j = 0; j < 8; j++) r[j] = f2h(v[j]);
  *(u16x8*)(o + i) = r;
}

// ---------------- fused transpose for all three weights (attn/data fp16, proj bf16) ----------------
__global__ __launch_bounds__(256) void transpose_all(const float* __restrict__ W_attn,
                                                     const float* __restrict__ W_data,
                                                     const float* __restrict__ W_proj,
                                                     us* __restrict__ Af, us* __restrict__ Df,
                                                     us* __restrict__ Pb){
  __shared__ float tile[32][33];
  int bx = blockIdx.x;
  const float* W; us* o; int N; bool tobf;
  if (bx < 96){ W = W_attn; o = Af; N = 3072; tobf = false; }
  else if (bx < 160){ W = W_data; o = Df; N = 2048; bx -= 96; tobf = false; }
  else { W = W_proj; o = Pb; N = 1024; bx -= 160; tobf = true; }
  int tx = threadIdx.x & 31, ty = threadIdx.x >> 5;   // 32 x 8
  int n0 = bx * 32, k0 = blockIdx.y * 32;
  for (int r = 0; r < 32; r += 8)
    tile[ty + r][tx] = W[(size_t)(k0 + ty + r) * N + n0 + tx];
  __syncthreads();
  for (int r = 0; r < 32; r += 8){
    float v = tile[tx][ty + r];
    size_t idx = (size_t)(n0 + ty + r) * 1024 + k0 + tx;
    o[idx] = tobf ? f2bf(v) : f2h(v);
  }
}

// ---------------- merged projection GEMM, single-pass fp16 ----------------
__global__ __launch_bounds__(256) void gemm_all(const us* __restrict__ xf, const us* __restrict__ df,
                                                const us* __restrict__ Watf, const us* __restrict__ Wdtf,
                                                const float* __restrict__ b_attn, const float* __restrict__ b_data,
                                                us* __restrict__ Qf, us* __restrict__ Kf,
                                                us* __restrict__ VT){
  __shared__ us sm[8192];  // A@0, B@4096
  const int bx = blockIdx.x;
  const us *Ah, *Bth; const float* bias; int region, kroff, col0;
  if (bx < 24){
    Ah = xf; Bth = Watf; bias = b_attn;
    region = bx >> 3; kroff = 0; col0 = bx * 128;
  } else {
    int b2 = bx - 24;
    Ah = df; Bth = Wdtf; bias = b_data;
    region = 1 + (b2 >> 3); kroff = 2048; col0 = b2 * 128;
  }
  const int tid = threadIdx.x, wid = tid >> 6, lane = tid & 63;
  const int l15 = lane & 15, l16 = lane >> 4;
  const int row0 = blockIdx.y * 128;
  const int wr = (wid >> 1) * 64, wc = (wid & 1) * 64;
  f32x4 acc[4][4] = {};

  for (int k0 = 0; k0 < 1024; k0 += 32){
    for (int c = 0; c < 2; ++c){
      int i = c * 256 + tid;                           // 0..511: row=i>>2, k8=(i&3)*8
      size_t aoff = (size_t)(row0 + (i >> 2)) * 1024 + k0 + (i & 3) * 8;
      size_t boff = (size_t)(col0 + (i >> 2)) * 1024 + k0 + (i & 3) * 8;
      GLDS(Ah + aoff, &sm[c * 2048 + wid * 512]);
      GLDS(Bth + boff, &sm[4096 + c * 2048 + wid * 512]);
    }
    __syncthreads();
    f16x8 af[4], bf[4];
    for (int m = 0; m < 4; m++) af[m] = *(const f16x8*)&sm[(wr + m * 16 + l15) * 32 + l16 * 8];
    for (int n = 0; n < 4; n++) bf[n] = *(const f16x8*)&sm[4096 + (wc + n * 16 + l15) * 32 + l16 * 8];
    for (int m = 0; m < 4; m++)
      for (int n = 0; n < 4; n++)
        acc[m][n] = __builtin_amdgcn_mfma_f32_16x16x32_f16(af[m], bf[n], acc[m][n], 0, 0, 0);
    __syncthreads();
  }

  for (int m = 0; m < 4; m++)
    for (int n = 0; n < 4; n++){
      int gcol = col0 + wc + n * 16 + l15;
      int ocol = gcol & 1023;
      float bv = bias[gcol];
      if (region == 2){                    // V -> VT[b][d][t] bf16, vectorized over 4 rows
        int r = row0 + wr + m * 16 + l16 * 4;
        u16x4 o;
        for (int j = 0; j < 4; j++) o[j] = f2bf(acc[m][n][j] + bv);
        *(u16x4*)&VT[((size_t)((r >> 11) * 1024 + ocol)) * 4096 + kroff + (r & 2047)] = o;
      } else {                             // Q or K -> fp16
        us* P = (region == 0) ? Qf : Kf;
        for (int j = 0; j < 4; j++){
          int r = row0 + wr + m * 16 + l16 * 4 + j;
          size_t orow = (region == 0) ? (size_t)r
                                      : (size_t)((r >> 11) * 4096 + kroff + (r & 2047));
          P[orow * 1024 + ocol] = f2h(acc[m][n][j] + bv);
        }
      }
    }
}

// ---------------- output projection GEMM (bf16, fp32 out) ----------------
__global__ __launch_bounds__(256) void gemm_proj(const us* __restrict__ Ah,
                                                 const us* __restrict__ Bth,
                                                 const float* __restrict__ bias,
                                                 float* __restrict__ Co){
  __shared__ us sm[8192];
  const int tid = threadIdx.x, wid = tid >> 6, lane = tid & 63;
  const int l15 = lane & 15, l16 = lane >> 4;
  const int row0 = blockIdx.y * 128, col0 = blockIdx.x * 128;
  const int wr = (wid >> 1) * 64, wc = (wid & 1) * 64;
  f32x4 acc[4][4] = {};

  for (int k0 = 0; k0 < 1024; k0 += 32){
    for (int c = 0; c < 2; ++c){
      int i = c * 256 + tid;
      size_t aoff = (size_t)(row0 + (i >> 2)) * 1024 + k0 + (i & 3) * 8;
      size_t boff = (size_t)(col0 + (i >> 2)) * 1024 + k0 + (i & 3) * 8;
      GLDS(Ah + aoff, &sm[c * 2048 + wid * 512]);
      GLDS(Bth + boff, &sm[4096 + c * 2048 + wid * 512]);
    }
    __syncthreads();
    bf16x8 afh[4], bfh[4];
    for (int m = 0; m < 4; m++) afh[m] = *(const bf16x8*)&sm[(wr + m * 16 + l15) * 32 + l16 * 8];
    for (int n = 0; n < 4; n++) bfh[n] = *(const bf16x8*)&sm[4096 + (wc + n * 16 + l15) * 32 + l16 * 8];
    for (int m = 0; m < 4; m++)
      for (int n = 0; n < 4; n++)
        acc[m][n] = __builtin_amdgcn_mfma_f32_16x16x32_bf16(afh[m], bfh[n], acc[m][n], 0, 0, 0);
    __syncthreads();
  }

  for (int m = 0; m < 4; m++)
    for (int n = 0; n < 4; n++){
      int col = col0 + wc + n * 16 + l15;
      float bv = bias[col];
      for (int j = 0; j < 4; j++){
        int r = row0 + wr + m * 16 + l16 * 4 + j;
        Co[(size_t)r * 1024 + col] = acc[m][n][j] + bv;
      }
    }
}

// ---------------- fused attention, split-T WITH double-buffer (R8 redo, R12 loop kept) ----------------
// grid: 2 T-chunks x B*H*(M/128); 4 waves x 32 q-rows. q = lane&31, hb = lane>>5.
// Each block sweeps 2048 t (32 tiles of 64) with the R12 dbuf 1-barrier loop.
// LDS 36.8 KB x 4 blocks/CU = 147 KB < 160 -> 4 waves/SIMD.
// Writes UNNORMALIZED bf16 partial O + per-(q,h) m (log2 domain) and l.
__global__ __launch_bounds__(256, 4) void attn_kernel(const us* __restrict__ Qf,
                                                      const us* __restrict__ Kf,
                                                      const us* __restrict__ VT,
                                                      us* __restrict__ accP,
                                                      float* __restrict__ Mv, float* __restrict__ Lv){
  __shared__ us Kb[2][64 * 72];        // [dbuf][64 t][72] fp16
  __shared__ us Vb[2][64 * 72];        // [dbuf][64 d][72] bf16 (V^T tile)
  const int tid = threadIdx.x, wid = tid >> 6, lane = tid & 63;
  const int l31 = lane & 31, hb = lane >> 5, h8 = hb * 8;
  const int qt = blockIdx.x & 15;             // M/128 = 16
  const int bh = (blockIdx.x >> 4) & 31;
  const int tch = blockIdx.x >> 9;            // T-chunk 0/1
  const int hd = (bh & 15) * 64, b = bh >> 4;
  const int qrow = qt * 128 + wid * 32 + l31;
  const int tbase = tch * 2048, tend = tbase + 2048;

  // Q fragments (B operand): lane holds Q[qrow][d = kk*16 + h8 + i], fp16
  f16x8 qf[4];
  {
    const us* qp = Qf + (size_t)(b * MM + qrow) * 1024 + hd;
#pragma unroll
    for (int kk = 0; kk < 4; kk++)
      qf[kk] = *(const f16x8*)(qp + kk * 16 + h8);
  }

  // all-ones bf16 A-fragment for the l row-sum MFMA
  u16x8 ones_u;
#pragma unroll
  for (int j = 0; j < 8; j++) ones_u[j] = 0x3F80;
  const bf16x8 ones8 = __builtin_bit_cast(bf16x8, ones_u);

  const int i0 = tid, i1 = 256 + tid;
  const int kt0 = i0 >> 3, kd0 = (i0 & 7) * 8;
  const int kt1 = i1 >> 3, kd1 = (i1 & 7) * 8;

#define GK(t0_, t_, d_) (((size_t)(b * TT + (t0_) + (t_))) * 1024 + hd + (d_))
#define GV(t0_, d_, t_) (((size_t)b * 1024 + hd + (d_)) * 4096 + (t0_) + (t_))

  // prologue: stage K,V tile tbase into buf 0
  uint4 rK0 = *(const uint4*)(Kf + GK(tbase, kt0, kd0));
  uint4 rK1 = *(const uint4*)(Kf + GK(tbase, kt1, kd1));
  uint4 rV0 = *(const uint4*)(VT + GV(tbase, kt0, kd0));
  uint4 rV1 = *(const uint4*)(VT + GV(tbase, kt1, kd1));
  *(uint4*)&Kb[0][kt0 * 72 + kd0] = rK0;
  *(uint4*)&Kb[0][kt1 * 72 + kd1] = rK1;
  *(uint4*)&Vb[0][kt0 * 72 + kd0] = rV0;
  *(uint4*)&Vb[0][kt1 * 72 + kd1] = rV1;
  __syncthreads();

  f32x16 acc0 = {}, acc1 = {}, accS = {};
  float mrow = -1e30f;
  const float cs  = 0.125f * 1.44269504088896f;    // to log2 domain
  const float A23 = cs * 8388608.0f;               // cs * 2^23
  float B23 = 0.f;

  for (int t0 = tbase; t0 < tend; t0 += 64){
    const int cur = (t0 >> 6) & 1;
    const bool pre = (t0 + 64 < tend);
    if (pre){
      rK0 = *(const uint4*)(Kf + GK(t0 + 64, kt0, kd0));
      rK1 = *(const uint4*)(Kf + GK(t0 + 64, kt1, kd1));
      rV0 = *(const uint4*)(VT + GV(t0 + 64, kt0, kd0));
      rV1 = *(const uint4*)(VT + GV(t0 + 64, kt1, kd1));
    }

    // S^T = K . Q^T (fp16): frag ts holds t = ts*32 + tloc, q = l31
    const us* KbC = &Kb[cur][0];
    f32x16 sfr0 = {}, sfr1 = {};
    __builtin_amdgcn_s_setprio(1);
#pragma unroll
    for (int kk = 0; kk < 4; kk++){
      f16x8 a0 = *(const f16x8*)&KbC[l31 * 72 + kk * 16 + h8];
      f16x8 a1 = *(const f16x8*)&KbC[(32 + l31) * 72 + kk * 16 + h8];
      sfr0 = __builtin_amdgcn_mfma_f32_32x32x16_f16(a0, qf[kk], sfr0, 0, 0, 0);
      sfr1 = __builtin_amdgcn_mfma_f32_32x32x16_f16(a1, qf[kk], sfr1, 0, 0, 0);
    }
    __builtin_amdgcn_s_setprio(0);

    // tile max via two max3 chains (T17)
    float va = -1e30f, vb2 = -1e30f;
#pragma unroll
    for (int r = 0; r < 16; r += 2){
      va  = fmaxf(fmaxf(sfr0[r],     sfr1[r]),     va);
      vb2 = fmaxf(fmaxf(sfr0[r + 1], sfr1[r + 1]), vb2);
    }
    float v = fmaxf(va, vb2);
    float vs = v * cs;
    vs = fmaxf(vs, __shfl_xor(vs, 32, 64));
    if (!__all(vs <= mrow + 8.f)){      // T13 defer-max
      float mn = fmaxf(mrow, vs);
      float rs = __builtin_amdgcn_exp2f(mrow - mn);
      mrow = mn;
#pragma unroll
      for (int r = 0; r < 16; r++){ acc0[r] *= rs; acc1[r] *= rs; accS[r] *= rs; }
    }
    B23 = __builtin_fmaf(mrow, -8388608.0f, 1065103216.0f);
    unsigned int A0[4][2], A1[4][2];
#pragma unroll
    for (int g = 0; g < 4; g++){
      float e00 = fast_exp2(sfr0[4*g+0], A23, B23);
      float e01 = fast_exp2(sfr0[4*g+1], A23, B23);
      float e02 = fast_exp2(sfr0[4*g+2], A23, B23);
      float e03 = fast_exp2(sfr0[4*g+3], A23, B23);
      float e10 = fast_exp2(sfr1[4*g+0], A23, B23);
      float e11 = fast_exp2(sfr1[4*g+1], A23, B23);
      float e12 = fast_exp2(sfr1[4*g+2], A23, B23);
      float e13 = fast_exp2(sfr1[4*g+3], A23, B23);
      A0[g][0] = cvt_pk_bf16(e00, e01);
      A0[g][1] = cvt_pk_bf16(e02, e03);
      A1[g][0] = cvt_pk_bf16(e10, e11);
      A1[g][1] = cvt_pk_bf16(e12, e13);
    }

    // build P fragments in-register (T12): frag kk = {x'0, x'1, y'0, y'1}
    bf16x8 pf[4];
#pragma unroll
    for (int kkl = 0; kkl < 2; kkl++){
      unsigned int x0 = A0[2*kkl][0], y0 = A0[2*kkl+1][0];
      unsigned int x1 = A0[2*kkl][1], y1 = A0[2*kkl+1][1];
      plane_swap(x0, y0);
      plane_swap(x1, y1);
      u32x4 w = {x0, x1, y0, y1};
      pf[kkl] = __builtin_bit_cast(bf16x8, w);
      unsigned int z0 = A1[2*kkl][0], t0w = A1[2*kkl+1][0];
      unsigned int z1 = A1[2*kkl][1], t1w = A1[2*kkl+1][1];
      plane_swap(z0, t0w);
      plane_swap(z1, t1w);
      u32x4 w2 = {z0, z1, t0w, t1w};
      pf[2 + kkl] = __builtin_bit_cast(bf16x8, w2);
    }

    // O^T += V^T . P^T ; l-row-sum via ones-MFMA
    const us* VbC = &Vb[cur][0];
    __builtin_amdgcn_s_setprio(1);
#pragma unroll
    for (int kk = 0; kk < 4; kk++){
      bf16x8 av0 = *(const bf16x8*)&VbC[l31 * 72 + kk * 16 + h8];
      bf16x8 av1 = *(const bf16x8*)&VbC[(32 + l31) * 72 + kk * 16 + h8];
      acc0 = __builtin_amdgcn_mfma_f32_32x32x16_bf16(av0, pf[kk], acc0, 0, 0, 0);
      acc1 = __builtin_amdgcn_mfma_f32_32x32x16_bf16(av1, pf[kk], acc1, 0, 0, 0);
      accS = __builtin_amdgcn_mfma_f32_32x32x16_bf16(ones8, pf[kk], accS, 0, 0, 0);
    }
    __builtin_amdgcn_s_setprio(0);

    // stage next tile into the other buffer, then single barrier
    if (pre){
      const int nxt = cur ^ 1;
      *(uint4*)&Kb[nxt][kt0 * 72 + kd0] = rK0;
      *(uint4*)&Kb[nxt][kt1 * 72 + kd1] = rK1;
      *(uint4*)&Vb[nxt][kt0 * 72 + kd0] = rV0;
      *(uint4*)&Vb[nxt][kt1 * 72 + kd1] = rV1;
    }
    __syncthreads();
  }
#undef GK
#undef GV

  // unnormalized partial output + m/l scalars
  us* ap = accP + (size_t)tch * 4194304 + (size_t)(b * MM + qrow) * 1024 + hd;
#pragma unroll
  for (int g = 0; g < 4; g++){
    bf16x4 w0, w1;
#pragma unroll
    for (int j = 0; j < 4; j++){
      w0[j] = (__bf16)acc0[4 * g + j];
      w1[j] = (__bf16)acc1[4 * g + j];
    }
    *(u16x4*)&ap[8 * g + 4 * hb]      = __builtin_bit_cast(u16x4, w0);
    *(u16x4*)&ap[32 + 8 * g + 4 * hb] = __builtin_bit_cast(u16x4, w1);
  }
  if (hb == 0){
    int idx = tch * 65536 + (b * MM + qrow) * 16 + (hd >> 6);
    Mv[idx] = mrow;
    Lv[idx] = accS[0];
  }
}

// ---------------- combine the two T-chunk partials ----------------
__global__ __launch_bounds__(256) void combine_kernel(const us* __restrict__ accP,
                                                      const float* __restrict__ Mv,
                                                      const float* __restrict__ Lv,
                                                      us* __restrict__ attno){
  size_t i = ((size_t)blockIdx.x * 256 + threadIdx.x) * 8;
  size_t qg = i >> 10;
  int h = (int)((i & 1023) >> 6);
  size_t mi = qg * 16 + h;
  float m1 = Mv[mi], m2 = Mv[65536 + mi];
  float l1 = Lv[mi], l2 = Lv[65536 + mi];
  float m = fmaxf(m1, m2);
  float w1 = __builtin_amdgcn_exp2f(m1 - m);
  float w2 = __builtin_amdgcn_exp2f(m2 - m);
  float inv = 1.f / (w1 * l1 + w2 * l2);
  float s1 = w1 * inv, s2 = w2 * inv;
  u16x8 a1 = *(const u16x8*)(accP + i);
  u16x8 a2 = *(const u16x8*)(accP + 4194304 + i);
  u16x8 o;
#pragma unroll
  for (int j = 0; j < 8; j++)
    o[j] = f2bf(s1 * bf2f(a1[j]) + s2 * bf2f(a2[j]));
  *(u16x8*)(attno + i) = o;
}

extern "C" void kernel_launch(void* const* d_in, const int* in_sizes, int n_in,
                              void* d_out, int out_size, void* d_ws, size_t ws_size,
                              hipStream_t stream){
  const float* x      = (const float*)d_in[0];
  const float* data   = (const float*)d_in[1];
  const float* W_attn = (const float*)d_in[2];
  const float* b_attn = (const float*)d_in[3];
  const float* W_data = (const float*)d_in[4];
  const float* b_data = (const float*)d_in[5];
  const float* W_proj = (const float*)d_in[6];
  const float* b_proj = (const float*)d_in[7];
  float* out = (float*)d_out;

  char* ws = (char*)d_ws;
  us* xf    = (us*)(ws + 0);             // [2][2048][1024] fp16 (8 MB)
  us* df    = (us*)(ws + 8388608);       // [2][2048][1024] fp16 (8 MB)
  us* Watf  = (us*)(ws + 16777216);      // [3072][1024] fp16 (6 MB)
  us* Wdtf  = (us*)(ws + 23068672);      // [2048][1024] fp16 (4 MB)
  us* Wptb  = (us*)(ws + 27262976);      // [1024][1024] bf16 (2 MB)
  us* Qf    = (us*)(ws + 29360128);      // [2][2048][1024] fp16 (8 MB)
  us* Kf    = (us*)(ws + 37748736);      // [2][4096][1024] fp16 (16 MB)
  us* VT    = (us*)(ws + 54525952);      // [2][1024][4096] bf16 (16 MB)
  us* accP  = (us*)(ws + 71303168);      // 2 x [2][2048][1024] bf16 partials (16 MB)
  float* Mv = (float*)(ws + 88080384);   // 2 x 64K floats (512 KB)
  float* Lv = (float*)(ws + 88604672);   // 2 x 64K floats (512 KB)
  us* attno = (us*)(ws + 0);             // alias xf (dead after gemm_all)

  cast_f16_all<<<4096, 256, 0, stream>>>(x, data, xf, df);
  transpose_all<<<dim3(192, 32), 256, 0, stream>>>(W_attn, W_data, W_proj, Watf, Wdtf, Wptb);

  gemm_all<<<dim3(40, 32), 256, 0, stream>>>(xf, df, Watf, Wdtf,
                                             b_attn, b_data, Qf, Kf, VT);

  attn_kernel<<<1024, 256, 0, stream>>>(Qf, Kf, VT, accP, Mv, Lv);
  combine_kernel<<<2048, 256, 0, stream>>>(accP, Mv, Lv, attno);

  gemm_proj<<<dim3(8, 32), 256, 0, stream>>>(attno, Wptb, b_proj, out);
}

// Round 14
// 227.550 us; speedup vs baseline: 1.0677x; 1.0051x over previous
//
#include <hip/hip_runtime.h>

typedef __bf16 bf16x8 __attribute__((ext_vector_type(8)));
typedef __bf16 bf16x4 __attribute__((ext_vector_type(4)));
typedef _Float16 f16x8 __attribute__((ext_vector_type(8)));
typedef float f32x4 __attribute__((ext_vector_type(4)));
typedef float f32x16 __attribute__((ext_vector_type(16)));
typedef unsigned short u16x8 __attribute__((ext_vector_type(8)));
typedef unsigned short u16x4 __attribute__((ext_vector_type(4)));
typedef unsigned int u32x4 __attribute__((ext_vector_type(4)));
typedef unsigned short us;

#define MM 2048
#define TT 4096

__device__ __forceinline__ us f2bf(float f){
  unsigned int u = __builtin_bit_cast(unsigned int, f);
  u = (u + 0x7fffu + ((u >> 16) & 1u)) >> 16;
  return (us)u;
}
__device__ __forceinline__ float bf2f(us u){
  unsigned int x = ((unsigned int)u) << 16;
  return __builtin_bit_cast(float, x);
}
__device__ __forceinline__ us f2h(float f){
  _Float16 h = (_Float16)f;
  return __builtin_bit_cast(us, h);
}
__device__ __forceinline__ unsigned int cvt_pk_bf16(float lo, float hi){
  unsigned int r;
  asm("v_cvt_pk_bf16_f32 %0, %1, %2" : "=v"(r) : "v"(lo), "v"(hi));
  return r;
}
__device__ __forceinline__ void plane_swap(unsigned int &x, unsigned int &y){
  asm("v_permlane32_swap_b32 %0, %1" : "+v"(x), "+v"(y));
}
// Schraudolph 2^x, 2 full-rate VALU ops: fma + saturating cvt (neg -> 0 -> +0.0f).
__device__ __forceinline__ float fast_exp2(float s, float A23, float B23){
  float t = __builtin_fmaf(s, A23, B23);
  unsigned int u;
  asm("v_cvt_u32_f32 %0, %1" : "=v"(u) : "v"(t));
  return __builtin_bit_cast(float, u);
}

#define GLDS(gp, lp) __builtin_amdgcn_global_load_lds( \
    (const __attribute__((address_space(1))) unsigned int*)(gp), \
    (__attribute__((address_space(3))) unsigned int*)(lp), 16, 0, 0)

// ---------------- fused fp32 -> fp16 cast (x and data in one launch) ----------------
__global__ __launch_bounds__(256) void cast_f16_all(const float* __restrict__ x,
                                                    const float* __restrict__ data,
                                                    us* __restrict__ xf, us* __restrict__ df){
  int bid = blockIdx.x;
  const float* in; us* o;
  if (bid < 2048){ in = x; o = xf; }
  else           { in = data; o = df; bid -= 2048; }
  size_t i = ((size_t)bid * 256 + threadIdx.x) * 8;
  float4 a = *(const float4*)(in + i);
  float4 b = *(const float4*)(in + i + 4);
  float v[8] = {a.x,a.y,a.z,a.w,b.x,b.y,b.z,b.w};
  u16x8 r;
  for (int j = 0; j < 8; j++) r[j] = f2h(v[j]);
  *(u16x8*)(o + i) = r;
}

// ---------------- fused transpose for all three weights (attn/data fp16, proj bf16) ----------------
__global__ __launch_bounds__(256) void transpose_all(const float* __restrict__ W_attn,
                                                     const float* __restrict__ W_data,
                                                     const float* __restrict__ W_proj,
                                                     us* __restrict__ Af, us* __restrict__ Df,
                                                     us* __restrict__ Pb){
  __shared__ float tile[32][33];
  int bx = blockIdx.x;
  const float* W; us* o; int N; bool tobf;
  if (bx < 96){ W = W_attn; o = Af; N = 3072; tobf = false; }
  else if (bx < 160){ W = W_data; o = Df; N = 2048; bx -= 96; tobf = false; }
  else { W = W_proj; o = Pb; N = 1024; bx -= 160; tobf = true; }
  int tx = threadIdx.x & 31, ty = threadIdx.x >> 5;   // 32 x 8
  int n0 = bx * 32, k0 = blockIdx.y * 32;
  for (int r = 0; r < 32; r += 8)
    tile[ty + r][tx] = W[(size_t)(k0 + ty + r) * N + n0 + tx];
  __syncthreads();
  for (int r = 0; r < 32; r += 8){
    float v = tile[tx][ty + r];
    size_t idx = (size_t)(n0 + ty + r) * 1024 + k0 + tx;
    o[idx] = tobf ? f2bf(v) : f2h(v);
  }
}

// ---------------- merged projection GEMM, single-pass fp16, XCD-swizzled (T1) ----------------
// work id swz (bijective, nwg=1280=8*160): XCD i runs contiguous work [i*160,(i+1)*160)
// = 4 full row-panels x 40 cols -> A panels L2-resident per XCD.
__global__ __launch_bounds__(256) void gemm_all(const us* __restrict__ xf, const us* __restrict__ df,
                                                const us* __restrict__ Watf, const us* __restrict__ Wdtf,
                                                const float* __restrict__ b_attn, const float* __restrict__ b_data,
                                                us* __restrict__ Qf, us* __restrict__ Kf,
                                                us* __restrict__ VT){
  __shared__ us sm[8192];  // A@0, B@4096
  const int lin = blockIdx.y * 40 + blockIdx.x;
  const int swz = (lin & 7) * 160 + (lin >> 3);
  const int bx = swz % 40;
  const int row0 = (swz / 40) * 128;
  const us *Ah, *Bth; const float* bias; int region, kroff, col0;
  if (bx < 24){
    Ah = xf; Bth = Watf; bias = b_attn;
    region = bx >> 3; kroff = 0; col0 = bx * 128;
  } else {
    int b2 = bx - 24;
    Ah = df; Bth = Wdtf; bias = b_data;
    region = 1 + (b2 >> 3); kroff = 2048; col0 = b2 * 128;
  }
  const int tid = threadIdx.x, wid = tid >> 6, lane = tid & 63;
  const int l15 = lane & 15, l16 = lane >> 4;
  const int wr = (wid >> 1) * 64, wc = (wid & 1) * 64;
  f32x4 acc[4][4] = {};

  for (int k0 = 0; k0 < 1024; k0 += 32){
    for (int c = 0; c < 2; ++c){
      int i = c * 256 + tid;                           // 0..511: row=i>>2, k8=(i&3)*8
      size_t aoff = (size_t)(row0 + (i >> 2)) * 1024 + k0 + (i & 3) * 8;
      size_t boff = (size_t)(col0 + (i >> 2)) * 1024 + k0 + (i & 3) * 8;
      GLDS(Ah + aoff, &sm[c * 2048 + wid * 512]);
      GLDS(Bth + boff, &sm[4096 + c * 2048 + wid * 512]);
    }
    __syncthreads();
    f16x8 af[4], bf[4];
    for (int m = 0; m < 4; m++) af[m] = *(const f16x8*)&sm[(wr + m * 16 + l15) * 32 + l16 * 8];
    for (int n = 0; n < 4; n++) bf[n] = *(const f16x8*)&sm[4096 + (wc + n * 16 + l15) * 32 + l16 * 8];
    for (int m = 0; m < 4; m++)
      for (int n = 0; n < 4; n++)
        acc[m][n] = __builtin_amdgcn_mfma_f32_16x16x32_f16(af[m], bf[n], acc[m][n], 0, 0, 0);
    __syncthreads();
  }

  for (int m = 0; m < 4; m++)
    for (int n = 0; n < 4; n++){
      int gcol = col0 + wc + n * 16 + l15;
      int ocol = gcol & 1023;
      float bv = bias[gcol];
      if (region == 2){                    // V -> VT[b][d][t] bf16, vectorized over 4 rows
        int r = row0 + wr + m * 16 + l16 * 4;
        u16x4 o;
        for (int j = 0; j < 4; j++) o[j] = f2bf(acc[m][n][j] + bv);
        *(u16x4*)&VT[((size_t)((r >> 11) * 1024 + ocol)) * 4096 + kroff + (r & 2047)] = o;
      } else {                             // Q or K -> fp16
        us* P = (region == 0) ? Qf : Kf;
        for (int j = 0; j < 4; j++){
          int r = row0 + wr + m * 16 + l16 * 4 + j;
          size_t orow = (region == 0) ? (size_t)r
                                      : (size_t)((r >> 11) * 4096 + kroff + (r & 2047));
          P[orow * 1024 + ocol] = f2h(acc[m][n][j] + bv);
        }
      }
    }
}

// ---------------- output projection GEMM (bf16, fp32 out) ----------------
__global__ __launch_bounds__(256) void gemm_proj(const us* __restrict__ Ah,
                                                 const us* __restrict__ Bth,
                                                 const float* __restrict__ bias,
                                                 float* __restrict__ Co){
  __shared__ us sm[8192];
  const int tid = threadIdx.x, wid = tid >> 6, lane = tid & 63;
  const int l15 = lane & 15, l16 = lane >> 4;
  const int row0 = blockIdx.y * 128, col0 = blockIdx.x * 128;
  const int wr = (wid >> 1) * 64, wc = (wid & 1) * 64;
  f32x4 acc[4][4] = {};

  for (int k0 = 0; k0 < 1024; k0 += 32){
    for (int c = 0; c < 2; ++c){
      int i = c * 256 + tid;
      size_t aoff = (size_t)(row0 + (i >> 2)) * 1024 + k0 + (i & 3) * 8;
      size_t boff = (size_t)(col0 + (i >> 2)) * 1024 + k0 + (i & 3) * 8;
      GLDS(Ah + aoff, &sm[c * 2048 + wid * 512]);
      GLDS(Bth + boff, &sm[4096 + c * 2048 + wid * 512]);
    }
    __syncthreads();
    bf16x8 afh[4], bfh[4];
    for (int m = 0; m < 4; m++) afh[m] = *(const bf16x8*)&sm[(wr + m * 16 + l15) * 32 + l16 * 8];
    for (int n = 0; n < 4; n++) bfh[n] = *(const bf16x8*)&sm[4096 + (wc + n * 16 + l15) * 32 + l16 * 8];
    for (int m = 0; m < 4; m++)
      for (int n = 0; n < 4; n++)
        acc[m][n] = __builtin_amdgcn_mfma_f32_16x16x32_bf16(afh[m], bfh[n], acc[m][n], 0, 0, 0);
    __syncthreads();
  }

  for (int m = 0; m < 4; m++)
    for (int n = 0; n < 4; n++){
      int col = col0 + wc + n * 16 + l15;
      float bv = bias[col];
      for (int j = 0; j < 4; j++){
        int r = row0 + wr + m * 16 + l16 * 4 + j;
        Co[(size_t)r * 1024 + col] = acc[m][n][j] + bv;
      }
    }
}

// ---------------- fused attention, split-T + dbuf (R13) + VALU shave (R14) ----------------
// grid: 2 T-chunks x B*H*(M/128); 4 waves x 32 q-rows. q = lane&31, hb = lane>>5.
// LDS 36.8 KB x 4 blocks/CU -> 4 waves/SIMD. 2-op fast_exp2; prefetch ptrs strength-reduced;
// B23 recompute hoisted into (tile-0-always-taken) defer-max branch.
__global__ __launch_bounds__(256, 4) void attn_kernel(const us* __restrict__ Qf,
                                                      const us* __restrict__ Kf,
                                                      const us* __restrict__ VT,
                                                      us* __restrict__ accP,
                                                      float* __restrict__ Mv, float* __restrict__ Lv){
  __shared__ us Kb[2][64 * 72];        // [dbuf][64 t][72] fp16
  __shared__ us Vb[2][64 * 72];        // [dbuf][64 d][72] bf16 (V^T tile)
  const int tid = threadIdx.x, wid = tid >> 6, lane = tid & 63;
  const int l31 = lane & 31, hb = lane >> 5, h8 = hb * 8;
  const int qt = blockIdx.x & 15;             // M/128 = 16
  const int bh = (blockIdx.x >> 4) & 31;
  const int tch = blockIdx.x >> 9;            // T-chunk 0/1
  const int hd = (bh & 15) * 64, b = bh >> 4;
  const int qrow = qt * 128 + wid * 32 + l31;
  const int tbase = tch * 2048, tend = tbase + 2048;

  // Q fragments (B operand): lane holds Q[qrow][d = kk*16 + h8 + i], fp16
  f16x8 qf[4];
  {
    const us* qp = Qf + (size_t)(b * MM + qrow) * 1024 + hd;
#pragma unroll
    for (int kk = 0; kk < 4; kk++)
      qf[kk] = *(const f16x8*)(qp + kk * 16 + h8);
  }

  // all-ones bf16 A-fragment for the l row-sum MFMA
  u16x8 ones_u;
#pragma unroll
  for (int j = 0; j < 8; j++) ones_u[j] = 0x3F80;
  const bf16x8 ones8 = __builtin_bit_cast(bf16x8, ones_u);

  const int i0 = tid, i1 = 256 + tid;
  const int kt0 = i0 >> 3, kd0 = (i0 & 7) * 8;
  const int kt1 = i1 >> 3, kd1 = (i1 & 7) * 8;

#define GK(t0_, t_, d_) (((size_t)(b * TT + (t0_) + (t_))) * 1024 + hd + (d_))
#define GV(t0_, d_, t_) (((size_t)b * 1024 + hd + (d_)) * 4096 + (t0_) + (t_))

  // prologue: stage K,V tile tbase into buf 0
  uint4 rK0 = *(const uint4*)(Kf + GK(tbase, kt0, kd0));
  uint4 rK1 = *(const uint4*)(Kf + GK(tbase, kt1, kd1));
  uint4 rV0 = *(const uint4*)(VT + GV(tbase, kt0, kd0));
  uint4 rV1 = *(const uint4*)(VT + GV(tbase, kt1, kd1));
  *(uint4*)&Kb[0][kt0 * 72 + kd0] = rK0;
  *(uint4*)&Kb[0][kt1 * 72 + kd1] = rK1;
  *(uint4*)&Vb[0][kt0 * 72 + kd0] = rV0;
  *(uint4*)&Vb[0][kt1 * 72 + kd1] = rV1;
  __syncthreads();

  // strength-reduced prefetch pointers (next tile)
  const us* pK0 = Kf + GK(tbase + 64, kt0, kd0);
  const us* pK1 = Kf + GK(tbase + 64, kt1, kd1);
  const us* pV0 = VT + GV(tbase + 64, kt0, kd0);
  const us* pV1 = VT + GV(tbase + 64, kt1, kd1);

  f32x16 acc0 = {}, acc1 = {}, accS = {};
  float mrow = -1e30f;
  const float cs  = 0.125f * 1.44269504088896f;    // to log2 domain
  const float A23 = cs * 8388608.0f;               // cs * 2^23
  float B23 = 0.f;                                 // set on first defer-max trigger (tile 0)

  for (int t0 = tbase; t0 < tend; t0 += 64){
    const int cur = (t0 >> 6) & 1;
    const bool pre = (t0 + 64 < tend);
    if (pre){
      rK0 = *(const uint4*)pK0; pK0 += 64 * 1024;
      rK1 = *(const uint4*)pK1; pK1 += 64 * 1024;
      rV0 = *(const uint4*)pV0; pV0 += 64;
      rV1 = *(const uint4*)pV1; pV1 += 64;
    }

    // S^T = K . Q^T (fp16): frag ts holds t = ts*32 + tloc, q = l31
    const us* KbC = &Kb[cur][0];
    f32x16 sfr0 = {}, sfr1 = {};
    __builtin_amdgcn_s_setprio(1);
#pragma unroll
    for (int kk = 0; kk < 4; kk++){
      f16x8 a0 = *(const f16x8*)&KbC[l31 * 72 + kk * 16 + h8];
      f16x8 a1 = *(const f16x8*)&KbC[(32 + l31) * 72 + kk * 16 + h8];
      sfr0 = __builtin_amdgcn_mfma_f32_32x32x16_f16(a0, qf[kk], sfr0, 0, 0, 0);
      sfr1 = __builtin_amdgcn_mfma_f32_32x32x16_f16(a1, qf[kk], sfr1, 0, 0, 0);
    }
    __builtin_amdgcn_s_setprio(0);

    // tile max via two max3 chains (T17)
    float va = -1e30f, vb2 = -1e30f;
#pragma unroll
    for (int r = 0; r < 16; r += 2){
      va  = fmaxf(fmaxf(sfr0[r],     sfr1[r]),     va);
      vb2 = fmaxf(fmaxf(sfr0[r + 1], sfr1[r + 1]), vb2);
    }
    float v = fmaxf(va, vb2);
    float vs = v * cs;
    vs = fmaxf(vs, __shfl_xor(vs, 32, 64));
    if (!__all(vs <= mrow + 8.f)){      // T13 defer-max (always taken on tile 0)
      float mn = fmaxf(mrow, vs);
      float rs = __builtin_amdgcn_exp2f(mrow - mn);
      mrow = mn;
      B23 = __builtin_fmaf(mrow, -8388608.0f, 1065103216.0f);
#pragma unroll
      for (int r = 0; r < 16; r++){ acc0[r] *= rs; acc1[r] *= rs; accS[r] *= rs; }
    }
    unsigned int A0[4][2], A1[4][2];
#pragma unroll
    for (int g = 0; g < 4; g++){
      float e00 = fast_exp2(sfr0[4*g+0], A23, B23);
      float e01 = fast_exp2(sfr0[4*g+1], A23, B23);
      float e02 = fast_exp2(sfr0[4*g+2], A23, B23);
      float e03 = fast_exp2(sfr0[4*g+3], A23, B23);
      float e10 = fast_exp2(sfr1[4*g+0], A23, B23);
      float e11 = fast_exp2(sfr1[4*g+1], A23, B23);
      float e12 = fast_exp2(sfr1[4*g+2], A23, B23);
      float e13 = fast_exp2(sfr1[4*g+3], A23, B23);
      A0[g][0] = cvt_pk_bf16(e00, e01);
      A0[g][1] = cvt_pk_bf16(e02, e03);
      A1[g][0] = cvt_pk_bf16(e10, e11);
      A1[g][1] = cvt_pk_bf16(e12, e13);
    }

    // build P fragments in-register (T12): frag kk = {x'0, x'1, y'0, y'1}
    bf16x8 pf[4];
#pragma unroll
    for (int kkl = 0; kkl < 2; kkl++){
      unsigned int x0 = A0[2*kkl][0], y0 = A0[2*kkl+1][0];
      unsigned int x1 = A0[2*kkl][1], y1 = A0[2*kkl+1][1];
      plane_swap(x0, y0);
      plane_swap(x1, y1);
      u32x4 w = {x0, x1, y0, y1};
      pf[kkl] = __builtin_bit_cast(bf16x8, w);
      unsigned int z0 = A1[2*kkl][0], t0w = A1[2*kkl+1][0];
      unsigned int z1 = A1[2*kkl][1], t1w = A1[2*kkl+1][1];
      plane_swap(z0, t0w);
      plane_swap(z1, t1w);
      u32x4 w2 = {z0, z1, t0w, t1w};
      pf[2 + kkl] = __builtin_bit_cast(bf16x8, w2);
    }

    // O^T += V^T . P^T ; l-row-sum via ones-MFMA
    const us* VbC = &Vb[cur][0];
    __builtin_amdgcn_s_setprio(1);
#pragma unroll
    for (int kk = 0; kk < 4; kk++){
      bf16x8 av0 = *(const bf16x8*)&VbC[l31 * 72 + kk * 16 + h8];
      bf16x8 av1 = *(const bf16x8*)&VbC[(32 + l31) * 72 + kk * 16 + h8];
      acc0 = __builtin_amdgcn_mfma_f32_32x32x16_bf16(av0, pf[kk], acc0, 0, 0, 0);
      acc1 = __builtin_amdgcn_mfma_f32_32x32x16_bf16(av1, pf[kk], acc1, 0, 0, 0);
      accS = __builtin_amdgcn_mfma_f32_32x32x16_bf16(ones8, pf[kk], accS, 0, 0, 0);
    }
    __builtin_amdgcn_s_setprio(0);

    // stage next tile into the other buffer, then single barrier
    if (pre){
      const int nxt = cur ^ 1;
      *(uint4*)&Kb[nxt][kt0 * 72 + kd0] = rK0;
      *(uint4*)&Kb[nxt][kt1 * 72 + kd1] = rK1;
      *(uint4*)&Vb[nxt][kt0 * 72 + kd0] = rV0;
      *(uint4*)&Vb[nxt][kt1 * 72 + kd1] = rV1;
    }
    __syncthreads();
  }
#undef GK
#undef GV

  // unnormalized partial output + m/l scalars
  us* ap = accP + (size_t)tch * 4194304 + (size_t)(b * MM + qrow) * 1024 + hd;
#pragma unroll
  for (int g = 0; g < 4; g++){
    bf16x4 w0, w1;
#pragma unroll
    for (int j = 0; j < 4; j++){
      w0[j] = (__bf16)acc0[4 * g + j];
      w1[j] = (__bf16)acc1[4 * g + j];
    }
    *(u16x4*)&ap[8 * g + 4 * hb]      = __builtin_bit_cast(u16x4, w0);
    *(u16x4*)&ap[32 + 8 * g + 4 * hb] = __builtin_bit_cast(u16x4, w1);
  }
  if (hb == 0){
    int idx = tch * 65536 + (b * MM + qrow) * 16 + (hd >> 6);
    Mv[idx] = mrow;
    Lv[idx] = accS[0];
  }
}

// ---------------- combine the two T-chunk partials ----------------
__global__ __launch_bounds__(256) void combine_kernel(const us* __restrict__ accP,
                                                      const float* __restrict__ Mv,
                                                      const float* __restrict__ Lv,
                                                      us* __restrict__ attno){
  size_t i = ((size_t)blockIdx.x * 256 + threadIdx.x) * 8;
  size_t qg = i >> 10;
  int h = (int)((i & 1023) >> 6);
  size_t mi = qg * 16 + h;
  float m1 = Mv[mi], m2 = Mv[65536 + mi];
  float l1 = Lv[mi], l2 = Lv[65536 + mi];
  float m = fmaxf(m1, m2);
  float w1 = __builtin_amdgcn_exp2f(m1 - m);
  float w2 = __builtin_amdgcn_exp2f(m2 - m);
  float inv = 1.f / (w1 * l1 + w2 * l2);
  float s1 = w1 * inv, s2 = w2 * inv;
  u16x8 a1 = *(const u16x8*)(accP + i);
  u16x8 a2 = *(const u16x8*)(accP + 4194304 + i);
  u16x8 o;
#pragma unroll
  for (int j = 0; j < 8; j++)
    o[j] = f2bf(s1 * bf2f(a1[j]) + s2 * bf2f(a2[j]));
  *(u16x8*)(attno + i) = o;
}

extern "C" void kernel_launch(void* const* d_in, const int* in_sizes, int n_in,
                              void* d_out, int out_size, void* d_ws, size_t ws_size,
                              hipStream_t stream){
  const float* x      = (const float*)d_in[0];
  const float* data   = (const float*)d_in[1];
  const float* W_attn = (const float*)d_in[2];
  const float* b_attn = (const float*)d_in[3];
  const float* W_data = (const float*)d_in[4];
  const float* b_data = (const float*)d_in[5];
  const float* W_proj = (const float*)d_in[6];
  const float* b_proj = (const float*)d_in[7];
  float* out = (float*)d_out;

  char* ws = (char*)d_ws;
  us* xf    = (us*)(ws + 0);             // [2][2048][1024] fp16 (8 MB)
  us* df    = (us*)(ws + 8388608);       // [2][2048][1024] fp16 (8 MB)
  us* Watf  = (us*)(ws + 16777216);      // [3072][1024] fp16 (6 MB)
  us* Wdtf  = (us*)(ws + 23068672);      // [2048][1024] fp16 (4 MB)
  us* Wptb  = (us*)(ws + 27262976);      // [1024][1024] bf16 (2 MB)
  us* Qf    = (us*)(ws + 29360128);      // [2][2048][1024] fp16 (8 MB)
  us* Kf    = (us*)(ws + 37748736);      // [2][4096][1024] fp16 (16 MB)
  us* VT    = (us*)(ws + 54525952);      // [2][1024][4096] bf16 (16 MB)
  us* accP  = (us*)(ws + 71303168);      // 2 x [2][2048][1024] bf16 partials (16 MB)
  float* Mv = (float*)(ws + 88080384);   // 2 x 64K floats (512 KB)
  float* Lv = (float*)(ws + 88604672);   // 2 x 64K floats (512 KB)
  us* attno = (us*)(ws + 0);             // alias xf (dead after gemm_all)

  cast_f16_all<<<4096, 256, 0, stream>>>(x, data, xf, df);
  transpose_all<<<dim3(192, 32), 256, 0, stream>>>(W_attn, W_data, W_proj, Watf, Wdtf, Wptb);

  gemm_all<<<dim3(40, 32), 256, 0, stream>>>(xf, df, Watf, Wdtf,
                                             b_attn, b_data, Qf, Kf, VT);

  attn_kernel<<<1024, 256, 0, stream>>>(Qf, Kf, VT, accP, Mv, Lv);
  combine_kernel<<<2048, 256, 0, stream>>>(accP, Mv, Lv, attno);

  gemm_proj<<<dim3(8, 32), 256, 0, stream>>>(attno, Wptb, b_proj, out);
}

// Round 15
// 224.679 us; speedup vs baseline: 1.0813x; 1.0128x over previous
//
#include <hip/hip_runtime.h>

typedef __bf16 bf16x8 __attribute__((ext_vector_type(8)));
typedef __bf16 bf16x4 __attribute__((ext_vector_type(4)));
typedef _Float16 f16x8 __attribute__((ext_vector_type(8)));
typedef float f32x4 __attribute__((ext_vector_type(4)));
typedef float f32x16 __attribute__((ext_vector_type(16)));
typedef unsigned short u16x8 __attribute__((ext_vector_type(8)));
typedef unsigned short u16x4 __attribute__((ext_vector_type(4)));
typedef unsigned int u32x4 __attribute__((ext_vector_type(4)));
typedef unsigned short us;

#define MM 2048
#define TT 4096

__device__ __forceinline__ us f2bf(float f){
  unsigned int u = __builtin_bit_cast(unsigned int, f);
  u = (u + 0x7fffu + ((u >> 16) & 1u)) >> 16;
  return (us)u;
}
__device__ __forceinline__ float bf2f(us u){
  unsigned int x = ((unsigned int)u) << 16;
  return __builtin_bit_cast(float, x);
}
__device__ __forceinline__ us f2h(float f){
  _Float16 h = (_Float16)f;
  return __builtin_bit_cast(us, h);
}
__device__ __forceinline__ unsigned int cvt_pk_bf16(float lo, float hi){
  unsigned int r;
  asm("v_cvt_pk_bf16_f32 %0, %1, %2" : "=v"(r) : "v"(lo), "v"(hi));
  return r;
}
__device__ __forceinline__ void plane_swap(unsigned int &x, unsigned int &y){
  asm("v_permlane32_swap_b32 %0, %1" : "+v"(x), "+v"(y));
}
// Schraudolph 2^x, 2 full-rate VALU ops: fma + saturating cvt (neg -> 0 -> +0.0f).
__device__ __forceinline__ float fast_exp2(float s, float A23, float B23){
  float t = __builtin_fmaf(s, A23, B23);
  unsigned int u;
  asm("v_cvt_u32_f32 %0, %1" : "=v"(u) : "v"(t));
  return __builtin_bit_cast(float, u);
}

#define GLDS(gp, lp) __builtin_amdgcn_global_load_lds( \
    (const __attribute__((address_space(1))) unsigned int*)(gp), \
    (__attribute__((address_space(3))) unsigned int*)(lp), 16, 0, 0)

// ---------------- fused fp32 -> fp16 cast (x and data in one launch) ----------------
__global__ __launch_bounds__(256) void cast_f16_all(const float* __restrict__ x,
                                                    const float* __restrict__ data,
                                                    us* __restrict__ xf, us* __restrict__ df){
  int bid = blockIdx.x;
  const float* in; us* o;
  if (bid < 2048){ in = x; o = xf; }
  else           { in = data; o = df; bid -= 2048; }
  size_t i = ((size_t)bid * 256 + threadIdx.x) * 8;
  float4 a = *(const float4*)(in + i);
  float4 b = *(const float4*)(in + i + 4);
  float v[8] = {a.x,a.y,a.z,a.w,b.x,b.y,b.z,b.w};
  u16x8 r;
  for (int j = 0; j < 8; j++) r[j] = f2h(v[j]);
  *(u16x8*)(o + i) = r;
}

// ---------------- fused transpose for all three weights (attn/data fp16, proj bf16) ----------------
__global__ __launch_bounds__(256) void transpose_all(const float* __restrict__ W_attn,
                                                     const float* __restrict__ W_data,
                                                     const float* __restrict__ W_proj,
                                                     us* __restrict__ Af, us* __restrict__ Df,
                                                     us* __restrict__ Pb){
  __shared__ float tile[32][33];
  int bx = blockIdx.x;
  const float* W; us* o; int N; bool tobf;
  if (bx < 96){ W = W_attn; o = Af; N = 3072; tobf = false; }
  else if (bx < 160){ W = W_data; o = Df; N = 2048; bx -= 96; tobf = false; }
  else { W = W_proj; o = Pb; N = 1024; bx -= 160; tobf = true; }
  int tx = threadIdx.x & 31, ty = threadIdx.x >> 5;   // 32 x 8
  int n0 = bx * 32, k0 = blockIdx.y * 32;
  for (int r = 0; r < 32; r += 8)
    tile[ty + r][tx] = W[(size_t)(k0 + ty + r) * N + n0 + tx];
  __syncthreads();
  for (int r = 0; r < 32; r += 8){
    float v = tile[tx][ty + r];
    size_t idx = (size_t)(n0 + ty + r) * 1024 + k0 + tx;
    o[idx] = tobf ? f2bf(v) : f2h(v);
  }
}

// ---------------- merged projection GEMM, single-pass fp16 (R13 layout, no swizzle) ----------------
__global__ __launch_bounds__(256) void gemm_all(const us* __restrict__ xf, const us* __restrict__ df,
                                                const us* __restrict__ Watf, const us* __restrict__ Wdtf,
                                                const float* __restrict__ b_attn, const float* __restrict__ b_data,
                                                us* __restrict__ Qf, us* __restrict__ Kf,
                                                us* __restrict__ VT){
  __shared__ us sm[8192];  // A@0, B@4096
  const int bx = blockIdx.x;
  const us *Ah, *Bth; const float* bias; int region, kroff, col0;
  if (bx < 24){
    Ah = xf; Bth = Watf; bias = b_attn;
    region = bx >> 3; kroff = 0; col0 = bx * 128;
  } else {
    int b2 = bx - 24;
    Ah = df; Bth = Wdtf; bias = b_data;
    region = 1 + (b2 >> 3); kroff = 2048; col0 = b2 * 128;
  }
  const int tid = threadIdx.x, wid = tid >> 6, lane = tid & 63;
  const int l15 = lane & 15, l16 = lane >> 4;
  const int row0 = blockIdx.y * 128;
  const int wr = (wid >> 1) * 64, wc = (wid & 1) * 64;
  f32x4 acc[4][4] = {};

  for (int k0 = 0; k0 < 1024; k0 += 32){
    for (int c = 0; c < 2; ++c){
      int i = c * 256 + tid;                           // 0..511: row=i>>2, k8=(i&3)*8
      size_t aoff = (size_t)(row0 + (i >> 2)) * 1024 + k0 + (i & 3) * 8;
      size_t boff = (size_t)(col0 + (i >> 2)) * 1024 + k0 + (i & 3) * 8;
      GLDS(Ah + aoff, &sm[c * 2048 + wid * 512]);
      GLDS(Bth + boff, &sm[4096 + c * 2048 + wid * 512]);
    }
    __syncthreads();
    f16x8 af[4], bf[4];
    for (int m = 0; m < 4; m++) af[m] = *(const f16x8*)&sm[(wr + m * 16 + l15) * 32 + l16 * 8];
    for (int n = 0; n < 4; n++) bf[n] = *(const f16x8*)&sm[4096 + (wc + n * 16 + l15) * 32 + l16 * 8];
    for (int m = 0; m < 4; m++)
      for (int n = 0; n < 4; n++)
        acc[m][n] = __builtin_amdgcn_mfma_f32_16x16x32_f16(af[m], bf[n], acc[m][n], 0, 0, 0);
    __syncthreads();
  }

  for (int m = 0; m < 4; m++)
    for (int n = 0; n < 4; n++){
      int gcol = col0 + wc + n * 16 + l15;
      int ocol = gcol & 1023;
      float bv = bias[gcol];
      if (region == 2){                    // V -> VT[b][d][t] bf16, vectorized over 4 rows
        int r = row0 + wr + m * 16 + l16 * 4;
        u16x4 o;
        for (int j = 0; j < 4; j++) o[j] = f2bf(acc[m][n][j] + bv);
        *(u16x4*)&VT[((size_t)((r >> 11) * 1024 + ocol)) * 4096 + kroff + (r & 2047)] = o;
      } else {                             // Q or K -> fp16
        us* P = (region == 0) ? Qf : Kf;
        for (int j = 0; j < 4; j++){
          int r = row0 + wr + m * 16 + l16 * 4 + j;
          size_t orow = (region == 0) ? (size_t)r
                                      : (size_t)((r >> 11) * 4096 + kroff + (r & 2047));
          P[orow * 1024 + ocol] = f2h(acc[m][n][j] + bv);
        }
      }
    }
}

// ---------------- output projection GEMM (bf16, fp32 out), 128x64 tile, 2 blocks/CU ----------------
// grid (16,32): 512 blocks. Waves 2x2: per wave 64x32 (4x2 frags).
__global__ __launch_bounds__(256) void gemm_proj(const us* __restrict__ Ah,
                                                 const us* __restrict__ Bth,
                                                 const float* __restrict__ bias,
                                                 float* __restrict__ Co){
  __shared__ us sm[12288];   // A [128][32] @0 (8192), B [64][32] @8192 (4096)
  const int tid = threadIdx.x, wid = tid >> 6, lane = tid & 63;
  const int l15 = lane & 15, l16 = lane >> 4;
  const int row0 = blockIdx.y * 128, col0 = blockIdx.x * 64;
  const int wr = (wid >> 1) * 64, wc = (wid & 1) * 32;
  f32x4 acc[4][2] = {};

  for (int k0 = 0; k0 < 1024; k0 += 32){
    for (int c = 0; c < 2; ++c){
      int i = c * 256 + tid;
      size_t aoff = (size_t)(row0 + (i >> 2)) * 1024 + k0 + (i & 3) * 8;
      GLDS(Ah + aoff, &sm[c * 2048 + wid * 512]);
    }
    {
      size_t boff = (size_t)(col0 + (tid >> 2)) * 1024 + k0 + (tid & 3) * 8;
      GLDS(Bth + boff, &sm[8192 + wid * 512]);
    }
    __syncthreads();
    bf16x8 afh[4], bfh[2];
    for (int m = 0; m < 4; m++) afh[m] = *(const bf16x8*)&sm[(wr + m * 16 + l15) * 32 + l16 * 8];
    for (int n = 0; n < 2; n++) bfh[n] = *(const bf16x8*)&sm[8192 + (wc + n * 16 + l15) * 32 + l16 * 8];
    for (int m = 0; m < 4; m++)
      for (int n = 0; n < 2; n++)
        acc[m][n] = __builtin_amdgcn_mfma_f32_16x16x32_bf16(afh[m], bfh[n], acc[m][n], 0, 0, 0);
    __syncthreads();
  }

  for (int m = 0; m < 4; m++)
    for (int n = 0; n < 2; n++){
      int col = col0 + wc + n * 16 + l15;
      float bv = bias[col];
      for (int j = 0; j < 4; j++){
        int r = row0 + wr + m * 16 + l16 * 4 + j;
        Co[(size_t)r * 1024 + col] = acc[m][n][j] + bv;
      }
    }
}

// ---------------- fused attention, split-T + dbuf + VALU shave (R14, unchanged) ----------------
__global__ __launch_bounds__(256, 4) void attn_kernel(const us* __restrict__ Qf,
                                                      const us* __restrict__ Kf,
                                                      const us* __restrict__ VT,
                                                      us* __restrict__ accP,
                                                      float* __restrict__ Mv, float* __restrict__ Lv){
  __shared__ us Kb[2][64 * 72];        // [dbuf][64 t][72] fp16
  __shared__ us Vb[2][64 * 72];        // [dbuf][64 d][72] bf16 (V^T tile)
  const int tid = threadIdx.x, wid = tid >> 6, lane = tid & 63;
  const int l31 = lane & 31, hb = lane >> 5, h8 = hb * 8;
  const int qt = blockIdx.x & 15;             // M/128 = 16
  const int bh = (blockIdx.x >> 4) & 31;
  const int tch = blockIdx.x >> 9;            // T-chunk 0/1
  const int hd = (bh & 15) * 64, b = bh >> 4;
  const int qrow = qt * 128 + wid * 32 + l31;
  const int tbase = tch * 2048, tend = tbase + 2048;

  // Q fragments (B operand): lane holds Q[qrow][d = kk*16 + h8 + i], fp16
  f16x8 qf[4];
  {
    const us* qp = Qf + (size_t)(b * MM + qrow) * 1024 + hd;
#pragma unroll
    for (int kk = 0; kk < 4; kk++)
      qf[kk] = *(const f16x8*)(qp + kk * 16 + h8);
  }

  // all-ones bf16 A-fragment for the l row-sum MFMA
  u16x8 ones_u;
#pragma unroll
  for (int j = 0; j < 8; j++) ones_u[j] = 0x3F80;
  const bf16x8 ones8 = __builtin_bit_cast(bf16x8, ones_u);

  const int i0 = tid, i1 = 256 + tid;
  const int kt0 = i0 >> 3, kd0 = (i0 & 7) * 8;
  const int kt1 = i1 >> 3, kd1 = (i1 & 7) * 8;

#define GK(t0_, t_, d_) (((size_t)(b * TT + (t0_) + (t_))) * 1024 + hd + (d_))
#define GV(t0_, d_, t_) (((size_t)b * 1024 + hd + (d_)) * 4096 + (t0_) + (t_))

  // prologue: stage K,V tile tbase into buf 0
  uint4 rK0 = *(const uint4*)(Kf + GK(tbase, kt0, kd0));
  uint4 rK1 = *(const uint4*)(Kf + GK(tbase, kt1, kd1));
  uint4 rV0 = *(const uint4*)(VT + GV(tbase, kt0, kd0));
  uint4 rV1 = *(const uint4*)(VT + GV(tbase, kt1, kd1));
  *(uint4*)&Kb[0][kt0 * 72 + kd0] = rK0;
  *(uint4*)&Kb[0][kt1 * 72 + kd1] = rK1;
  *(uint4*)&Vb[0][kt0 * 72 + kd0] = rV0;
  *(uint4*)&Vb[0][kt1 * 72 + kd1] = rV1;
  __syncthreads();

  // strength-reduced prefetch pointers (next tile)
  const us* pK0 = Kf + GK(tbase + 64, kt0, kd0);
  const us* pK1 = Kf + GK(tbase + 64, kt1, kd1);
  const us* pV0 = VT + GV(tbase + 64, kt0, kd0);
  const us* pV1 = VT + GV(tbase + 64, kt1, kd1);

  f32x16 acc0 = {}, acc1 = {}, accS = {};
  float mrow = -1e30f;
  const float cs  = 0.125f * 1.44269504088896f;    // to log2 domain
  const float A23 = cs * 8388608.0f;               // cs * 2^23
  float B23 = 0.f;                                 // set on first defer-max trigger (tile 0)

  for (int t0 = tbase; t0 < tend; t0 += 64){
    const int cur = (t0 >> 6) & 1;
    const bool pre = (t0 + 64 < tend);
    if (pre){
      rK0 = *(const uint4*)pK0; pK0 += 64 * 1024;
      rK1 = *(const uint4*)pK1; pK1 += 64 * 1024;
      rV0 = *(const uint4*)pV0; pV0 += 64;
      rV1 = *(const uint4*)pV1; pV1 += 64;
    }

    // S^T = K . Q^T (fp16): frag ts holds t = ts*32 + tloc, q = l31
    const us* KbC = &Kb[cur][0];
    f32x16 sfr0 = {}, sfr1 = {};
    __builtin_amdgcn_s_setprio(1);
#pragma unroll
    for (int kk = 0; kk < 4; kk++){
      f16x8 a0 = *(const f16x8*)&KbC[l31 * 72 + kk * 16 + h8];
      f16x8 a1 = *(const f16x8*)&KbC[(32 + l31) * 72 + kk * 16 + h8];
      sfr0 = __builtin_amdgcn_mfma_f32_32x32x16_f16(a0, qf[kk], sfr0, 0, 0, 0);
      sfr1 = __builtin_amdgcn_mfma_f32_32x32x16_f16(a1, qf[kk], sfr1, 0, 0, 0);
    }
    __builtin_amdgcn_s_setprio(0);

    // tile max via two max3 chains (T17)
    float va = -1e30f, vb2 = -1e30f;
#pragma unroll
    for (int r = 0; r < 16; r += 2){
      va  = fmaxf(fmaxf(sfr0[r],     sfr1[r]),     va);
      vb2 = fmaxf(fmaxf(sfr0[r + 1], sfr1[r + 1]), vb2);
    }
    float v = fmaxf(va, vb2);
    float vs = v * cs;
    vs = fmaxf(vs, __shfl_xor(vs, 32, 64));
    if (!__all(vs <= mrow + 8.f)){      // T13 defer-max (always taken on tile 0)
      float mn = fmaxf(mrow, vs);
      float rs = __builtin_amdgcn_exp2f(mrow - mn);
      mrow = mn;
      B23 = __builtin_fmaf(mrow, -8388608.0f, 1065103216.0f);
#pragma unroll
      for (int r = 0; r < 16; r++){ acc0[r] *= rs; acc1[r] *= rs; accS[r] *= rs; }
    }
    unsigned int A0[4][2], A1[4][2];
#pragma unroll
    for (int g = 0; g < 4; g++){
      float e00 = fast_exp2(sfr0[4*g+0], A23, B23);
      float e01 = fast_exp2(sfr0[4*g+1], A23, B23);
      float e02 = fast_exp2(sfr0[4*g+2], A23, B23);
      float e03 = fast_exp2(sfr0[4*g+3], A23, B23);
      float e10 = fast_exp2(sfr1[4*g+0], A23, B23);
      float e11 = fast_exp2(sfr1[4*g+1], A23, B23);
      float e12 = fast_exp2(sfr1[4*g+2], A23, B23);
      float e13 = fast_exp2(sfr1[4*g+3], A23, B23);
      A0[g][0] = cvt_pk_bf16(e00, e01);
      A0[g][1] = cvt_pk_bf16(e02, e03);
      A1[g][0] = cvt_pk_bf16(e10, e11);
      A1[g][1] = cvt_pk_bf16(e12, e13);
    }

    // build P fragments in-register (T12): frag kk = {x'0, x'1, y'0, y'1}
    bf16x8 pf[4];
#pragma unroll
    for (int kkl = 0; kkl < 2; kkl++){
      unsigned int x0 = A0[2*kkl][0], y0 = A0[2*kkl+1][0];
      unsigned int x1 = A0[2*kkl][1], y1 = A0[2*kkl+1][1];
      plane_swap(x0, y0);
      plane_swap(x1, y1);
      u32x4 w = {x0, x1, y0, y1};
      pf[kkl] = __builtin_bit_cast(bf16x8, w);
      unsigned int z0 = A1[2*kkl][0], t0w = A1[2*kkl+1][0];
      unsigned int z1 = A1[2*kkl][1], t1w = A1[2*kkl+1][1];
      plane_swap(z0, t0w);
      plane_swap(z1, t1w);
      u32x4 w2 = {z0, z1, t0w, t1w};
      pf[2 + kkl] = __builtin_bit_cast(bf16x8, w2);
    }

    // O^T += V^T . P^T ; l-row-sum via ones-MFMA
    const us* VbC = &Vb[cur][0];
    __builtin_amdgcn_s_setprio(1);
#pragma unroll
    for (int kk = 0; kk < 4; kk++){
      bf16x8 av0 = *(const bf16x8*)&VbC[l31 * 72 + kk * 16 + h8];
      bf16x8 av1 = *(const bf16x8*)&VbC[(32 + l31) * 72 + kk * 16 + h8];
      acc0 = __builtin_amdgcn_mfma_f32_32x32x16_bf16(av0, pf[kk], acc0, 0, 0, 0);
      acc1 = __builtin_amdgcn_mfma_f32_32x32x16_bf16(av1, pf[kk], acc1, 0, 0, 0);
      accS = __builtin_amdgcn_mfma_f32_32x32x16_bf16(ones8, pf[kk], accS, 0, 0, 0);
    }
    __builtin_amdgcn_s_setprio(0);

    // stage next tile into the other buffer, then single barrier
    if (pre){
      const int nxt = cur ^ 1;
      *(uint4*)&Kb[nxt][kt0 * 72 + kd0] = rK0;
      *(uint4*)&Kb[nxt][kt1 * 72 + kd1] = rK1;
      *(uint4*)&Vb[nxt][kt0 * 72 + kd0] = rV0;
      *(uint4*)&Vb[nxt][kt1 * 72 + kd1] = rV1;
    }
    __syncthreads();
  }
#undef GK
#undef GV

  // unnormalized partial output + m/l scalars
  us* ap = accP + (size_t)tch * 4194304 + (size_t)(b * MM + qrow) * 1024 + hd;
#pragma unroll
  for (int g = 0; g < 4; g++){
    bf16x4 w0, w1;
#pragma unroll
    for (int j = 0; j < 4; j++){
      w0[j] = (__bf16)acc0[4 * g + j];
      w1[j] = (__bf16)acc1[4 * g + j];
    }
    *(u16x4*)&ap[8 * g + 4 * hb]      = __builtin_bit_cast(u16x4, w0);
    *(u16x4*)&ap[32 + 8 * g + 4 * hb] = __builtin_bit_cast(u16x4, w1);
  }
  if (hb == 0){
    int idx = tch * 65536 + (b * MM + qrow) * 16 + (hd >> 6);
    Mv[idx] = mrow;
    Lv[idx] = accS[0];
  }
}

// ---------------- combine the two T-chunk partials ----------------
__global__ __launch_bounds__(256) void combine_kernel(const us* __restrict__ accP,
                                                      const float* __restrict__ Mv,
                                                      const float* __restrict__ Lv,
                                                      us* __restrict__ attno){
  size_t i = ((size_t)blockIdx.x * 256 + threadIdx.x) * 8;
  size_t qg = i >> 10;
  int h = (int)((i & 1023) >> 6);
  size_t mi = qg * 16 + h;
  float m1 = Mv[mi], m2 = Mv[65536 + mi];
  float l1 = Lv[mi], l2 = Lv[65536 + mi];
  float m = fmaxf(m1, m2);
  float w1 = __builtin_amdgcn_exp2f(m1 - m);
  float w2 = __builtin_amdgcn_exp2f(m2 - m);
  float inv = 1.f / (w1 * l1 + w2 * l2);
  float s1 = w1 * inv, s2 = w2 * inv;
  u16x8 a1 = *(const u16x8*)(accP + i);
  u16x8 a2 = *(const u16x8*)(accP + 4194304 + i);
  u16x8 o;
#pragma unroll
  for (int j = 0; j < 8; j++)
    o[j] = f2bf(s1 * bf2f(a1[j]) + s2 * bf2f(a2[j]));
  *(u16x8*)(attno + i) = o;
}

extern "C" void kernel_launch(void* const* d_in, const int* in_sizes, int n_in,
                              void* d_out, int out_size, void* d_ws, size_t ws_size,
                              hipStream_t stream){
  const float* x      = (const float*)d_in[0];
  const float* data   = (const float*)d_in[1];
  const float* W_attn = (const float*)d_in[2];
  const float* b_attn = (const float*)d_in[3];
  const float* W_data = (const float*)d_in[4];
  const float* b_data = (const float*)d_in[5];
  const float* W_proj = (const float*)d_in[6];
  const float* b_proj = (const float*)d_in[7];
  float* out = (float*)d_out;

  char* ws = (char*)d_ws;
  us* xf    = (us*)(ws + 0);             // [2][2048][1024] fp16 (8 MB)
  us* df    = (us*)(ws + 8388608);       // [2][2048][1024] fp16 (8 MB)
  us* Watf  = (us*)(ws + 16777216);      // [3072][1024] fp16 (6 MB)
  us* Wdtf  = (us*)(ws + 23068672);      // [2048][1024] fp16 (4 MB)
  us* Wptb  = (us*)(ws + 27262976);      // [1024][1024] bf16 (2 MB)
  us* Qf    = (us*)(ws + 29360128);      // [2][2048][1024] fp16 (8 MB)
  us* Kf    = (us*)(ws + 37748736);      // [2][4096][1024] fp16 (16 MB)
  us* VT    = (us*)(ws + 54525952);      // [2][1024][4096] bf16 (16 MB)
  us* accP  = (us*)(ws + 71303168);      // 2 x [2][2048][1024] bf16 partials (16 MB)
  float* Mv = (float*)(ws + 88080384);   // 2 x 64K floats (512 KB)
  float* Lv = (float*)(ws + 88604672);   // 2 x 64K floats (512 KB)
  us* attno = (us*)(ws + 0);             // alias xf (dead after gemm_all)

  cast_f16_all<<<4096, 256, 0, stream>>>(x, data, xf, df);
  transpose_all<<<dim3(192, 32), 256, 0, stream>>>(W_attn, W_data, W_proj, Watf, Wdtf, Wptb);

  gemm_all<<<dim3(40, 32), 256, 0, stream>>>(xf, df, Watf, Wdtf,
                                             b_attn, b_data, Qf, Kf, VT);

  attn_kernel<<<1024, 256, 0, stream>>>(Qf, Kf, VT, accP, Mv, Lv);
  combine_kernel<<<2048, 256, 0, stream>>>(accP, Mv, Lv, attno);

  gemm_proj<<<dim3(16, 32), 256, 0, stream>>>(attno, Wptb, b_proj, out);
}

// Round 16
// 220.304 us; speedup vs baseline: 1.1028x; 1.0199x over previous
//
#include <hip/hip_runtime.h>

typedef __bf16 bf16x8 __attribute__((ext_vector_type(8)));
typedef __bf16 bf16x4 __attribute__((ext_vector_type(4)));
typedef _Float16 f16x8 __attribute__((ext_vector_type(8)));
typedef float f32x4 __attribute__((ext_vector_type(4)));
typedef float f32x16 __attribute__((ext_vector_type(16)));
typedef unsigned short u16x8 __attribute__((ext_vector_type(8)));
typedef unsigned short u16x4 __attribute__((ext_vector_type(4)));
typedef unsigned int u32x4 __attribute__((ext_vector_type(4)));
typedef unsigned short us;

#define MM 2048
#define TT 4096

__device__ __forceinline__ us f2bf(float f){
  unsigned int u = __builtin_bit_cast(unsigned int, f);
  u = (u + 0x7fffu + ((u >> 16) & 1u)) >> 16;
  return (us)u;
}
__device__ __forceinline__ float bf2f(us u){
  unsigned int x = ((unsigned int)u) << 16;
  return __builtin_bit_cast(float, x);
}
__device__ __forceinline__ us f2h(float f){
  _Float16 h = (_Float16)f;
  return __builtin_bit_cast(us, h);
}
__device__ __forceinline__ unsigned int cvt_pk_bf16(float lo, float hi){
  unsigned int r;
  asm("v_cvt_pk_bf16_f32 %0, %1, %2" : "=v"(r) : "v"(lo), "v"(hi));
  return r;
}
__device__ __forceinline__ void plane_swap(unsigned int &x, unsigned int &y){
  asm("v_permlane32_swap_b32 %0, %1" : "+v"(x), "+v"(y));
}
// Schraudolph 2^x, 2 full-rate VALU ops: fma + saturating cvt (neg -> 0 -> +0.0f).
__device__ __forceinline__ float fast_exp2(float s, float A23, float B23){
  float t = __builtin_fmaf(s, A23, B23);
  unsigned int u;
  asm("v_cvt_u32_f32 %0, %1" : "=v"(u) : "v"(t));
  return __builtin_bit_cast(float, u);
}

#define GLDS(gp, lp) __builtin_amdgcn_global_load_lds( \
    (const __attribute__((address_space(1))) unsigned int*)(gp), \
    (__attribute__((address_space(3))) unsigned int*)(lp), 16, 0, 0)

// ---------------- fused fp32 -> fp16 cast (x and data in one launch) ----------------
__global__ __launch_bounds__(256) void cast_f16_all(const float* __restrict__ x,
                                                    const float* __restrict__ data,
                                                    us* __restrict__ xf, us* __restrict__ df){
  int bid = blockIdx.x;
  const float* in; us* o;
  if (bid < 2048){ in = x; o = xf; }
  else           { in = data; o = df; bid -= 2048; }
  size_t i = ((size_t)bid * 256 + threadIdx.x) * 8;
  float4 a = *(const float4*)(in + i);
  float4 b = *(const float4*)(in + i + 4);
  float v[8] = {a.x,a.y,a.z,a.w,b.x,b.y,b.z,b.w};
  u16x8 r;
  for (int j = 0; j < 8; j++) r[j] = f2h(v[j]);
  *(u16x8*)(o + i) = r;
}

// ---------------- fused transpose for all three weights (attn/data fp16, proj bf16) ----------------
__global__ __launch_bounds__(256) void transpose_all(const float* __restrict__ W_attn,
                                                     const float* __restrict__ W_data,
                                                     const float* __restrict__ W_proj,
                                                     us* __restrict__ Af, us* __restrict__ Df,
                                                     us* __restrict__ Pb){
  __shared__ float tile[32][33];
  int bx = blockIdx.x;
  const float* W; us* o; int N; bool tobf;
  if (bx < 96){ W = W_attn; o = Af; N = 3072; tobf = false; }
  else if (bx < 160){ W = W_data; o = Df; N = 2048; bx -= 96; tobf = false; }
  else { W = W_proj; o = Pb; N = 1024; bx -= 160; tobf = true; }
  int tx = threadIdx.x & 31, ty = threadIdx.x >> 5;   // 32 x 8
  int n0 = bx * 32, k0 = blockIdx.y * 32;
  for (int r = 0; r < 32; r += 8)
    tile[ty + r][tx] = W[(size_t)(k0 + ty + r) * N + n0 + tx];
  __syncthreads();
  for (int r = 0; r < 32; r += 8){
    float v = tile[tx][ty + r];
    size_t idx = (size_t)(n0 + ty + r) * 1024 + k0 + tx;
    o[idx] = tobf ? f2bf(v) : f2h(v);
  }
}

// ---------------- merged projection GEMM, single-pass fp16 (R13 layout, no swizzle) ----------------
__global__ __launch_bounds__(256) void gemm_all(const us* __restrict__ xf, const us* __restrict__ df,
                                                const us* __restrict__ Watf, const us* __restrict__ Wdtf,
                                                const float* __restrict__ b_attn, const float* __restrict__ b_data,
                                                us* __restrict__ Qf, us* __restrict__ Kf,
                                                us* __restrict__ VT){
  __shared__ us sm[8192];  // A@0, B@4096
  const int bx = blockIdx.x;
  const us *Ah, *Bth; const float* bias; int region, kroff, col0;
  if (bx < 24){
    Ah = xf; Bth = Watf; bias = b_attn;
    region = bx >> 3; kroff = 0; col0 = bx * 128;
  } else {
    int b2 = bx - 24;
    Ah = df; Bth = Wdtf; bias = b_data;
    region = 1 + (b2 >> 3); kroff = 2048; col0 = b2 * 128;
  }
  const int tid = threadIdx.x, wid = tid >> 6, lane = tid & 63;
  const int l15 = lane & 15, l16 = lane >> 4;
  const int row0 = blockIdx.y * 128;
  const int wr = (wid >> 1) * 64, wc = (wid & 1) * 64;
  f32x4 acc[4][4] = {};

  for (int k0 = 0; k0 < 1024; k0 += 32){
    for (int c = 0; c < 2; ++c){
      int i = c * 256 + tid;                           // 0..511: row=i>>2, k8=(i&3)*8
      size_t aoff = (size_t)(row0 + (i >> 2)) * 1024 + k0 + (i & 3) * 8;
      size_t boff = (size_t)(col0 + (i >> 2)) * 1024 + k0 + (i & 3) * 8;
      GLDS(Ah + aoff, &sm[c * 2048 + wid * 512]);
      GLDS(Bth + boff, &sm[4096 + c * 2048 + wid * 512]);
    }
    __syncthreads();
    f16x8 af[4], bf[4];
    for (int m = 0; m < 4; m++) af[m] = *(const f16x8*)&sm[(wr + m * 16 + l15) * 32 + l16 * 8];
    for (int n = 0; n < 4; n++) bf[n] = *(const f16x8*)&sm[4096 + (wc + n * 16 + l15) * 32 + l16 * 8];
    for (int m = 0; m < 4; m++)
      for (int n = 0; n < 4; n++)
        acc[m][n] = __builtin_amdgcn_mfma_f32_16x16x32_f16(af[m], bf[n], acc[m][n], 0, 0, 0);
    __syncthreads();
  }

  for (int m = 0; m < 4; m++)
    for (int n = 0; n < 4; n++){
      int gcol = col0 + wc + n * 16 + l15;
      int ocol = gcol & 1023;
      float bv = bias[gcol];
      if (region == 2){                    // V -> VT[b][d][t] bf16, vectorized over 4 rows
        int r = row0 + wr + m * 16 + l16 * 4;
        u16x4 o;
        for (int j = 0; j < 4; j++) o[j] = f2bf(acc[m][n][j] + bv);
        *(u16x4*)&VT[((size_t)((r >> 11) * 1024 + ocol)) * 4096 + kroff + (r & 2047)] = o;
      } else {                             // Q or K -> fp16
        us* P = (region == 0) ? Qf : Kf;
        for (int j = 0; j < 4; j++){
          int r = row0 + wr + m * 16 + l16 * 4 + j;
          size_t orow = (region == 0) ? (size_t)r
                                      : (size_t)((r >> 11) * 4096 + kroff + (r & 2047));
          P[orow * 1024 + ocol] = f2h(acc[m][n][j] + bv);
        }
      }
    }
}

// ---------------- output projection GEMM (bf16, fp32 out), 128x64 tile, 2 blocks/CU ----------------
__global__ __launch_bounds__(256) void gemm_proj(const us* __restrict__ Ah,
                                                 const us* __restrict__ Bth,
                                                 const float* __restrict__ bias,
                                                 float* __restrict__ Co){
  __shared__ us sm[12288];   // A [128][32] @0 (8192), B [64][32] @8192 (4096)
  const int tid = threadIdx.x, wid = tid >> 6, lane = tid & 63;
  const int l15 = lane & 15, l16 = lane >> 4;
  const int row0 = blockIdx.y * 128, col0 = blockIdx.x * 64;
  const int wr = (wid >> 1) * 64, wc = (wid & 1) * 32;
  f32x4 acc[4][2] = {};

  for (int k0 = 0; k0 < 1024; k0 += 32){
    for (int c = 0; c < 2; ++c){
      int i = c * 256 + tid;
      size_t aoff = (size_t)(row0 + (i >> 2)) * 1024 + k0 + (i & 3) * 8;
      GLDS(Ah + aoff, &sm[c * 2048 + wid * 512]);
    }
    {
      size_t boff = (size_t)(col0 + (tid >> 2)) * 1024 + k0 + (tid & 3) * 8;
      GLDS(Bth + boff, &sm[8192 + wid * 512]);
    }
    __syncthreads();
    bf16x8 afh[4], bfh[2];
    for (int m = 0; m < 4; m++) afh[m] = *(const bf16x8*)&sm[(wr + m * 16 + l15) * 32 + l16 * 8];
    for (int n = 0; n < 2; n++) bfh[n] = *(const bf16x8*)&sm[8192 + (wc + n * 16 + l15) * 32 + l16 * 8];
    for (int m = 0; m < 4; m++)
      for (int n = 0; n < 2; n++)
        acc[m][n] = __builtin_amdgcn_mfma_f32_16x16x32_bf16(afh[m], bfh[n], acc[m][n], 0, 0, 0);
    __syncthreads();
  }

  for (int m = 0; m < 4; m++)
    for (int n = 0; n < 2; n++){
      int col = col0 + wc + n * 16 + l15;
      float bv = bias[col];
      for (int j = 0; j < 4; j++){
        int r = row0 + wr + m * 16 + l16 * 4 + j;
        Co[(size_t)r * 1024 + col] = acc[m][n][j] + bv;
      }
    }
}

// ---------------- fused attention, split-T + dbuf + VALU shave + XCD swizzle (R16) ----------------
// Work-id remap: XCD i (blocks == i mod 8) gets 128 contiguous work-ids = 8 complete
// (tch,b,h) groups -> each group's 512 KB K/V-half fetched by ONE XCD, not all 8.
__global__ __launch_bounds__(256, 4) void attn_kernel(const us* __restrict__ Qf,
                                                      const us* __restrict__ Kf,
                                                      const us* __restrict__ VT,
                                                      us* __restrict__ accP,
                                                      float* __restrict__ Mv, float* __restrict__ Lv){
  __shared__ us Kb[2][64 * 72];        // [dbuf][64 t][72] fp16
  __shared__ us Vb[2][64 * 72];        // [dbuf][64 d][72] bf16 (V^T tile)
  const int tid = threadIdx.x, wid = tid >> 6, lane = tid & 63;
  const int l31 = lane & 31, hb = lane >> 5, h8 = hb * 8;
  const int bid = blockIdx.x;
  const int swz = (bid & 7) * 128 + (bid >> 3);   // bijective, 1024 = 8*128
  const int qt = swz & 15;                    // M/128 = 16
  const int bh = (swz >> 4) & 31;
  const int tch = swz >> 9;                   // T-chunk 0/1
  const int hd = (bh & 15) * 64, b = bh >> 4;
  const int qrow = qt * 128 + wid * 32 + l31;
  const int tbase = tch * 2048, tend = tbase + 2048;

  // Q fragments (B operand): lane holds Q[qrow][d = kk*16 + h8 + i], fp16
  f16x8 qf[4];
  {
    const us* qp = Qf + (size_t)(b * MM + qrow) * 1024 + hd;
#pragma unroll
    for (int kk = 0; kk < 4; kk++)
      qf[kk] = *(const f16x8*)(qp + kk * 16 + h8);
  }

  // all-ones bf16 A-fragment for the l row-sum MFMA
  u16x8 ones_u;
#pragma unroll
  for (int j = 0; j < 8; j++) ones_u[j] = 0x3F80;
  const bf16x8 ones8 = __builtin_bit_cast(bf16x8, ones_u);

  const int i0 = tid, i1 = 256 + tid;
  const int kt0 = i0 >> 3, kd0 = (i0 & 7) * 8;
  const int kt1 = i1 >> 3, kd1 = (i1 & 7) * 8;

#define GK(t0_, t_, d_) (((size_t)(b * TT + (t0_) + (t_))) * 1024 + hd + (d_))
#define GV(t0_, d_, t_) (((size_t)b * 1024 + hd + (d_)) * 4096 + (t0_) + (t_))

  // prologue: stage K,V tile tbase into buf 0
  uint4 rK0 = *(const uint4*)(Kf + GK(tbase, kt0, kd0));
  uint4 rK1 = *(const uint4*)(Kf + GK(tbase, kt1, kd1));
  uint4 rV0 = *(const uint4*)(VT + GV(tbase, kt0, kd0));
  uint4 rV1 = *(const uint4*)(VT + GV(tbase, kt1, kd1));
  *(uint4*)&Kb[0][kt0 * 72 + kd0] = rK0;
  *(uint4*)&Kb[0][kt1 * 72 + kd1] = rK1;
  *(uint4*)&Vb[0][kt0 * 72 + kd0] = rV0;
  *(uint4*)&Vb[0][kt1 * 72 + kd1] = rV1;
  __syncthreads();

  // strength-reduced prefetch pointers (next tile)
  const us* pK0 = Kf + GK(tbase + 64, kt0, kd0);
  const us* pK1 = Kf + GK(tbase + 64, kt1, kd1);
  const us* pV0 = VT + GV(tbase + 64, kt0, kd0);
  const us* pV1 = VT + GV(tbase + 64, kt1, kd1);

  f32x16 acc0 = {}, acc1 = {}, accS = {};
  float mrow = -1e30f;
  const float cs  = 0.125f * 1.44269504088896f;    // to log2 domain
  const float A23 = cs * 8388608.0f;               // cs * 2^23
  float B23 = 0.f;                                 // set on first defer-max trigger (tile 0)

  for (int t0 = tbase; t0 < tend; t0 += 64){
    const int cur = (t0 >> 6) & 1;
    const bool pre = (t0 + 64 < tend);
    if (pre){
      rK0 = *(const uint4*)pK0; pK0 += 64 * 1024;
      rK1 = *(const uint4*)pK1; pK1 += 64 * 1024;
      rV0 = *(const uint4*)pV0; pV0 += 64;
      rV1 = *(const uint4*)pV1; pV1 += 64;
    }

    // S^T = K . Q^T (fp16): frag ts holds t = ts*32 + tloc, q = l31
    const us* KbC = &Kb[cur][0];
    f32x16 sfr0 = {}, sfr1 = {};
    __builtin_amdgcn_s_setprio(1);
#pragma unroll
    for (int kk = 0; kk < 4; kk++){
      f16x8 a0 = *(const f16x8*)&KbC[l31 * 72 + kk * 16 + h8];
      f16x8 a1 = *(const f16x8*)&KbC[(32 + l31) * 72 + kk * 16 + h8];
      sfr0 = __builtin_amdgcn_mfma_f32_32x32x16_f16(a0, qf[kk], sfr0, 0, 0, 0);
      sfr1 = __builtin_amdgcn_mfma_f32_32x32x16_f16(a1, qf[kk], sfr1, 0, 0, 0);
    }
    __builtin_amdgcn_s_setprio(0);

    // tile max via two max3 chains (T17)
    float va = -1e30f, vb2 = -1e30f;
#pragma unroll
    for (int r = 0; r < 16; r += 2){
      va  = fmaxf(fmaxf(sfr0[r],     sfr1[r]),     va);
      vb2 = fmaxf(fmaxf(sfr0[r + 1], sfr1[r + 1]), vb2);
    }
    float v = fmaxf(va, vb2);
    float vs = v * cs;
    vs = fmaxf(vs, __shfl_xor(vs, 32, 64));
    if (!__all(vs <= mrow + 8.f)){      // T13 defer-max (always taken on tile 0)
      float mn = fmaxf(mrow, vs);
      float rs = __builtin_amdgcn_exp2f(mrow - mn);
      mrow = mn;
      B23 = __builtin_fmaf(mrow, -8388608.0f, 1065103216.0f);
#pragma unroll
      for (int r = 0; r < 16; r++){ acc0[r] *= rs; acc1[r] *= rs; accS[r] *= rs; }
    }
    unsigned int A0[4][2], A1[4][2];
#pragma unroll
    for (int g = 0; g < 4; g++){
      float e00 = fast_exp2(sfr0[4*g+0], A23, B23);
      float e01 = fast_exp2(sfr0[4*g+1], A23, B23);
      float e02 = fast_exp2(sfr0[4*g+2], A23, B23);
      float e03 = fast_exp2(sfr0[4*g+3], A23, B23);
      float e10 = fast_exp2(sfr1[4*g+0], A23, B23);
      float e11 = fast_exp2(sfr1[4*g+1], A23, B23);
      float e12 = fast_exp2(sfr1[4*g+2], A23, B23);
      float e13 = fast_exp2(sfr1[4*g+3], A23, B23);
      A0[g][0] = cvt_pk_bf16(e00, e01);
      A0[g][1] = cvt_pk_bf16(e02, e03);
      A1[g][0] = cvt_pk_bf16(e10, e11);
      A1[g][1] = cvt_pk_bf16(e12, e13);
    }

    // build P fragments in-register (T12): frag kk = {x'0, x'1, y'0, y'1}
    bf16x8 pf[4];
#pragma unroll
    for (int kkl = 0; kkl < 2; kkl++){
      unsigned int x0 = A0[2*kkl][0], y0 = A0[2*kkl+1][0];
      unsigned int x1 = A0[2*kkl][1], y1 = A0[2*kkl+1][1];
      plane_swap(x0, y0);
      plane_swap(x1, y1);
      u32x4 w = {x0, x1, y0, y1};
      pf[kkl] = __builtin_bit_cast(bf16x8, w);
      unsigned int z0 = A1[2*kkl][0], t0w = A1[2*kkl+1][0];
      unsigned int z1 = A1[2*kkl][1], t1w = A1[2*kkl+1][1];
      plane_swap(z0, t0w);
      plane_swap(z1, t1w);
      u32x4 w2 = {z0, z1, t0w, t1w};
      pf[2 + kkl] = __builtin_bit_cast(bf16x8, w2);
    }

    // O^T += V^T . P^T ; l-row-sum via ones-MFMA
    const us* VbC = &Vb[cur][0];
    __builtin_amdgcn_s_setprio(1);
#pragma unroll
    for (int kk = 0; kk < 4; kk++){
      bf16x8 av0 = *(const bf16x8*)&VbC[l31 * 72 + kk * 16 + h8];
      bf16x8 av1 = *(const bf16x8*)&VbC[(32 + l31) * 72 + kk * 16 + h8];
      acc0 = __builtin_amdgcn_mfma_f32_32x32x16_bf16(av0, pf[kk], acc0, 0, 0, 0);
      acc1 = __builtin_amdgcn_mfma_f32_32x32x16_bf16(av1, pf[kk], acc1, 0, 0, 0);
      accS = __builtin_amdgcn_mfma_f32_32x32x16_bf16(ones8, pf[kk], accS, 0, 0, 0);
    }
    __builtin_amdgcn_s_setprio(0);

    // stage next tile into the other buffer, then single barrier
    if (pre){
      const int nxt = cur ^ 1;
      *(uint4*)&Kb[nxt][kt0 * 72 + kd0] = rK0;
      *(uint4*)&Kb[nxt][kt1 * 72 + kd1] = rK1;
      *(uint4*)&Vb[nxt][kt0 * 72 + kd0] = rV0;
      *(uint4*)&Vb[nxt][kt1 * 72 + kd1] = rV1;
    }
    __syncthreads();
  }
#undef GK
#undef GV

  // unnormalized partial output + m/l scalars
  us* ap = accP + (size_t)tch * 4194304 + (size_t)(b * MM + qrow) * 1024 + hd;
#pragma unroll
  for (int g = 0; g < 4; g++){
    bf16x4 w0, w1;
#pragma unroll
    for (int j = 0; j < 4; j++){
      w0[j] = (__bf16)acc0[4 * g + j];
      w1[j] = (__bf16)acc1[4 * g + j];
    }
    *(u16x4*)&ap[8 * g + 4 * hb]      = __builtin_bit_cast(u16x4, w0);
    *(u16x4*)&ap[32 + 8 * g + 4 * hb] = __builtin_bit_cast(u16x4, w1);
  }
  if (hb == 0){
    int idx = tch * 65536 + (b * MM + qrow) * 16 + (hd >> 6);
    Mv[idx] = mrow;
    Lv[idx] = accS[0];
  }
}

// ---------------- combine the two T-chunk partials ----------------
__global__ __launch_bounds__(256) void combine_kernel(const us* __restrict__ accP,
                                                      const float* __restrict__ Mv,
                                                      const float* __restrict__ Lv,
                                                      us* __restrict__ attno){
  size_t i = ((size_t)blockIdx.x * 256 + threadIdx.x) * 8;
  size_t qg = i >> 10;
  int h = (int)((i & 1023) >> 6);
  size_t mi = qg * 16 + h;
  float m1 = Mv[mi], m2 = Mv[65536 + mi];
  float l1 = Lv[mi], l2 = Lv[65536 + mi];
  float m = fmaxf(m1, m2);
  float w1 = __builtin_amdgcn_exp2f(m1 - m);
  float w2 = __builtin_amdgcn_exp2f(m2 - m);
  float inv = 1.f / (w1 * l1 + w2 * l2);
  float s1 = w1 * inv, s2 = w2 * inv;
  u16x8 a1 = *(const u16x8*)(accP + i);
  u16x8 a2 = *(const u16x8*)(accP + 4194304 + i);
  u16x8 o;
#pragma unroll
  for (int j = 0; j < 8; j++)
    o[j] = f2bf(s1 * bf2f(a1[j]) + s2 * bf2f(a2[j]));
  *(u16x8*)(attno + i) = o;
}

extern "C" void kernel_launch(void* const* d_in, const int* in_sizes, int n_in,
                              void* d_out, int out_size, void* d_ws, size_t ws_size,
                              hipStream_t stream){
  const float* x      = (const float*)d_in[0];
  const float* data   = (const float*)d_in[1];
  const float* W_attn = (const float*)d_in[2];
  const float* b_attn = (const float*)d_in[3];
  const float* W_data = (const float*)d_in[4];
  const float* b_data = (const float*)d_in[5];
  const float* W_proj = (const float*)d_in[6];
  const float* b_proj = (const float*)d_in[7];
  float* out = (float*)d_out;

  char* ws = (char*)d_ws;
  us* xf    = (us*)(ws + 0);             // [2][2048][1024] fp16 (8 MB)
  us* df    = (us*)(ws + 8388608);       // [2][2048][1024] fp16 (8 MB)
  us* Watf  = (us*)(ws + 16777216);      // [3072][1024] fp16 (6 MB)
  us* Wdtf  = (us*)(ws + 23068672);      // [2048][1024] fp16 (4 MB)
  us* Wptb  = (us*)(ws + 27262976);      // [1024][1024] bf16 (2 MB)
  us* Qf    = (us*)(ws + 29360128);      // [2][2048][1024] fp16 (8 MB)
  us* Kf    = (us*)(ws + 37748736);      // [2][4096][1024] fp16 (16 MB)
  us* VT    = (us*)(ws + 54525952);      // [2][1024][4096] bf16 (16 MB)
  us* accP  = (us*)(ws + 71303168);      // 2 x [2][2048][1024] bf16 partials (16 MB)
  float* Mv = (float*)(ws + 88080384);   // 2 x 64K floats (512 KB)
  float* Lv = (float*)(ws + 88604672);   // 2 x 64K floats (512 KB)
  us* attno = (us*)(ws + 0);             // alias xf (dead after gemm_all)

  cast_f16_all<<<4096, 256, 0, stream>>>(x, data, xf, df);
  transpose_all<<<dim3(192, 32), 256, 0, stream>>>(W_attn, W_data, W_proj, Watf, Wdtf, Wptb);

  gemm_all<<<dim3(40, 32), 256, 0, stream>>>(xf, df, Watf, Wdtf,
                                             b_attn, b_data, Qf, Kf, VT);

  attn_kernel<<<1024, 256, 0, stream>>>(Qf, Kf, VT, accP, Mv, Lv);
  combine_kernel<<<2048, 256, 0, stream>>>(accP, Mv, Lv, attno);

  gemm_proj<<<dim3(16, 32), 256, 0, stream>>>(attno, Wptb, b_proj, out);
}

// Round 17
// 220.097 us; speedup vs baseline: 1.1039x; 1.0009x over previous
//
#include <hip/hip_runtime.h>

typedef __bf16 bf16x8 __attribute__((ext_vector_type(8)));
typedef __bf16 bf16x4 __attribute__((ext_vector_type(4)));
typedef _Float16 f16x8 __attribute__((ext_vector_type(8)));
typedef float f32x4 __attribute__((ext_vector_type(4)));
typedef float f32x16 __attribute__((ext_vector_type(16)));
typedef unsigned short u16x8 __attribute__((ext_vector_type(8)));
typedef unsigned short u16x4 __attribute__((ext_vector_type(4)));
typedef unsigned int u32x4 __attribute__((ext_vector_type(4)));
typedef unsigned short us;

#define MM 2048
#define TT 4096

__device__ __forceinline__ us f2bf(float f){
  unsigned int u = __builtin_bit_cast(unsigned int, f);
  u = (u + 0x7fffu + ((u >> 16) & 1u)) >> 16;
  return (us)u;
}
__device__ __forceinline__ float bf2f(us u){
  unsigned int x = ((unsigned int)u) << 16;
  return __builtin_bit_cast(float, x);
}
__device__ __forceinline__ us f2h(float f){
  _Float16 h = (_Float16)f;
  return __builtin_bit_cast(us, h);
}
__device__ __forceinline__ unsigned int cvt_pk_bf16(float lo, float hi){
  unsigned int r;
  asm("v_cvt_pk_bf16_f32 %0, %1, %2" : "=v"(r) : "v"(lo), "v"(hi));
  return r;
}
__device__ __forceinline__ void plane_swap(unsigned int &x, unsigned int &y){
  asm("v_permlane32_swap_b32 %0, %1" : "+v"(x), "+v"(y));
}
// Schraudolph 2^x, 2 full-rate VALU ops: fma + saturating cvt (neg -> 0 -> +0.0f).
__device__ __forceinline__ float fast_exp2(float s, float A23, float B23){
  float t = __builtin_fmaf(s, A23, B23);
  unsigned int u;
  asm("v_cvt_u32_f32 %0, %1" : "=v"(u) : "v"(t));
  return __builtin_bit_cast(float, u);
}

#define GLDS(gp, lp) __builtin_amdgcn_global_load_lds( \
    (const __attribute__((address_space(1))) unsigned int*)(gp), \
    (__attribute__((address_space(3))) unsigned int*)(lp), 16, 0, 0)

// ---------------- fused fp32 -> fp16 cast (x and data in one launch) ----------------
__global__ __launch_bounds__(256) void cast_f16_all(const float* __restrict__ x,
                                                    const float* __restrict__ data,
                                                    us* __restrict__ xf, us* __restrict__ df){
  int bid = blockIdx.x;
  const float* in; us* o;
  if (bid < 2048){ in = x; o = xf; }
  else           { in = data; o = df; bid -= 2048; }
  size_t i = ((size_t)bid * 256 + threadIdx.x) * 8;
  float4 a = *(const float4*)(in + i);
  float4 b = *(const float4*)(in + i + 4);
  float v[8] = {a.x,a.y,a.z,a.w,b.x,b.y,b.z,b.w};
  u16x8 r;
  for (int j = 0; j < 8; j++) r[j] = f2h(v[j]);
  *(u16x8*)(o + i) = r;
}

// ---------------- fused transpose for all three weights (attn/data fp16, proj bf16) ----------------
__global__ __launch_bounds__(256) void transpose_all(const float* __restrict__ W_attn,
                                                     const float* __restrict__ W_data,
                                                     const float* __restrict__ W_proj,
                                                     us* __restrict__ Af, us* __restrict__ Df,
                                                     us* __restrict__ Pb){
  __shared__ float tile[32][33];
  int bx = blockIdx.x;
  const float* W; us* o; int N; bool tobf;
  if (bx < 96){ W = W_attn; o = Af; N = 3072; tobf = false; }
  else if (bx < 160){ W = W_data; o = Df; N = 2048; bx -= 96; tobf = false; }
  else { W = W_proj; o = Pb; N = 1024; bx -= 160; tobf = true; }
  int tx = threadIdx.x & 31, ty = threadIdx.x >> 5;   // 32 x 8
  int n0 = bx * 32, k0 = blockIdx.y * 32;
  for (int r = 0; r < 32; r += 8)
    tile[ty + r][tx] = W[(size_t)(k0 + ty + r) * N + n0 + tx];
  __syncthreads();
  for (int r = 0; r < 32; r += 8){
    float v = tile[tx][ty + r];
    size_t idx = (size_t)(n0 + ty + r) * 1024 + k0 + tx;
    o[idx] = tobf ? f2bf(v) : f2h(v);
  }
}

// ---------------- merged projection GEMM, single-pass fp16, col-major XCD chunks ----------------
// lin = by*40+bx; XCD i (lin%8) gets cols [i*5, i*5+5) x all 32 row-panels:
// resident B = 5x256KB = 1.28MB <= 4MB L2; A k-slices stay hot (5 sharing blocks in sync).
__global__ __launch_bounds__(256) void gemm_all(const us* __restrict__ xf, const us* __restrict__ df,
                                                const us* __restrict__ Watf, const us* __restrict__ Wdtf,
                                                const float* __restrict__ b_attn, const float* __restrict__ b_data,
                                                us* __restrict__ Qf, us* __restrict__ Kf,
                                                us* __restrict__ VT){
  __shared__ us sm[8192];  // A@0, B@4096
  const int lin = blockIdx.y * 40 + blockIdx.x;
  const int xcd = lin & 7, j = lin >> 3;          // j in [0,160)
  const int bx = xcd * 5 + (j % 5);               // col-panel
  const int row0 = (j / 5) * 128;                 // row-panel
  const us *Ah, *Bth; const float* bias; int region, kroff, col0;
  if (bx < 24){
    Ah = xf; Bth = Watf; bias = b_attn;
    region = bx >> 3; kroff = 0; col0 = bx * 128;
  } else {
    int b2 = bx - 24;
    Ah = df; Bth = Wdtf; bias = b_data;
    region = 1 + (b2 >> 3); kroff = 2048; col0 = b2 * 128;
  }
  const int tid = threadIdx.x, wid = tid >> 6, lane = tid & 63;
  const int l15 = lane & 15, l16 = lane >> 4;
  const int wr = (wid >> 1) * 64, wc = (wid & 1) * 64;
  f32x4 acc[4][4] = {};

  for (int k0 = 0; k0 < 1024; k0 += 32){
    for (int c = 0; c < 2; ++c){
      int i = c * 256 + tid;                           // 0..511: row=i>>2, k8=(i&3)*8
      size_t aoff = (size_t)(row0 + (i >> 2)) * 1024 + k0 + (i & 3) * 8;
      size_t boff = (size_t)(col0 + (i >> 2)) * 1024 + k0 + (i & 3) * 8;
      GLDS(Ah + aoff, &sm[c * 2048 + wid * 512]);
      GLDS(Bth + boff, &sm[4096 + c * 2048 + wid * 512]);
    }
    __syncthreads();
    f16x8 af[4], bf[4];
    for (int m = 0; m < 4; m++) af[m] = *(const f16x8*)&sm[(wr + m * 16 + l15) * 32 + l16 * 8];
    for (int n = 0; n < 4; n++) bf[n] = *(const f16x8*)&sm[4096 + (wc + n * 16 + l15) * 32 + l16 * 8];
    for (int m = 0; m < 4; m++)
      for (int n = 0; n < 4; n++)
        acc[m][n] = __builtin_amdgcn_mfma_f32_16x16x32_f16(af[m], bf[n], acc[m][n], 0, 0, 0);
    __syncthreads();
  }

  for (int m = 0; m < 4; m++)
    for (int n = 0; n < 4; n++){
      int gcol = col0 + wc + n * 16 + l15;
      int ocol = gcol & 1023;
      float bv = bias[gcol];
      if (region == 2){                    // V -> VT[b][d][t] bf16, vectorized over 4 rows
        int r = row0 + wr + m * 16 + l16 * 4;
        u16x4 o;
        for (int j2 = 0; j2 < 4; j2++) o[j2] = f2bf(acc[m][n][j2] + bv);
        *(u16x4*)&VT[((size_t)((r >> 11) * 1024 + ocol)) * 4096 + kroff + (r & 2047)] = o;
      } else {                             // Q or K -> fp16
        us* P = (region == 0) ? Qf : Kf;
        for (int j2 = 0; j2 < 4; j2++){
          int r = row0 + wr + m * 16 + l16 * 4 + j2;
          size_t orow = (region == 0) ? (size_t)r
                                      : (size_t)((r >> 11) * 4096 + kroff + (r & 2047));
          P[orow * 1024 + ocol] = f2h(acc[m][n][j2] + bv);
        }
      }
    }
}

// ---------------- output projection GEMM (bf16, fp32 out), 128x64 tile, 2 blocks/CU ----------------
__global__ __launch_bounds__(256) void gemm_proj(const us* __restrict__ Ah,
                                                 const us* __restrict__ Bth,
                                                 const float* __restrict__ bias,
                                                 float* __restrict__ Co){
  __shared__ us sm[12288];   // A [128][32] @0 (8192), B [64][32] @8192 (4096)
  const int tid = threadIdx.x, wid = tid >> 6, lane = tid & 63;
  const int l15 = lane & 15, l16 = lane >> 4;
  const int row0 = blockIdx.y * 128, col0 = blockIdx.x * 64;
  const int wr = (wid >> 1) * 64, wc = (wid & 1) * 32;
  f32x4 acc[4][2] = {};

  for (int k0 = 0; k0 < 1024; k0 += 32){
    for (int c = 0; c < 2; ++c){
      int i = c * 256 + tid;
      size_t aoff = (size_t)(row0 + (i >> 2)) * 1024 + k0 + (i & 3) * 8;
      GLDS(Ah + aoff, &sm[c * 2048 + wid * 512]);
    }
    {
      size_t boff = (size_t)(col0 + (tid >> 2)) * 1024 + k0 + (tid & 3) * 8;
      GLDS(Bth + boff, &sm[8192 + wid * 512]);
    }
    __syncthreads();
    bf16x8 afh[4], bfh[2];
    for (int m = 0; m < 4; m++) afh[m] = *(const bf16x8*)&sm[(wr + m * 16 + l15) * 32 + l16 * 8];
    for (int n = 0; n < 2; n++) bfh[n] = *(const bf16x8*)&sm[8192 + (wc + n * 16 + l15) * 32 + l16 * 8];
    for (int m = 0; m < 4; m++)
      for (int n = 0; n < 2; n++)
        acc[m][n] = __builtin_amdgcn_mfma_f32_16x16x32_bf16(afh[m], bfh[n], acc[m][n], 0, 0, 0);
    __syncthreads();
  }

  for (int m = 0; m < 4; m++)
    for (int n = 0; n < 2; n++){
      int col = col0 + wc + n * 16 + l15;
      float bv = bias[col];
      for (int j = 0; j < 4; j++){
        int r = row0 + wr + m * 16 + l16 * 4 + j;
        Co[(size_t)r * 1024 + col] = acc[m][n][j] + bv;
      }
    }
}

// ---------------- fused attention (R16, unchanged) ----------------
__global__ __launch_bounds__(256, 4) void attn_kernel(const us* __restrict__ Qf,
                                                      const us* __restrict__ Kf,
                                                      const us* __restrict__ VT,
                                                      us* __restrict__ accP,
                                                      float* __restrict__ Mv, float* __restrict__ Lv){
  __shared__ us Kb[2][64 * 72];        // [dbuf][64 t][72] fp16
  __shared__ us Vb[2][64 * 72];        // [dbuf][64 d][72] bf16 (V^T tile)
  const int tid = threadIdx.x, wid = tid >> 6, lane = tid & 63;
  const int l31 = lane & 31, hb = lane >> 5, h8 = hb * 8;
  const int bid = blockIdx.x;
  const int swz = (bid & 7) * 128 + (bid >> 3);   // bijective, 1024 = 8*128
  const int qt = swz & 15;                    // M/128 = 16
  const int bh = (swz >> 4) & 31;
  const int tch = swz >> 9;                   // T-chunk 0/1
  const int hd = (bh & 15) * 64, b = bh >> 4;
  const int qrow = qt * 128 + wid * 32 + l31;
  const int tbase = tch * 2048, tend = tbase + 2048;

  // Q fragments (B operand): lane holds Q[qrow][d = kk*16 + h8 + i], fp16
  f16x8 qf[4];
  {
    const us* qp = Qf + (size_t)(b * MM + qrow) * 1024 + hd;
#pragma unroll
    for (int kk = 0; kk < 4; kk++)
      qf[kk] = *(const f16x8*)(qp + kk * 16 + h8);
  }

  // all-ones bf16 A-fragment for the l row-sum MFMA
  u16x8 ones_u;
#pragma unroll
  for (int j = 0; j < 8; j++) ones_u[j] = 0x3F80;
  const bf16x8 ones8 = __builtin_bit_cast(bf16x8, ones_u);

  const int i0 = tid, i1 = 256 + tid;
  const int kt0 = i0 >> 3, kd0 = (i0 & 7) * 8;
  const int kt1 = i1 >> 3, kd1 = (i1 & 7) * 8;

#define GK(t0_, t_, d_) (((size_t)(b * TT + (t0_) + (t_))) * 1024 + hd + (d_))
#define GV(t0_, d_, t_) (((size_t)b * 1024 + hd + (d_)) * 4096 + (t0_) + (t_))

  // prologue: stage K,V tile tbase into buf 0
  uint4 rK0 = *(const uint4*)(Kf + GK(tbase, kt0, kd0));
  uint4 rK1 = *(const uint4*)(Kf + GK(tbase, kt1, kd1));
  uint4 rV0 = *(const uint4*)(VT + GV(tbase, kt0, kd0));
  uint4 rV1 = *(const uint4*)(VT + GV(tbase, kt1, kd1));
  *(uint4*)&Kb[0][kt0 * 72 + kd0] = rK0;
  *(uint4*)&Kb[0][kt1 * 72 + kd1] = rK1;
  *(uint4*)&Vb[0][kt0 * 72 + kd0] = rV0;
  *(uint4*)&Vb[0][kt1 * 72 + kd1] = rV1;
  __syncthreads();

  // strength-reduced prefetch pointers (next tile)
  const us* pK0 = Kf + GK(tbase + 64, kt0, kd0);
  const us* pK1 = Kf + GK(tbase + 64, kt1, kd1);
  const us* pV0 = VT + GV(tbase + 64, kt0, kd0);
  const us* pV1 = VT + GV(tbase + 64, kt1, kd1);

  f32x16 acc0 = {}, acc1 = {}, accS = {};
  float mrow = -1e30f;
  const float cs  = 0.125f * 1.44269504088896f;    // to log2 domain
  const float A23 = cs * 8388608.0f;               // cs * 2^23
  float B23 = 0.f;                                 // set on first defer-max trigger (tile 0)

  for (int t0 = tbase; t0 < tend; t0 += 64){
    const int cur = (t0 >> 6) & 1;
    const bool pre = (t0 + 64 < tend);
    if (pre){
      rK0 = *(const uint4*)pK0; pK0 += 64 * 1024;
      rK1 = *(const uint4*)pK1; pK1 += 64 * 1024;
      rV0 = *(const uint4*)pV0; pV0 += 64;
      rV1 = *(const uint4*)pV1; pV1 += 64;
    }

    // S^T = K . Q^T (fp16): frag ts holds t = ts*32 + tloc, q = l31
    const us* KbC = &Kb[cur][0];
    f32x16 sfr0 = {}, sfr1 = {};
    __builtin_amdgcn_s_setprio(1);
#pragma unroll
    for (int kk = 0; kk < 4; kk++){
      f16x8 a0 = *(const f16x8*)&KbC[l31 * 72 + kk * 16 + h8];
      f16x8 a1 = *(const f16x8*)&KbC[(32 + l31) * 72 + kk * 16 + h8];
      sfr0 = __builtin_amdgcn_mfma_f32_32x32x16_f16(a0, qf[kk], sfr0, 0, 0, 0);
      sfr1 = __builtin_amdgcn_mfma_f32_32x32x16_f16(a1, qf[kk], sfr1, 0, 0, 0);
    }
    __builtin_amdgcn_s_setprio(0);

    // tile max via two max3 chains (T17)
    float va = -1e30f, vb2 = -1e30f;
#pragma unroll
    for (int r = 0; r < 16; r += 2){
      va  = fmaxf(fmaxf(sfr0[r],     sfr1[r]),     va);
      vb2 = fmaxf(fmaxf(sfr0[r + 1], sfr1[r + 1]), vb2);
    }
    float v = fmaxf(va, vb2);
    float vs = v * cs;
    vs = fmaxf(vs, __shfl_xor(vs, 32, 64));
    if (!__all(vs <= mrow + 8.f)){      // T13 defer-max (always taken on tile 0)
      float mn = fmaxf(mrow, vs);
      float rs = __builtin_amdgcn_exp2f(mrow - mn);
      mrow = mn;
      B23 = __builtin_fmaf(mrow, -8388608.0f, 1065103216.0f);
#pragma unroll
      for (int r = 0; r < 16; r++){ acc0[r] *= rs; acc1[r] *= rs; accS[r] *= rs; }
    }
    unsigned int A0[4][2], A1[4][2];
#pragma unroll
    for (int g = 0; g < 4; g++){
      float e00 = fast_exp2(sfr0[4*g+0], A23, B23);
      float e01 = fast_exp2(sfr0[4*g+1], A23, B23);
      float e02 = fast_exp2(sfr0[4*g+2], A23, B23);
      float e03 = fast_exp2(sfr0[4*g+3], A23, B23);
      float e10 = fast_exp2(sfr1[4*g+0], A23, B23);
      float e11 = fast_exp2(sfr1[4*g+1], A23, B23);
      float e12 = fast_exp2(sfr1[4*g+2], A23, B23);
      float e13 = fast_exp2(sfr1[4*g+3], A23, B23);
      A0[g][0] = cvt_pk_bf16(e00, e01);
      A0[g][1] = cvt_pk_bf16(e02, e03);
      A1[g][0] = cvt_pk_bf16(e10, e11);
      A1[g][1] = cvt_pk_bf16(e12, e13);
    }

    // build P fragments in-register (T12): frag kk = {x'0, x'1, y'0, y'1}
    bf16x8 pf[4];
#pragma unroll
    for (int kkl = 0; kkl < 2; kkl++){
      unsigned int x0 = A0[2*kkl][0], y0 = A0[2*kkl+1][0];
      unsigned int x1 = A0[2*kkl][1], y1 = A0[2*kkl+1][1];
      plane_swap(x0, y0);
      plane_swap(x1, y1);
      u32x4 w = {x0, x1, y0, y1};
      pf[kkl] = __builtin_bit_cast(bf16x8, w);
      unsigned int z0 = A1[2*kkl][0], t0w = A1[2*kkl+1][0];
      unsigned int z1 = A1[2*kkl][1], t1w = A1[2*kkl+1][1];
      plane_swap(z0, t0w);
      plane_swap(z1, t1w);
      u32x4 w2 = {z0, z1, t0w, t1w};
      pf[2 + kkl] = __builtin_bit_cast(bf16x8, w2);
    }

    // O^T += V^T . P^T ; l-row-sum via ones-MFMA
    const us* VbC = &Vb[cur][0];
    __builtin_amdgcn_s_setprio(1);
#pragma unroll
    for (int kk = 0; kk < 4; kk++){
      bf16x8 av0 = *(const bf16x8*)&VbC[l31 * 72 + kk * 16 + h8];
      bf16x8 av1 = *(const bf16x8*)&VbC[(32 + l31) * 72 + kk * 16 + h8];
      acc0 = __builtin_amdgcn_mfma_f32_32x32x16_bf16(av0, pf[kk], acc0, 0, 0, 0);
      acc1 = __builtin_amdgcn_mfma_f32_32x32x16_bf16(av1, pf[kk], acc1, 0, 0, 0);
      accS = __builtin_amdgcn_mfma_f32_32x32x16_bf16(ones8, pf[kk], accS, 0, 0, 0);
    }
    __builtin_amdgcn_s_setprio(0);

    // stage next tile into the other buffer, then single barrier
    if (pre){
      const int nxt = cur ^ 1;
      *(uint4*)&Kb[nxt][kt0 * 72 + kd0] = rK0;
      *(uint4*)&Kb[nxt][kt1 * 72 + kd1] = rK1;
      *(uint4*)&Vb[nxt][kt0 * 72 + kd0] = rV0;
      *(uint4*)&Vb[nxt][kt1 * 72 + kd1] = rV1;
    }
    __syncthreads();
  }
#undef GK
#undef GV

  // unnormalized partial output + m/l scalars
  us* ap = accP + (size_t)tch * 4194304 + (size_t)(b * MM + qrow) * 1024 + hd;
#pragma unroll
  for (int g = 0; g < 4; g++){
    bf16x4 w0, w1;
#pragma unroll
    for (int j = 0; j < 4; j++){
      w0[j] = (__bf16)acc0[4 * g + j];
      w1[j] = (__bf16)acc1[4 * g + j];
    }
    *(u16x4*)&ap[8 * g + 4 * hb]      = __builtin_bit_cast(u16x4, w0);
    *(u16x4*)&ap[32 + 8 * g + 4 * hb] = __builtin_bit_cast(u16x4, w1);
  }
  if (hb == 0){
    int idx = tch * 65536 + (b * MM + qrow) * 16 + (hd >> 6);
    Mv[idx] = mrow;
    Lv[idx] = accS[0];
  }
}

// ---------------- combine the two T-chunk partials ----------------
__global__ __launch_bounds__(256) void combine_kernel(const us* __restrict__ accP,
                                                      const float* __restrict__ Mv,
                                                      const float* __restrict__ Lv,
                                                      us* __restrict__ attno){
  size_t i = ((size_t)blockIdx.x * 256 + threadIdx.x) * 8;
  size_t qg = i >> 10;
  int h = (int)((i & 1023) >> 6);
  size_t mi = qg * 16 + h;
  float m1 = Mv[mi], m2 = Mv[65536 + mi];
  float l1 = Lv[mi], l2 = Lv[65536 + mi];
  float m = fmaxf(m1, m2);
  float w1 = __builtin_amdgcn_exp2f(m1 - m);
  float w2 = __builtin_amdgcn_exp2f(m2 - m);
  float inv = 1.f / (w1 * l1 + w2 * l2);
  float s1 = w1 * inv, s2 = w2 * inv;
  u16x8 a1 = *(const u16x8*)(accP + i);
  u16x8 a2 = *(const u16x8*)(accP + 4194304 + i);
  u16x8 o;
#pragma unroll
  for (int j = 0; j < 8; j++)
    o[j] = f2bf(s1 * bf2f(a1[j]) + s2 * bf2f(a2[j]));
  *(u16x8*)(attno + i) = o;
}

extern "C" void kernel_launch(void* const* d_in, const int* in_sizes, int n_in,
                              void* d_out, int out_size, void* d_ws, size_t ws_size,
                              hipStream_t stream){
  const float* x      = (const float*)d_in[0];
  const float* data   = (const float*)d_in[1];
  const float* W_attn = (const float*)d_in[2];
  const float* b_attn = (const float*)d_in[3];
  const float* W_data = (const float*)d_in[4];
  const float* b_data = (const float*)d_in[5];
  const float* W_proj = (const float*)d_in[6];
  const float* b_proj = (const float*)d_in[7];
  float* out = (float*)d_out;

  char* ws = (char*)d_ws;
  us* xf    = (us*)(ws + 0);             // [2][2048][1024] fp16 (8 MB)
  us* df    = (us*)(ws + 8388608);       // [2][2048][1024] fp16 (8 MB)
  us* Watf  = (us*)(ws + 16777216);      // [3072][1024] fp16 (6 MB)
  us* Wdtf  = (us*)(ws + 23068672);      // [2048][1024] fp16 (4 MB)
  us* Wptb  = (us*)(ws + 27262976);      // [1024][1024] bf16 (2 MB)
  us* Qf    = (us*)(ws + 29360128);      // [2][2048][1024] fp16 (8 MB)
  us* Kf    = (us*)(ws + 37748736);      // [2][4096][1024] fp16 (16 MB)
  us* VT    = (us*)(ws + 54525952);      // [2][1024][4096] bf16 (16 MB)
  us* accP  = (us*)(ws + 71303168);      // 2 x [2][2048][1024] bf16 partials (16 MB)
  float* Mv = (float*)(ws + 88080384);   // 2 x 64K floats (512 KB)
  float* Lv = (float*)(ws + 88604672);   // 2 x 64K floats (512 KB)
  us* attno = (us*)(ws + 0);             // alias xf (dead after gemm_all)

  cast_f16_all<<<4096, 256, 0, stream>>>(x, data, xf, df);
  transpose_all<<<dim3(192, 32), 256, 0, stream>>>(W_attn, W_data, W_proj, Watf, Wdtf, Wptb);

  gemm_all<<<dim3(40, 32), 256, 0, stream>>>(xf, df, Watf, Wdtf,
                                             b_attn, b_data, Qf, Kf, VT);

  attn_kernel<<<1024, 256, 0, stream>>>(Qf, Kf, VT, accP, Mv, Lv);
  combine_kernel<<<2048, 256, 0, stream>>>(accP, Mv, Lv, attno);

  gemm_proj<<<dim3(16, 32), 256, 0, stream>>>(attno, Wptb, b_proj, out);
}

// Round 18
// 216.391 us; speedup vs baseline: 1.1228x; 1.0171x over previous
//
#include <hip/hip_runtime.h>

typedef __bf16 bf16x8 __attribute__((ext_vector_type(8)));
typedef __bf16 bf16x4 __attribute__((ext_vector_type(4)));
typedef _Float16 f16x8 __attribute__((ext_vector_type(8)));
typedef float f32x4 __attribute__((ext_vector_type(4)));
typedef float f32x16 __attribute__((ext_vector_type(16)));
typedef unsigned short u16x8 __attribute__((ext_vector_type(8)));
typedef unsigned short u16x4 __attribute__((ext_vector_type(4)));
typedef unsigned int u32x4 __attribute__((ext_vector_type(4)));
typedef unsigned short us;

#define MM 2048
#define TT 4096

__device__ __forceinline__ us f2bf(float f){
  unsigned int u = __builtin_bit_cast(unsigned int, f);
  u = (u + 0x7fffu + ((u >> 16) & 1u)) >> 16;
  return (us)u;
}
__device__ __forceinline__ float bf2f(us u){
  unsigned int x = ((unsigned int)u) << 16;
  return __builtin_bit_cast(float, x);
}
__device__ __forceinline__ us f2h(float f){
  _Float16 h = (_Float16)f;
  return __builtin_bit_cast(us, h);
}
__device__ __forceinline__ unsigned int cvt_pk_bf16(float lo, float hi){
  unsigned int r;
  asm("v_cvt_pk_bf16_f32 %0, %1, %2" : "=v"(r) : "v"(lo), "v"(hi));
  return r;
}
__device__ __forceinline__ void plane_swap(unsigned int &x, unsigned int &y){
  asm("v_permlane32_swap_b32 %0, %1" : "+v"(x), "+v"(y));
}
// Schraudolph 2^x, 2 full-rate VALU ops: fma + saturating cvt (neg -> 0 -> +0.0f).
__device__ __forceinline__ float fast_exp2(float s, float A23, float B23){
  float t = __builtin_fmaf(s, A23, B23);
  unsigned int u;
  asm("v_cvt_u32_f32 %0, %1" : "=v"(u) : "v"(t));
  return __builtin_bit_cast(float, u);
}

#define GLDS(gp, lp) __builtin_amdgcn_global_load_lds( \
    (const __attribute__((address_space(1))) unsigned int*)(gp), \
    (__attribute__((address_space(3))) unsigned int*)(lp), 16, 0, 0)

// ---------------- fused fp32 -> fp16 cast (x and data in one launch) ----------------
__global__ __launch_bounds__(256) void cast_f16_all(const float* __restrict__ x,
                                                    const float* __restrict__ data,
                                                    us* __restrict__ xf, us* __restrict__ df){
  int bid = blockIdx.x;
  const float* in; us* o;
  if (bid < 2048){ in = x; o = xf; }
  else           { in = data; o = df; bid -= 2048; }
  size_t i = ((size_t)bid * 256 + threadIdx.x) * 8;
  float4 a = *(const float4*)(in + i);
  float4 b = *(const float4*)(in + i + 4);
  float v[8] = {a.x,a.y,a.z,a.w,b.x,b.y,b.z,b.w};
  u16x8 r;
  for (int j = 0; j < 8; j++) r[j] = f2h(v[j]);
  *(u16x8*)(o + i) = r;
}

// ---------------- fused transpose for all three weights (attn/data fp16, proj bf16) ----------------
__global__ __launch_bounds__(256) void transpose_all(const float* __restrict__ W_attn,
                                                     const float* __restrict__ W_data,
                                                     const float* __restrict__ W_proj,
                                                     us* __restrict__ Af, us* __restrict__ Df,
                                                     us* __restrict__ Pb){
  __shared__ float tile[32][33];
  int bx = blockIdx.x;
  const float* W; us* o; int N; bool tobf;
  if (bx < 96){ W = W_attn; o = Af; N = 3072; tobf = false; }
  else if (bx < 160){ W = W_data; o = Df; N = 2048; bx -= 96; tobf = false; }
  else { W = W_proj; o = Pb; N = 1024; bx -= 160; tobf = true; }
  int tx = threadIdx.x & 31, ty = threadIdx.x >> 5;   // 32 x 8
  int n0 = bx * 32, k0 = blockIdx.y * 32;
  for (int r = 0; r < 32; r += 8)
    tile[ty + r][tx] = W[(size_t)(k0 + ty + r) * N + n0 + tx];
  __syncthreads();
  for (int r = 0; r < 32; r += 8){
    float v = tile[tx][ty + r];
    size_t idx = (size_t)(n0 + ty + r) * 1024 + k0 + tx;
    o[idx] = tobf ? f2bf(v) : f2h(v);
  }
}

// ---------------- merged projection GEMM, single-pass fp16 ----------------
// V epilogue: per-wave LDS transpose (Tv, stride 65 -> conflict-free column gather)
// then 128B-contiguous VT stores (was 8B/64B-sector scatter = 8x write amplification).
__global__ __launch_bounds__(256) void gemm_all(const us* __restrict__ xf, const us* __restrict__ df,
                                                const us* __restrict__ Watf, const us* __restrict__ Wdtf,
                                                const float* __restrict__ b_attn, const float* __restrict__ b_data,
                                                us* __restrict__ Qf, us* __restrict__ Kf,
                                                us* __restrict__ VT){
  __shared__ us sm[8192];         // A@0, B@4096
  __shared__ us Tv[4][64 * 65];   // V-epilogue transpose staging (33.3 KB)
  const int bx = blockIdx.x;
  const us *Ah, *Bth; const float* bias; int region, kroff, col0;
  if (bx < 24){
    Ah = xf; Bth = Watf; bias = b_attn;
    region = bx >> 3; kroff = 0; col0 = bx * 128;
  } else {
    int b2 = bx - 24;
    Ah = df; Bth = Wdtf; bias = b_data;
    region = 1 + (b2 >> 3); kroff = 2048; col0 = b2 * 128;
  }
  const int tid = threadIdx.x, wid = tid >> 6, lane = tid & 63;
  const int l15 = lane & 15, l16 = lane >> 4;
  const int row0 = blockIdx.y * 128;
  const int wr = (wid >> 1) * 64, wc = (wid & 1) * 64;
  f32x4 acc[4][4] = {};

  for (int k0 = 0; k0 < 1024; k0 += 32){
    for (int c = 0; c < 2; ++c){
      int i = c * 256 + tid;                           // 0..511: row=i>>2, k8=(i&3)*8
      size_t aoff = (size_t)(row0 + (i >> 2)) * 1024 + k0 + (i & 3) * 8;
      size_t boff = (size_t)(col0 + (i >> 2)) * 1024 + k0 + (i & 3) * 8;
      GLDS(Ah + aoff, &sm[c * 2048 + wid * 512]);
      GLDS(Bth + boff, &sm[4096 + c * 2048 + wid * 512]);
    }
    __syncthreads();
    f16x8 af[4], bf[4];
    for (int m = 0; m < 4; m++) af[m] = *(const f16x8*)&sm[(wr + m * 16 + l15) * 32 + l16 * 8];
    for (int n = 0; n < 4; n++) bf[n] = *(const f16x8*)&sm[4096 + (wc + n * 16 + l15) * 32 + l16 * 8];
    for (int m = 0; m < 4; m++)
      for (int n = 0; n < 4; n++)
        acc[m][n] = __builtin_amdgcn_mfma_f32_16x16x32_f16(af[m], bf[n], acc[m][n], 0, 0, 0);
    __syncthreads();
  }

  if (region == 2){
    // V: stage wave's 64x64 C-tile (with bias, bf16) into Tv[wid], then coalesced VT stores
    for (int m = 0; m < 4; m++)
      for (int n = 0; n < 4; n++){
        float bv = bias[col0 + wc + n * 16 + l15];
        for (int j = 0; j < 4; j++)
          Tv[wid][(m * 16 + l16 * 4 + j) * 65 + n * 16 + l15] = f2bf(acc[m][n][j] + bv);
      }
    __syncthreads();
    const int b2r = (row0 + wr) >> 11;
    const int t64 = kroff + ((row0 + wr) & 2047);
    const int d0  = (col0 + wc) & 1023;
    const int dl  = lane >> 2, tl = (lane & 3) * 16;
#pragma unroll
    for (int p = 0; p < 4; p++){
      int dloc = p * 16 + dl;
      u16x8 w0, w1;
#pragma unroll
      for (int i = 0; i < 8; i++){
        w0[i] = Tv[wid][(tl + i) * 65 + dloc];
        w1[i] = Tv[wid][(tl + 8 + i) * 65 + dloc];
      }
      us* dst = &VT[((size_t)(b2r * 1024 + d0 + dloc)) * 4096 + t64 + tl];
      *(u16x8*)dst = w0;
      *(u16x8*)(dst + 8) = w1;
    }
  } else {
    for (int m = 0; m < 4; m++)
      for (int n = 0; n < 4; n++){
        int gcol = col0 + wc + n * 16 + l15;
        int ocol = gcol & 1023;
        float bv = bias[gcol];
        us* P = (region == 0) ? Qf : Kf;
        for (int j = 0; j < 4; j++){
          int r = row0 + wr + m * 16 + l16 * 4 + j;
          size_t orow = (region == 0) ? (size_t)r
                                      : (size_t)((r >> 11) * 4096 + kroff + (r & 2047));
          P[orow * 1024 + ocol] = f2h(acc[m][n][j] + bv);
        }
      }
  }
}

// ---------------- output projection GEMM (bf16, fp32 out), 128x64 tile, 2 blocks/CU ----------------
__global__ __launch_bounds__(256) void gemm_proj(const us* __restrict__ Ah,
                                                 const us* __restrict__ Bth,
                                                 const float* __restrict__ bias,
                                                 float* __restrict__ Co){
  __shared__ us sm[12288];   // A [128][32] @0 (8192), B [64][32] @8192 (4096)
  const int tid = threadIdx.x, wid = tid >> 6, lane = tid & 63;
  const int l15 = lane & 15, l16 = lane >> 4;
  const int row0 = blockIdx.y * 128, col0 = blockIdx.x * 64;
  const int wr = (wid >> 1) * 64, wc = (wid & 1) * 32;
  f32x4 acc[4][2] = {};

  for (int k0 = 0; k0 < 1024; k0 += 32){
    for (int c = 0; c < 2; ++c){
      int i = c * 256 + tid;
      size_t aoff = (size_t)(row0 + (i >> 2)) * 1024 + k0 + (i & 3) * 8;
      GLDS(Ah + aoff, &sm[c * 2048 + wid * 512]);
    }
    {
      size_t boff = (size_t)(col0 + (tid >> 2)) * 1024 + k0 + (tid & 3) * 8;
      GLDS(Bth + boff, &sm[8192 + wid * 512]);
    }
    __syncthreads();
    bf16x8 afh[4], bfh[2];
    for (int m = 0; m < 4; m++) afh[m] = *(const bf16x8*)&sm[(wr + m * 16 + l15) * 32 + l16 * 8];
    for (int n = 0; n < 2; n++) bfh[n] = *(const bf16x8*)&sm[8192 + (wc + n * 16 + l15) * 32 + l16 * 8];
    for (int m = 0; m < 4; m++)
      for (int n = 0; n < 2; n++)
        acc[m][n] = __builtin_amdgcn_mfma_f32_16x16x32_bf16(afh[m], bfh[n], acc[m][n], 0, 0, 0);
    __syncthreads();
  }

  for (int m = 0; m < 4; m++)
    for (int n = 0; n < 2; n++){
      int col = col0 + wc + n * 16 + l15;
      float bv = bias[col];
      for (int j = 0; j < 4; j++){
        int r = row0 + wr + m * 16 + l16 * 4 + j;
        Co[(size_t)r * 1024 + col] = acc[m][n][j] + bv;
      }
    }
}

// ---------------- fused attention (R16, unchanged) ----------------
__global__ __launch_bounds__(256, 4) void attn_kernel(const us* __restrict__ Qf,
                                                      const us* __restrict__ Kf,
                                                      const us* __restrict__ VT,
                                                      us* __restrict__ accP,
                                                      float* __restrict__ Mv, float* __restrict__ Lv){
  __shared__ us Kb[2][64 * 72];        // [dbuf][64 t][72] fp16
  __shared__ us Vb[2][64 * 72];        // [dbuf][64 d][72] bf16 (V^T tile)
  const int tid = threadIdx.x, wid = tid >> 6, lane = tid & 63;
  const int l31 = lane & 31, hb = lane >> 5, h8 = hb * 8;
  const int bid = blockIdx.x;
  const int swz = (bid & 7) * 128 + (bid >> 3);   // bijective, 1024 = 8*128
  const int qt = swz & 15;                    // M/128 = 16
  const int bh = (swz >> 4) & 31;
  const int tch = swz >> 9;                   // T-chunk 0/1
  const int hd = (bh & 15) * 64, b = bh >> 4;
  const int qrow = qt * 128 + wid * 32 + l31;
  const int tbase = tch * 2048, tend = tbase + 2048;

  // Q fragments (B operand): lane holds Q[qrow][d = kk*16 + h8 + i], fp16
  f16x8 qf[4];
  {
    const us* qp = Qf + (size_t)(b * MM + qrow) * 1024 + hd;
#pragma unroll
    for (int kk = 0; kk < 4; kk++)
      qf[kk] = *(const f16x8*)(qp + kk * 16 + h8);
  }

  // all-ones bf16 A-fragment for the l row-sum MFMA
  u16x8 ones_u;
#pragma unroll
  for (int j = 0; j < 8; j++) ones_u[j] = 0x3F80;
  const bf16x8 ones8 = __builtin_bit_cast(bf16x8, ones_u);

  const int i0 = tid, i1 = 256 + tid;
  const int kt0 = i0 >> 3, kd0 = (i0 & 7) * 8;
  const int kt1 = i1 >> 3, kd1 = (i1 & 7) * 8;

#define GK(t0_, t_, d_) (((size_t)(b * TT + (t0_) + (t_))) * 1024 + hd + (d_))
#define GV(t0_, d_, t_) (((size_t)b * 1024 + hd + (d_)) * 4096 + (t0_) + (t_))

  // prologue: stage K,V tile tbase into buf 0
  uint4 rK0 = *(const uint4*)(Kf + GK(tbase, kt0, kd0));
  uint4 rK1 = *(const uint4*)(Kf + GK(tbase, kt1, kd1));
  uint4 rV0 = *(const uint4*)(VT + GV(tbase, kt0, kd0));
  uint4 rV1 = *(const uint4*)(VT + GV(tbase, kt1, kd1));
  *(uint4*)&Kb[0][kt0 * 72 + kd0] = rK0;
  *(uint4*)&Kb[0][kt1 * 72 + kd1] = rK1;
  *(uint4*)&Vb[0][kt0 * 72 + kd0] = rV0;
  *(uint4*)&Vb[0][kt1 * 72 + kd1] = rV1;
  __syncthreads();

  // strength-reduced prefetch pointers (next tile)
  const us* pK0 = Kf + GK(tbase + 64, kt0, kd0);
  const us* pK1 = Kf + GK(tbase + 64, kt1, kd1);
  const us* pV0 = VT + GV(tbase + 64, kt0, kd0);
  const us* pV1 = VT + GV(tbase + 64, kt1, kd1);

  f32x16 acc0 = {}, acc1 = {}, accS = {};
  float mrow = -1e30f;
  const float cs  = 0.125f * 1.44269504088896f;    // to log2 domain
  const float A23 = cs * 8388608.0f;               // cs * 2^23
  float B23 = 0.f;                                 // set on first defer-max trigger (tile 0)

  for (int t0 = tbase; t0 < tend; t0 += 64){
    const int cur = (t0 >> 6) & 1;
    const bool pre = (t0 + 64 < tend);
    if (pre){
      rK0 = *(const uint4*)pK0; pK0 += 64 * 1024;
      rK1 = *(const uint4*)pK1; pK1 += 64 * 1024;
      rV0 = *(const uint4*)pV0; pV0 += 64;
      rV1 = *(const uint4*)pV1; pV1 += 64;
    }

    // S^T = K . Q^T (fp16): frag ts holds t = ts*32 + tloc, q = l31
    const us* KbC = &Kb[cur][0];
    f32x16 sfr0 = {}, sfr1 = {};
    __builtin_amdgcn_s_setprio(1);
#pragma unroll
    for (int kk = 0; kk < 4; kk++){
      f16x8 a0 = *(const f16x8*)&KbC[l31 * 72 + kk * 16 + h8];
      f16x8 a1 = *(const f16x8*)&KbC[(32 + l31) * 72 + kk * 16 + h8];
      sfr0 = __builtin_amdgcn_mfma_f32_32x32x16_f16(a0, qf[kk], sfr0, 0, 0, 0);
      sfr1 = __builtin_amdgcn_mfma_f32_32x32x16_f16(a1, qf[kk], sfr1, 0, 0, 0);
    }
    __builtin_amdgcn_s_setprio(0);

    // tile max via two max3 chains (T17)
    float va = -1e30f, vb2 = -1e30f;
#pragma unroll
    for (int r = 0; r < 16; r += 2){
      va  = fmaxf(fmaxf(sfr0[r],     sfr1[r]),     va);
      vb2 = fmaxf(fmaxf(sfr0[r + 1], sfr1[r + 1]), vb2);
    }
    float v = fmaxf(va, vb2);
    float vs = v * cs;
    vs = fmaxf(vs, __shfl_xor(vs, 32, 64));
    if (!__all(vs <= mrow + 8.f)){      // T13 defer-max (always taken on tile 0)
      float mn = fmaxf(mrow, vs);
      float rs = __builtin_amdgcn_exp2f(mrow - mn);
      mrow = mn;
      B23 = __builtin_fmaf(mrow, -8388608.0f, 1065103216.0f);
#pragma unroll
      for (int r = 0; r < 16; r++){ acc0[r] *= rs; acc1[r] *= rs; accS[r] *= rs; }
    }
    unsigned int A0[4][2], A1[4][2];
#pragma unroll
    for (int g = 0; g < 4; g++){
      float e00 = fast_exp2(sfr0[4*g+0], A23, B23);
      float e01 = fast_exp2(sfr0[4*g+1], A23, B23);
      float e02 = fast_exp2(sfr0[4*g+2], A23, B23);
      float e03 = fast_exp2(sfr0[4*g+3], A23, B23);
      float e10 = fast_exp2(sfr1[4*g+0], A23, B23);
      float e11 = fast_exp2(sfr1[4*g+1], A23, B23);
      float e12 = fast_exp2(sfr1[4*g+2], A23, B23);
      float e13 = fast_exp2(sfr1[4*g+3], A23, B23);
      A0[g][0] = cvt_pk_bf16(e00, e01);
      A0[g][1] = cvt_pk_bf16(e02, e03);
      A1[g][0] = cvt_pk_bf16(e10, e11);
      A1[g][1] = cvt_pk_bf16(e12, e13);
    }

    // build P fragments in-register (T12): frag kk = {x'0, x'1, y'0, y'1}
    bf16x8 pf[4];
#pragma unroll
    for (int kkl = 0; kkl < 2; kkl++){
      unsigned int x0 = A0[2*kkl][0], y0 = A0[2*kkl+1][0];
      unsigned int x1 = A0[2*kkl][1], y1 = A0[2*kkl+1][1];
      plane_swap(x0, y0);
      plane_swap(x1, y1);
      u32x4 w = {x0, x1, y0, y1};
      pf[kkl] = __builtin_bit_cast(bf16x8, w);
      unsigned int z0 = A1[2*kkl][0], t0w = A1[2*kkl+1][0];
      unsigned int z1 = A1[2*kkl][1], t1w = A1[2*kkl+1][1];
      plane_swap(z0, t0w);
      plane_swap(z1, t1w);
      u32x4 w2 = {z0, z1, t0w, t1w};
      pf[2 + kkl] = __builtin_bit_cast(bf16x8, w2);
    }

    // O^T += V^T . P^T ; l-row-sum via ones-MFMA
    const us* VbC = &Vb[cur][0];
    __builtin_amdgcn_s_setprio(1);
#pragma unroll
    for (int kk = 0; kk < 4; kk++){
      bf16x8 av0 = *(const bf16x8*)&VbC[l31 * 72 + kk * 16 + h8];
      bf16x8 av1 = *(const bf16x8*)&VbC[(32 + l31) * 72 + kk * 16 + h8];
      acc0 = __builtin_amdgcn_mfma_f32_32x32x16_bf16(av0, pf[kk], acc0, 0, 0, 0);
      acc1 = __builtin_amdgcn_mfma_f32_32x32x16_bf16(av1, pf[kk], acc1, 0, 0, 0);
      accS = __builtin_amdgcn_mfma_f32_32x32x16_bf16(ones8, pf[kk], accS, 0, 0, 0);
    }
    __builtin_amdgcn_s_setprio(0);

    // stage next tile into the other buffer, then single barrier
    if (pre){
      const int nxt = cur ^ 1;
      *(uint4*)&Kb[nxt][kt0 * 72 + kd0] = rK0;
      *(uint4*)&Kb[nxt][kt1 * 72 + kd1] = rK1;
      *(uint4*)&Vb[nxt][kt0 * 72 + kd0] = rV0;
      *(uint4*)&Vb[nxt][kt1 * 72 + kd1] = rV1;
    }
    __syncthreads();
  }
#undef GK
#undef GV

  // unnormalized partial output + m/l scalars
  us* ap = accP + (size_t)tch * 4194304 + (size_t)(b * MM + qrow) * 1024 + hd;
#pragma unroll
  for (int g = 0; g < 4; g++){
    bf16x4 w0, w1;
#pragma unroll
    for (int j = 0; j < 4; j++){
      w0[j] = (__bf16)acc0[4 * g + j];
      w1[j] = (__bf16)acc1[4 * g + j];
    }
    *(u16x4*)&ap[8 * g + 4 * hb]      = __builtin_bit_cast(u16x4, w0);
    *(u16x4*)&ap[32 + 8 * g + 4 * hb] = __builtin_bit_cast(u16x4, w1);
  }
  if (hb == 0){
    int idx = tch * 65536 + (b * MM + qrow) * 16 + (hd >> 6);
    Mv[idx] = mrow;
    Lv[idx] = accS[0];
  }
}

// ---------------- combine the two T-chunk partials ----------------
__global__ __launch_bounds__(256) void combine_kernel(const us* __restrict__ accP,
                                                      const float* __restrict__ Mv,
                                                      const float* __restrict__ Lv,
                                                      us* __restrict__ attno){
  size_t i = ((size_t)blockIdx.x * 256 + threadIdx.x) * 8;
  size_t qg = i >> 10;
  int h = (int)((i & 1023) >> 6);
  size_t mi = qg * 16 + h;
  float m1 = Mv[mi], m2 = Mv[65536 + mi];
  float l1 = Lv[mi], l2 = Lv[65536 + mi];
  float m = fmaxf(m1, m2);
  float w1 = __builtin_amdgcn_exp2f(m1 - m);
  float w2 = __builtin_amdgcn_exp2f(m2 - m);
  float inv = 1.f / (w1 * l1 + w2 * l2);
  float s1 = w1 * inv, s2 = w2 * inv;
  u16x8 a1 = *(const u16x8*)(accP + i);
  u16x8 a2 = *(const u16x8*)(accP + 4194304 + i);
  u16x8 o;
#pragma unroll
  for (int j = 0; j < 8; j++)
    o[j] = f2bf(s1 * bf2f(a1[j]) + s2 * bf2f(a2[j]));
  *(u16x8*)(attno + i) = o;
}

extern "C" void kernel_launch(void* const* d_in, const int* in_sizes, int n_in,
                              void* d_out, int out_size, void* d_ws, size_t ws_size,
                              hipStream_t stream){
  const float* x      = (const float*)d_in[0];
  const float* data   = (const float*)d_in[1];
  const float* W_attn = (const float*)d_in[2];
  const float* b_attn = (const float*)d_in[3];
  const float* W_data = (const float*)d_in[4];
  const float* b_data = (const float*)d_in[5];
  const float* W_proj = (const float*)d_in[6];
  const float* b_proj = (const float*)d_in[7];
  float* out = (float*)d_out;

  char* ws = (char*)d_ws;
  us* xf    = (us*)(ws + 0);             // [2][2048][1024] fp16 (8 MB)
  us* df    = (us*)(ws + 8388608);       // [2][2048][1024] fp16 (8 MB)
  us* Watf  = (us*)(ws + 16777216);      // [3072][1024] fp16 (6 MB)
  us* Wdtf  = (us*)(ws + 23068672);      // [2048][1024] fp16 (4 MB)
  us* Wptb  = (us*)(ws + 27262976);      // [1024][1024] bf16 (2 MB)
  us* Qf    = (us*)(ws + 29360128);      // [2][2048][1024] fp16 (8 MB)
  us* Kf    = (us*)(ws + 37748736);      // [2][4096][1024] fp16 (16 MB)
  us* VT    = (us*)(ws + 54525952);      // [2][1024][4096] bf16 (16 MB)
  us* accP  = (us*)(ws + 71303168);      // 2 x [2][2048][1024] bf16 partials (16 MB)
  float* Mv = (float*)(ws + 88080384);   // 2 x 64K floats (512 KB)
  float* Lv = (float*)(ws + 88604672);   // 2 x 64K floats (512 KB)
  us* attno = (us*)(ws + 0);             // alias xf (dead after gemm_all)

  cast_f16_all<<<4096, 256, 0, stream>>>(x, data, xf, df);
  transpose_all<<<dim3(192, 32), 256, 0, stream>>>(W_attn, W_data, W_proj, Watf, Wdtf, Wptb);

  gemm_all<<<dim3(40, 32), 256, 0, stream>>>(xf, df, Watf, Wdtf,
                                             b_attn, b_data, Qf, Kf, VT);

  attn_kernel<<<1024, 256, 0, stream>>>(Qf, Kf, VT, accP, Mv, Lv);
  combine_kernel<<<2048, 256, 0, stream>>>(accP, Mv, Lv, attno);

  gemm_proj<<<dim3(16, 32), 256, 0, stream>>>(attno, Wptb, b_proj, out);
}

// Round 19
// 214.556 us; speedup vs baseline: 1.1324x; 1.0086x over previous
//
#include <hip/hip_runtime.h>

typedef __bf16 bf16x8 __attribute__((ext_vector_type(8)));
typedef __bf16 bf16x4 __attribute__((ext_vector_type(4)));
typedef _Float16 f16x8 __attribute__((ext_vector_type(8)));
typedef float f32x4 __attribute__((ext_vector_type(4)));
typedef float f32x16 __attribute__((ext_vector_type(16)));
typedef unsigned short u16x8 __attribute__((ext_vector_type(8)));
typedef unsigned short u16x4 __attribute__((ext_vector_type(4)));
typedef unsigned int u32x4 __attribute__((ext_vector_type(4)));
typedef unsigned short us;

#define MM 2048
#define TT 4096

__device__ __forceinline__ us f2bf(float f){
  unsigned int u = __builtin_bit_cast(unsigned int, f);
  u = (u + 0x7fffu + ((u >> 16) & 1u)) >> 16;
  return (us)u;
}
__device__ __forceinline__ float bf2f(us u){
  unsigned int x = ((unsigned int)u) << 16;
  return __builtin_bit_cast(float, x);
}
__device__ __forceinline__ us f2h(float f){
  _Float16 h = (_Float16)f;
  return __builtin_bit_cast(us, h);
}
__device__ __forceinline__ unsigned int cvt_pk_bf16(float lo, float hi){
  unsigned int r;
  asm("v_cvt_pk_bf16_f32 %0, %1, %2" : "=v"(r) : "v"(lo), "v"(hi));
  return r;
}
__device__ __forceinline__ void plane_swap(unsigned int &x, unsigned int &y){
  asm("v_permlane32_swap_b32 %0, %1" : "+v"(x), "+v"(y));
}
// Schraudolph 2^x, 2 full-rate VALU ops: fma + saturating cvt (neg -> 0 -> +0.0f).
__device__ __forceinline__ float fast_exp2(float s, float A23, float B23){
  float t = __builtin_fmaf(s, A23, B23);
  unsigned int u;
  asm("v_cvt_u32_f32 %0, %1" : "=v"(u) : "v"(t));
  return __builtin_bit_cast(float, u);
}

#define GLDS(gp, lp) __builtin_amdgcn_global_load_lds( \
    (const __attribute__((address_space(1))) unsigned int*)(gp), \
    (__attribute__((address_space(3))) unsigned int*)(lp), 16, 0, 0)

// ---------------- fused prep: fp32->fp16 cast (x,data) + weight transposes, one launch ----------------
// blocks [0,4096): cast; [4096, 10240): transpose (flattened 192 x 32).
__global__ __launch_bounds__(256) void prep_all(const float* __restrict__ x,
                                                const float* __restrict__ data,
                                                const float* __restrict__ W_attn,
                                                const float* __restrict__ W_data,
                                                const float* __restrict__ W_proj,
                                                us* __restrict__ xf, us* __restrict__ df,
                                                us* __restrict__ Af, us* __restrict__ Df,
                                                us* __restrict__ Pb){
  __shared__ float tile[32][33];
  int bid = blockIdx.x;
  if (bid < 4096){
    const float* in; us* o;
    if (bid < 2048){ in = x; o = xf; }
    else           { in = data; o = df; bid -= 2048; }
    size_t i = ((size_t)bid * 256 + threadIdx.x) * 8;
    float4 a = *(const float4*)(in + i);
    float4 b = *(const float4*)(in + i + 4);
    float v[8] = {a.x,a.y,a.z,a.w,b.x,b.y,b.z,b.w};
    u16x8 r;
    for (int j = 0; j < 8; j++) r[j] = f2h(v[j]);
    *(u16x8*)(o + i) = r;
    return;
  }
  int blk = bid - 4096;
  int bx = blk % 192;
  int k0 = (blk / 192) * 32;
  const float* W; us* o; int N; bool tobf;
  if (bx < 96){ W = W_attn; o = Af; N = 3072; tobf = false; }
  else if (bx < 160){ W = W_data; o = Df; N = 2048; bx -= 96; tobf = false; }
  else { W = W_proj; o = Pb; N = 1024; bx -= 160; tobf = true; }
  int tx = threadIdx.x & 31, ty = threadIdx.x >> 5;   // 32 x 8
  int n0 = bx * 32;
  for (int r = 0; r < 32; r += 8)
    tile[ty + r][tx] = W[(size_t)(k0 + ty + r) * N + n0 + tx];
  __syncthreads();
  for (int r = 0; r < 32; r += 8){
    float v = tile[tx][ty + r];
    size_t idx = (size_t)(n0 + ty + r) * 1024 + k0 + tx;
    o[idx] = tobf ? f2bf(v) : f2h(v);
  }
}

// ---------------- merged projection GEMM, single-pass fp16 ----------------
// LDS: single 33.3KB buffer; first 16KB = A/B staging during K-loop, whole = Tv transpose
// staging in the V epilogue (disjoint in time; per-wave Tv regions). 4 blocks/CU.
__global__ __launch_bounds__(256) void gemm_all(const us* __restrict__ xf, const us* __restrict__ df,
                                                const us* __restrict__ Watf, const us* __restrict__ Wdtf,
                                                const float* __restrict__ b_attn, const float* __restrict__ b_data,
                                                us* __restrict__ Qf, us* __restrict__ Kf,
                                                us* __restrict__ VT){
  __shared__ us shm[16640];       // loop: A@0 (4096), B@4096 (4096); epilogue: Tv[4][64*65]
  us* sm = shm;
  const int bx = blockIdx.x;
  const us *Ah, *Bth; const float* bias; int region, kroff, col0;
  if (bx < 24){
    Ah = xf; Bth = Watf; bias = b_attn;
    region = bx >> 3; kroff = 0; col0 = bx * 128;
  } else {
    int b2 = bx - 24;
    Ah = df; Bth = Wdtf; bias = b_data;
    region = 1 + (b2 >> 3); kroff = 2048; col0 = b2 * 128;
  }
  const int tid = threadIdx.x, wid = tid >> 6, lane = tid & 63;
  const int l15 = lane & 15, l16 = lane >> 4;
  const int row0 = blockIdx.y * 128;
  const int wr = (wid >> 1) * 64, wc = (wid & 1) * 64;
  f32x4 acc[4][4] = {};

  for (int k0 = 0; k0 < 1024; k0 += 32){
    for (int c = 0; c < 2; ++c){
      int i = c * 256 + tid;                           // 0..511: row=i>>2, k8=(i&3)*8
      size_t aoff = (size_t)(row0 + (i >> 2)) * 1024 + k0 + (i & 3) * 8;
      size_t boff = (size_t)(col0 + (i >> 2)) * 1024 + k0 + (i & 3) * 8;
      GLDS(Ah + aoff, &sm[c * 2048 + wid * 512]);
      GLDS(Bth + boff, &sm[4096 + c * 2048 + wid * 512]);
    }
    __syncthreads();
    f16x8 af[4], bf[4];
    for (int m = 0; m < 4; m++) af[m] = *(const f16x8*)&sm[(wr + m * 16 + l15) * 32 + l16 * 8];
    for (int n = 0; n < 4; n++) bf[n] = *(const f16x8*)&sm[4096 + (wc + n * 16 + l15) * 32 + l16 * 8];
    for (int m = 0; m < 4; m++)
      for (int n = 0; n < 4; n++)
        acc[m][n] = __builtin_amdgcn_mfma_f32_16x16x32_f16(af[m], bf[n], acc[m][n], 0, 0, 0);
    __syncthreads();
  }

  if (region == 2){
    // V: stage wave's 64x64 C-tile (with bias, bf16) into Tv region, then coalesced VT stores
    us* Tv = &shm[wid * 4160];   // [64][65]
    for (int m = 0; m < 4; m++)
      for (int n = 0; n < 4; n++){
        float bv = bias[col0 + wc + n * 16 + l15];
        for (int j = 0; j < 4; j++)
          Tv[(m * 16 + l16 * 4 + j) * 65 + n * 16 + l15] = f2bf(acc[m][n][j] + bv);
      }
    __syncthreads();
    const int b2r = (row0 + wr) >> 11;
    const int t64 = kroff + ((row0 + wr) & 2047);
    const int d0  = (col0 + wc) & 1023;
    const int dl  = lane >> 2, tl = (lane & 3) * 16;
#pragma unroll
    for (int p = 0; p < 4; p++){
      int dloc = p * 16 + dl;
      u16x8 w0, w1;
#pragma unroll
      for (int i = 0; i < 8; i++){
        w0[i] = Tv[(tl + i) * 65 + dloc];
        w1[i] = Tv[(tl + 8 + i) * 65 + dloc];
      }
      us* dst = &VT[((size_t)(b2r * 1024 + d0 + dloc)) * 4096 + t64 + tl];
      *(u16x8*)dst = w0;
      *(u16x8*)(dst + 8) = w1;
    }
  } else {
    for (int m = 0; m < 4; m++)
      for (int n = 0; n < 4; n++){
        int gcol = col0 + wc + n * 16 + l15;
        int ocol = gcol & 1023;
        float bv = bias[gcol];
        us* P = (region == 0) ? Qf : Kf;
        for (int j = 0; j < 4; j++){
          int r = row0 + wr + m * 16 + l16 * 4 + j;
          size_t orow = (region == 0) ? (size_t)r
                                      : (size_t)((r >> 11) * 4096 + kroff + (r & 2047));
          P[orow * 1024 + ocol] = f2h(acc[m][n][j] + bv);
        }
      }
  }
}

// ---------------- output projection GEMM (bf16, fp32 out), 128x64 tile, 2 blocks/CU ----------------
__global__ __launch_bounds__(256) void gemm_proj(const us* __restrict__ Ah,
                                                 const us* __restrict__ Bth,
                                                 const float* __restrict__ bias,
                                                 float* __restrict__ Co){
  __shared__ us sm[12288];   // A [128][32] @0 (8192), B [64][32] @8192 (4096)
  const int tid = threadIdx.x, wid = tid >> 6, lane = tid & 63;
  const int l15 = lane & 15, l16 = lane >> 4;
  const int row0 = blockIdx.y * 128, col0 = blockIdx.x * 64;
  const int wr = (wid >> 1) * 64, wc = (wid & 1) * 32;
  f32x4 acc[4][2] = {};

  for (int k0 = 0; k0 < 1024; k0 += 32){
    for (int c = 0; c < 2; ++c){
      int i = c * 256 + tid;
      size_t aoff = (size_t)(row0 + (i >> 2)) * 1024 + k0 + (i & 3) * 8;
      GLDS(Ah + aoff, &sm[c * 2048 + wid * 512]);
    }
    {
      size_t boff = (size_t)(col0 + (tid >> 2)) * 1024 + k0 + (tid & 3) * 8;
      GLDS(Bth + boff, &sm[8192 + wid * 512]);
    }
    __syncthreads();
    bf16x8 afh[4], bfh[2];
    for (int m = 0; m < 4; m++) afh[m] = *(const bf16x8*)&sm[(wr + m * 16 + l15) * 32 + l16 * 8];
    for (int n = 0; n < 2; n++) bfh[n] = *(const bf16x8*)&sm[8192 + (wc + n * 16 + l15) * 32 + l16 * 8];
    for (int m = 0; m < 4; m++)
      for (int n = 0; n < 2; n++)
        acc[m][n] = __builtin_amdgcn_mfma_f32_16x16x32_bf16(afh[m], bfh[n], acc[m][n], 0, 0, 0);
    __syncthreads();
  }

  for (int m = 0; m < 4; m++)
    for (int n = 0; n < 2; n++){
      int col = col0 + wc + n * 16 + l15;
      float bv = bias[col];
      for (int j = 0; j < 4; j++){
        int r = row0 + wr + m * 16 + l16 * 4 + j;
        Co[(size_t)r * 1024 + col] = acc[m][n][j] + bv;
      }
    }
}

// ---------------- fused attention (R16, unchanged) ----------------
__global__ __launch_bounds__(256, 4) void attn_kernel(const us* __restrict__ Qf,
                                                      const us* __restrict__ Kf,
                                                      const us* __restrict__ VT,
                                                      us* __restrict__ accP,
                                                      float* __restrict__ Mv, float* __restrict__ Lv){
  __shared__ us Kb[2][64 * 72];        // [dbuf][64 t][72] fp16
  __shared__ us Vb[2][64 * 72];        // [dbuf][64 d][72] bf16 (V^T tile)
  const int tid = threadIdx.x, wid = tid >> 6, lane = tid & 63;
  const int l31 = lane & 31, hb = lane >> 5, h8 = hb * 8;
  const int bid = blockIdx.x;
  const int swz = (bid & 7) * 128 + (bid >> 3);   // bijective, 1024 = 8*128
  const int qt = swz & 15;                    // M/128 = 16
  const int bh = (swz >> 4) & 31;
  const int tch = swz >> 9;                   // T-chunk 0/1
  const int hd = (bh & 15) * 64, b = bh >> 4;
  const int qrow = qt * 128 + wid * 32 + l31;
  const int tbase = tch * 2048, tend = tbase + 2048;

  // Q fragments (B operand): lane holds Q[qrow][d = kk*16 + h8 + i], fp16
  f16x8 qf[4];
  {
    const us* qp = Qf + (size_t)(b * MM + qrow) * 1024 + hd;
#pragma unroll
    for (int kk = 0; kk < 4; kk++)
      qf[kk] = *(const f16x8*)(qp + kk * 16 + h8);
  }

  // all-ones bf16 A-fragment for the l row-sum MFMA
  u16x8 ones_u;
#pragma unroll
  for (int j = 0; j < 8; j++) ones_u[j] = 0x3F80;
  const bf16x8 ones8 = __builtin_bit_cast(bf16x8, ones_u);

  const int i0 = tid, i1 = 256 + tid;
  const int kt0 = i0 >> 3, kd0 = (i0 & 7) * 8;
  const int kt1 = i1 >> 3, kd1 = (i1 & 7) * 8;

#define GK(t0_, t_, d_) (((size_t)(b * TT + (t0_) + (t_))) * 1024 + hd + (d_))
#define GV(t0_, d_, t_) (((size_t)b * 1024 + hd + (d_)) * 4096 + (t0_) + (t_))

  // prologue: stage K,V tile tbase into buf 0
  uint4 rK0 = *(const uint4*)(Kf + GK(tbase, kt0, kd0));
  uint4 rK1 = *(const uint4*)(Kf + GK(tbase, kt1, kd1));
  uint4 rV0 = *(const uint4*)(VT + GV(tbase, kt0, kd0));
  uint4 rV1 = *(const uint4*)(VT + GV(tbase, kt1, kd1));
  *(uint4*)&Kb[0][kt0 * 72 + kd0] = rK0;
  *(uint4*)&Kb[0][kt1 * 72 + kd1] = rK1;
  *(uint4*)&Vb[0][kt0 * 72 + kd0] = rV0;
  *(uint4*)&Vb[0][kt1 * 72 + kd1] = rV1;
  __syncthreads();

  // strength-reduced prefetch pointers (next tile)
  const us* pK0 = Kf + GK(tbase + 64, kt0, kd0);
  const us* pK1 = Kf + GK(tbase + 64, kt1, kd1);
  const us* pV0 = VT + GV(tbase + 64, kt0, kd0);
  const us* pV1 = VT + GV(tbase + 64, kt1, kd1);

  f32x16 acc0 = {}, acc1 = {}, accS = {};
  float mrow = -1e30f;
  const float cs  = 0.125f * 1.44269504088896f;    // to log2 domain
  const float A23 = cs * 8388608.0f;               // cs * 2^23
  float B23 = 0.f;                                 // set on first defer-max trigger (tile 0)

  for (int t0 = tbase; t0 < tend; t0 += 64){
    const int cur = (t0 >> 6) & 1;
    const bool pre = (t0 + 64 < tend);
    if (pre){
      rK0 = *(const uint4*)pK0; pK0 += 64 * 1024;
      rK1 = *(const uint4*)pK1; pK1 += 64 * 1024;
      rV0 = *(const uint4*)pV0; pV0 += 64;
      rV1 = *(const uint4*)pV1; pV1 += 64;
    }

    // S^T = K . Q^T (fp16): frag ts holds t = ts*32 + tloc, q = l31
    const us* KbC = &Kb[cur][0];
    f32x16 sfr0 = {}, sfr1 = {};
    __builtin_amdgcn_s_setprio(1);
#pragma unroll
    for (int kk = 0; kk < 4; kk++){
      f16x8 a0 = *(const f16x8*)&KbC[l31 * 72 + kk * 16 + h8];
      f16x8 a1 = *(const f16x8*)&KbC[(32 + l31) * 72 + kk * 16 + h8];
      sfr0 = __builtin_amdgcn_mfma_f32_32x32x16_f16(a0, qf[kk], sfr0, 0, 0, 0);
      sfr1 = __builtin_amdgcn_mfma_f32_32x32x16_f16(a1, qf[kk], sfr1, 0, 0, 0);
    }
    __builtin_amdgcn_s_setprio(0);

    // tile max via two max3 chains (T17)
    float va = -1e30f, vb2 = -1e30f;
#pragma unroll
    for (int r = 0; r < 16; r += 2){
      va  = fmaxf(fmaxf(sfr0[r],     sfr1[r]),     va);
      vb2 = fmaxf(fmaxf(sfr0[r + 1], sfr1[r + 1]), vb2);
    }
    float v = fmaxf(va, vb2);
    float vs = v * cs;
    vs = fmaxf(vs, __shfl_xor(vs, 32, 64));
    if (!__all(vs <= mrow + 8.f)){      // T13 defer-max (always taken on tile 0)
      float mn = fmaxf(mrow, vs);
      float rs = __builtin_amdgcn_exp2f(mrow - mn);
      mrow = mn;
      B23 = __builtin_fmaf(mrow, -8388608.0f, 1065103216.0f);
#pragma unroll
      for (int r = 0; r < 16; r++){ acc0[r] *= rs; acc1[r] *= rs; accS[r] *= rs; }
    }
    unsigned int A0[4][2], A1[4][2];
#pragma unroll
    for (int g = 0; g < 4; g++){
      float e00 = fast_exp2(sfr0[4*g+0], A23, B23);
      float e01 = fast_exp2(sfr0[4*g+1], A23, B23);
      float e02 = fast_exp2(sfr0[4*g+2], A23, B23);
      float e03 = fast_exp2(sfr0[4*g+3], A23, B23);
      float e10 = fast_exp2(sfr1[4*g+0], A23, B23);
      float e11 = fast_exp2(sfr1[4*g+1], A23, B23);
      float e12 = fast_exp2(sfr1[4*g+2], A23, B23);
      float e13 = fast_exp2(sfr1[4*g+3], A23, B23);
      A0[g][0] = cvt_pk_bf16(e00, e01);
      A0[g][1] = cvt_pk_bf16(e02, e03);
      A1[g][0] = cvt_pk_bf16(e10, e11);
      A1[g][1] = cvt_pk_bf16(e12, e13);
    }

    // build P fragments in-register (T12): frag kk = {x'0, x'1, y'0, y'1}
    bf16x8 pf[4];
#pragma unroll
    for (int kkl = 0; kkl < 2; kkl++){
      unsigned int x0 = A0[2*kkl][0], y0 = A0[2*kkl+1][0];
      unsigned int x1 = A0[2*kkl][1], y1 = A0[2*kkl+1][1];
      plane_swap(x0, y0);
      plane_swap(x1, y1);
      u32x4 w = {x0, x1, y0, y1};
      pf[kkl] = __builtin_bit_cast(bf16x8, w);
      unsigned int z0 = A1[2*kkl][0], t0w = A1[2*kkl+1][0];
      unsigned int z1 = A1[2*kkl][1], t1w = A1[2*kkl+1][1];
      plane_swap(z0, t0w);
      plane_swap(z1, t1w);
      u32x4 w2 = {z0, z1, t0w, t1w};
      pf[2 + kkl] = __builtin_bit_cast(bf16x8, w2);
    }

    // O^T += V^T . P^T ; l-row-sum via ones-MFMA
    const us* VbC = &Vb[cur][0];
    __builtin_amdgcn_s_setprio(1);
#pragma unroll
    for (int kk = 0; kk < 4; kk++){
      bf16x8 av0 = *(const bf16x8*)&VbC[l31 * 72 + kk * 16 + h8];
      bf16x8 av1 = *(const bf16x8*)&VbC[(32 + l31) * 72 + kk * 16 + h8];
      acc0 = __builtin_amdgcn_mfma_f32_32x32x16_bf16(av0, pf[kk], acc0, 0, 0, 0);
      acc1 = __builtin_amdgcn_mfma_f32_32x32x16_bf16(av1, pf[kk], acc1, 0, 0, 0);
      accS = __builtin_amdgcn_mfma_f32_32x32x16_bf16(ones8, pf[kk], accS, 0, 0, 0);
    }
    __builtin_amdgcn_s_setprio(0);

    // stage next tile into the other buffer, then single barrier
    if (pre){
      const int nxt = cur ^ 1;
      *(uint4*)&Kb[nxt][kt0 * 72 + kd0] = rK0;
      *(uint4*)&Kb[nxt][kt1 * 72 + kd1] = rK1;
      *(uint4*)&Vb[nxt][kt0 * 72 + kd0] = rV0;
      *(uint4*)&Vb[nxt][kt1 * 72 + kd1] = rV1;
    }
    __syncthreads();
  }
#undef GK
#undef GV

  // unnormalized partial output + m/l scalars
  us* ap = accP + (size_t)tch * 4194304 + (size_t)(b * MM + qrow) * 1024 + hd;
#pragma unroll
  for (int g = 0; g < 4; g++){
    bf16x4 w0, w1;
#pragma unroll
    for (int j = 0; j < 4; j++){
      w0[j] = (__bf16)acc0[4 * g + j];
      w1[j] = (__bf16)acc1[4 * g + j];
    }
    *(u16x4*)&ap[8 * g + 4 * hb]      = __builtin_bit_cast(u16x4, w0);
    *(u16x4*)&ap[32 + 8 * g + 4 * hb] = __builtin_bit_cast(u16x4, w1);
  }
  if (hb == 0){
    int idx = tch * 65536 + (b * MM + qrow) * 16 + (hd >> 6);
    Mv[idx] = mrow;
    Lv[idx] = accS[0];
  }
}

// ---------------- combine the two T-chunk partials ----------------
__global__ __launch_bounds__(256) void combine_kernel(const us* __restrict__ accP,
                                                      const float* __restrict__ Mv,
                                                      const float* __restrict__ Lv,
                                                      us* __restrict__ attno){
  size_t i = ((size_t)blockIdx.x * 256 + threadIdx.x) * 8;
  size_t qg = i >> 10;
  int h = (int)((i & 1023) >> 6);
  size_t mi = qg * 16 + h;
  float m1 = Mv[mi], m2 = Mv[65536 + mi];
  float l1 = Lv[mi], l2 = Lv[65536 + mi];
  float m = fmaxf(m1, m2);
  float w1 = __builtin_amdgcn_exp2f(m1 - m);
  float w2 = __builtin_amdgcn_exp2f(m2 - m);
  float inv = 1.f / (w1 * l1 + w2 * l2);
  float s1 = w1 * inv, s2 = w2 * inv;
  u16x8 a1 = *(const u16x8*)(accP + i);
  u16x8 a2 = *(const u16x8*)(accP + 4194304 + i);
  u16x8 o;
#pragma unroll
  for (int j = 0; j < 8; j++)
    o[j] = f2bf(s1 * bf2f(a1[j]) + s2 * bf2f(a2[j]));
  *(u16x8*)(attno + i) = o;
}

extern "C" void kernel_launch(void* const* d_in, const int* in_sizes, int n_in,
                              void* d_out, int out_size, void* d_ws, size_t ws_size,
                              hipStream_t stream){
  const float* x      = (const float*)d_in[0];
  const float* data   = (const float*)d_in[1];
  const float* W_attn = (const float*)d_in[2];
  const float* b_attn = (const float*)d_in[3];
  const float* W_data = (const float*)d_in[4];
  const float* b_data = (const float*)d_in[5];
  const float* W_proj = (const float*)d_in[6];
  const float* b_proj = (const float*)d_in[7];
  float* out = (float*)d_out;

  char* ws = (char*)d_ws;
  us* xf    = (us*)(ws + 0);             // [2][2048][1024] fp16 (8 MB)
  us* df    = (us*)(ws + 8388608);       // [2][2048][1024] fp16 (8 MB)
  us* Watf  = (us*)(ws + 16777216);      // [3072][1024] fp16 (6 MB)
  us* Wdtf  = (us*)(ws + 23068672);      // [2048][1024] fp16 (4 MB)
  us* Wptb  = (us*)(ws + 27262976);      // [1024][1024] bf16 (2 MB)
  us* Qf    = (us*)(ws + 29360128);      // [2][2048][1024] fp16 (8 MB)
  us* Kf    = (us*)(ws + 37748736);      // [2][4096][1024] fp16 (16 MB)
  us* VT    = (us*)(ws + 54525952);      // [2][1024][4096] bf16 (16 MB)
  us* accP  = (us*)(ws + 71303168);      // 2 x [2][2048][1024] bf16 partials (16 MB)
  float* Mv = (float*)(ws + 88080384);   // 2 x 64K floats (512 KB)
  float* Lv = (float*)(ws + 88604672);   // 2 x 64K floats (512 KB)
  us* attno = (us*)(ws + 0);             // alias xf (dead after gemm_all)

  prep_all<<<10240, 256, 0, stream>>>(x, data, W_attn, W_data, W_proj,
                                      xf, df, Watf, Wdtf, Wptb);

  gemm_all<<<dim3(40, 32), 256, 0, stream>>>(xf, df, Watf, Wdtf,
                                             b_attn, b_data, Qf, Kf, VT);

  attn_kernel<<<1024, 256, 0, stream>>>(Qf, Kf, VT, accP, Mv, Lv);
  combine_kernel<<<2048, 256, 0, stream>>>(accP, Mv, Lv, attno);

  gemm_proj<<<dim3(16, 32), 256, 0, stream>>>(attno, Wptb, b_proj, out);
}